// Round 5
// baseline (3983.368 us; speedup 1.0000x reference)
//
#include <hip/hip_runtime.h>
#include <math.h>

// ---------------- conv 7x7 stride4 pad3, Cin=3, 224->56, fused ReLU ----------------
__global__ __launch_bounds__(256) void k_conv7(const float* __restrict__ x,
                                               const float* __restrict__ w,
                                               float* __restrict__ y) {
  __shared__ float ws[147];
  const int boc = blockIdx.y;              // b*64 + oc
  const int oc = boc & 63;
  const int b = boc >> 6;
  for (int i = threadIdx.x; i < 147; i += 256) ws[i] = w[oc * 147 + i];
  __syncthreads();
  int px = blockIdx.x * 256 + threadIdx.x;
  if (px >= 56 * 56) return;
  int oy = px / 56, ox = px % 56;
  int iy0 = oy * 4 - 3, ix0 = ox * 4 - 3;
  float acc = 0.f;
  for (int c = 0; c < 3; ++c) {
    const float* xp = x + ((size_t)(b * 3 + c)) * 224 * 224;
    #pragma unroll
    for (int ky = 0; ky < 7; ++ky) {
      int iy = iy0 + ky;
      if ((unsigned)iy < 224u) {
        #pragma unroll
        for (int kx = 0; kx < 7; ++kx) {
          int ix = ix0 + kx;
          if ((unsigned)ix < 224u)
            acc += xp[iy * 224 + ix] * ws[c * 49 + ky * 7 + kx];
        }
      }
    }
  }
  y[((size_t)boc * 56 + oy) * 56 + ox] = fmaxf(acc, 0.f);
}

// ---------------- generic 3x3 stride2 pad1 conv, f32, fused ReLU ----------------
// Block tile: 64 oc x 64 px, thread tile 4x4, K chunked by 8 cin (72 k-steps).
template <int CIN, int HIN, int WIN, int COUT, int HOUT, int WOUT>
__global__ __launch_bounds__(256) void k_conv3(const float* __restrict__ x,
                                               const float* __restrict__ w,
                                               float* __restrict__ y) {
  constexpr int NPX = 4 * HOUT * WOUT;
  constexpr int CK = 8, KK = CK * 9, LDSW = 68;  // 68 = 64 + pad (keeps 16B align, kills write conflicts)
  __shared__ float Ws[KK][LDSW];
  __shared__ float Xs[KK][LDSW];
  __shared__ int pb[64], pyA[64], pxA[64];
  const int tid = threadIdx.x;
  const int oc0 = blockIdx.y * 64, px0 = blockIdx.x * 64;
  if (tid < 64) {
    int p = px0 + tid;
    if (p > NPX - 1) p = NPX - 1;
    int hw = HOUT * WOUT;
    pb[tid] = p / hw;
    int r = p % hw;
    pyA[tid] = r / WOUT;
    pxA[tid] = r % WOUT;
  }
  float acc[4][4] = {};
  const int tx = tid & 15, ty = tid >> 4;
  __syncthreads();
  for (int c0 = 0; c0 < CIN; c0 += CK) {
    // stage weights: Ws[kk][oc], kk contiguous per oc row -> coalesced-ish reads
    {
      int oc = tid >> 2, kb = (tid & 3) * 18;
      const float* wp = w + (size_t)(oc0 + oc) * CIN * 9 + c0 * 9 + kb;
      #pragma unroll
      for (int i = 0; i < 18; ++i) Ws[kb + i][oc] = wp[i];
    }
    // stage im2col X: Xs[kk][px]
    for (int e = tid; e < KK * 64; e += 256) {
      int kk = e >> 6, p = e & 63;
      int ci = kk / 9, tap = kk % 9, ky = tap / 3, kx = tap % 3;
      int iy = pyA[p] * 2 - 1 + ky, ix = pxA[p] * 2 - 1 + kx;
      float v = 0.f;
      if ((unsigned)iy < (unsigned)HIN && (unsigned)ix < (unsigned)WIN)
        v = x[(((size_t)pb[p] * CIN + c0 + ci) * HIN + iy) * WIN + ix];
      Xs[kk][p] = v;
    }
    __syncthreads();
    #pragma unroll 4
    for (int k = 0; k < KK; ++k) {
      float4 wv = *(const float4*)&Ws[k][ty * 4];
      float4 xv = *(const float4*)&Xs[k][tx * 4];
      float wr[4] = {wv.x, wv.y, wv.z, wv.w};
      float xr[4] = {xv.x, xv.y, xv.z, xv.w};
      #pragma unroll
      for (int i = 0; i < 4; ++i)
        #pragma unroll
        for (int j = 0; j < 4; ++j) acc[i][j] += wr[i] * xr[j];
    }
    __syncthreads();
  }
  #pragma unroll
  for (int i = 0; i < 4; ++i) {
    int oc = oc0 + ty * 4 + i;
    #pragma unroll
    for (int j = 0; j < 4; ++j) {
      int pidx = px0 + tx * 4 + j;
      if (pidx < NPX) {
        int t = tx * 4 + j;
        y[(((size_t)pb[t] * COUT + oc) * HOUT + pyA[t]) * WOUT + pxA[t]] = fmaxf(acc[i][j], 0.f);
      }
    }
  }
}

// ---------------- global-max-pool (7x7) + FC + sigmoid ----------------
__global__ __launch_bounds__(256) void k_poolfc(const float* __restrict__ feat,
                                                const float* __restrict__ fw,
                                                const float* __restrict__ fb,
                                                float* __restrict__ pool,
                                                float* __restrict__ out) {
  __shared__ float pl[2048];
  __shared__ float red[256];
  const int b = blockIdx.x, tid = threadIdx.x;
  for (int ch = tid; ch < 2048; ch += 256) {
    const float* fp = feat + ((size_t)b * 2048 + ch) * 49;
    float m = fp[0];
    #pragma unroll
    for (int i = 1; i < 49; ++i) m = fmaxf(m, fp[i]);
    pl[ch] = m;
    pool[b * 2048 + ch] = m;
  }
  __syncthreads();
  for (int c = 0; c < 14; ++c) {
    float s = 0.f;
    for (int k = tid; k < 2048; k += 256) s += pl[k] * fw[c * 2048 + k];
    red[tid] = s;
    __syncthreads();
    for (int st = 128; st > 0; st >>= 1) {
      if (tid < st) red[tid] += red[tid + st];
      __syncthreads();
    }
    if (tid == 0) out[b * 14 + c] = 1.f / (1.f + expf(-(red[0] + fb[c])));
    __syncthreads();
  }
}

// ---------------- per-sample 7x7 heatmap: channel max|.| then min-max normalize ----------------
__global__ __launch_bounds__(256) void k_hm7(const float* __restrict__ feat, float* __restrict__ hm7) {
  __shared__ float red[256];
  __shared__ float hm[49];
  const int b = blockIdx.x, tid = threadIdx.x;
  for (int cell = 0; cell < 49; ++cell) {
    float m = 0.f;
    for (int ch = tid; ch < 2048; ch += 256)
      m = fmaxf(m, fabsf(feat[((size_t)b * 2048 + ch) * 49 + cell]));
    red[tid] = m;
    __syncthreads();
    for (int st = 128; st > 0; st >>= 1) {
      if (tid < st) red[tid] = fmaxf(red[tid], red[tid + st]);
      __syncthreads();
    }
    if (tid == 0) hm[cell] = red[0];
    __syncthreads();
  }
  if (tid == 0) {
    float mn = hm[0], mx = hm[0];
    for (int i = 1; i < 49; ++i) {
      mn = fminf(mn, hm[i]);
      mx = fmaxf(mx, hm[i]);
    }
    for (int i = 0; i < 49; ++i) hm7[b * 49 + i] = (hm[i] - mn) / (mx - mn);
  }
}

// ---------------- mask runs + union-find CCL + bbox of largest component ----------------
// mask(y,x) = bilerp(hm7, halfpixel 7->224) > 0.7 ; label of a component after the
// reference's 448 max-dilations == max linear id in component. Winner: max count, tie -> min label.
#define MAXR 8
__global__ __launch_bounds__(256) void k_ccl(const float* __restrict__ hm7, float* __restrict__ bbox) {
  const int b = blockIdx.x, tid = threadIdx.x;
  __shared__ float h7[49];
  __shared__ short ci0[224];
  __shared__ float cf[224];
  __shared__ short rx0[224 * MAXR], rx1[224 * MAXR];
  __shared__ short nr[224];
  __shared__ unsigned short par[224 * MAXR];
  __shared__ int cnt[224 * MAXR];
  __shared__ int mid[224 * MAXR];
  __shared__ short rmn[224 * MAXR], rmx[224 * MAXR], cmn[224 * MAXR], cmx[224 * MAXR];

  if (tid < 49) h7[tid] = hm7[b * 49 + tid];
  for (int i = tid; i < 224; i += 256) {
    float p = ((float)i + 0.5f) * (7.f / 224.f) - 0.5f;
    p = fminf(fmaxf(p, 0.f), 6.f);
    int i0 = (int)floorf(p);
    if (i0 > 5) i0 = 5;
    ci0[i] = (short)i0;
    cf[i] = p - (float)i0;
  }
  for (int i = tid; i < 224 * MAXR; i += 256) {
    par[i] = (unsigned short)i; cnt[i] = 0; mid[i] = -1;
    rmn[i] = 32767; rmx[i] = -1; cmn[i] = 32767; cmx[i] = -1;
  }
  __syncthreads();
  if (tid < 224) {
    int yy = tid;
    int y0 = ci0[yy];
    float fy = cf[yy];
    const float* h0 = &h7[y0 * 7];
    const float* h1 = &h7[(y0 + 1) * 7];
    int n = 0, start = -1;
    for (int xx = 0; xx < 224; ++xx) {
      int x0 = ci0[xx];
      float fx = cf[xx];
      float v = (1.f - fy) * ((1.f - fx) * h0[x0] + fx * h0[x0 + 1]) +
                fy * ((1.f - fx) * h1[x0] + fx * h1[x0 + 1]);
      bool m = v > 0.7f;
      if (m && start < 0) start = xx;
      if (!m && start >= 0) {
        if (n < MAXR) { rx0[yy * MAXR + n] = (short)start; rx1[yy * MAXR + n] = (short)(xx - 1); n++; }
        start = -1;
      }
    }
    if (start >= 0 && n < MAXR) { rx0[yy * MAXR + n] = (short)start; rx1[yy * MAXR + n] = 223; n++; }
    nr[yy] = (short)n;
  }
  __syncthreads();
  if (tid == 0) {
    auto find = [&](int r) {
      while (par[r] != r) { par[r] = par[par[r]]; r = par[r]; }
      return r;
    };
    for (int yy = 1; yy < 224; ++yy)
      for (int k = 0; k < nr[yy]; ++k) {
        int r = yy * MAXR + k;
        int a0 = rx0[r], a1 = rx1[r];
        for (int kk = 0; kk < nr[yy - 1]; ++kk) {
          int q = (yy - 1) * MAXR + kk;
          if (a0 <= rx1[q] + 1 && a1 >= rx0[q] - 1) {   // 8-connected overlap
            int ra = find(r), rb = find(q);
            if (ra != rb) { par[ra > rb ? ra : rb] = (unsigned short)(ra < rb ? ra : rb); }
          }
        }
      }
    for (int yy = 0; yy < 224; ++yy)
      for (int k = 0; k < nr[yy]; ++k) {
        int r = yy * MAXR + k, rt = find(r);
        int a0 = rx0[r], a1 = rx1[r];
        cnt[rt] += a1 - a0 + 1;
        int idm = yy * 224 + a1 + 1;
        if (idm > mid[rt]) mid[rt] = idm;
        if (yy < rmn[rt]) rmn[rt] = (short)yy;
        if (yy > rmx[rt]) rmx[rt] = (short)yy;
        if (a0 < cmn[rt]) cmn[rt] = (short)a0;
        if (a1 > cmx[rt]) cmx[rt] = (short)a1;
      }
    int bc = -1, bm = 0x7fffffff, bi = -1;
    for (int yy = 0; yy < 224; ++yy)
      for (int k = 0; k < nr[yy]; ++k) {
        int r = yy * MAXR + k;
        if (par[r] != r) continue;
        if (cnt[r] > bc || (cnt[r] == bc && mid[r] < bm)) { bc = cnt[r]; bm = mid[r]; bi = r; }
      }
    float fy0, chf, fx0, cwf;
    if (bi < 0) { fy0 = 224.f; chf = 1.f; fx0 = 224.f; cwf = 1.f; }
    else {
      int dr = (int)rmx[bi] - (int)rmn[bi]; if (dr < 1) dr = 1;
      int dc = (int)cmx[bi] - (int)cmn[bi]; if (dc < 1) dc = 1;
      fy0 = (float)rmn[bi]; chf = (float)dr;
      fx0 = (float)cmn[bi]; cwf = (float)dc;
    }
    bbox[b * 4 + 0] = fy0; bbox[b * 4 + 1] = chf;
    bbox[b * 4 + 2] = fx0; bbox[b * 4 + 3] = cwf;
  }
}

// ---------------- bilinear crop-resize back to 224x224 ----------------
__global__ __launch_bounds__(256) void k_sample(const float* __restrict__ img,
                                                const float* __restrict__ bbox,
                                                float* __restrict__ patch_out,
                                                float* __restrict__ patch_ws) {
  int idx = blockIdx.x * 256 + threadIdx.x;
  if (idx >= 4 * 3 * 224 * 224) return;
  int b = idx / (3 * 224 * 224);
  int r = idx % (3 * 224 * 224);
  int c = r / (224 * 224);
  int p = r % (224 * 224);
  int oy = p / 224, ox = p % 224;
  float fy0 = bbox[b * 4 + 0], chf = bbox[b * 4 + 1];
  float fx0 = bbox[b * 4 + 2], cwf = bbox[b * 4 + 3];
  float gy = ((float)oy + 0.5f) * (chf / 224.f) + fy0 - 0.5f;
  float gx = ((float)ox + 0.5f) * (cwf / 224.f) + fx0 - 0.5f;
  gy = fminf(fmaxf(gy, fy0), fmaxf(fy0 + chf - 1.f, fy0));
  gx = fminf(fmaxf(gx, fx0), fmaxf(fx0 + cwf - 1.f, fx0));
  int y0 = (int)floorf(gy);
  int x0 = (int)floorf(gx);
  float fy = gy - (float)y0, fx = gx - (float)x0;
  int y0c = min(max(y0, 0), 223), y1c = min(max(y0 + 1, 0), 223);
  int x0c = min(max(x0, 0), 223), x1c = min(max(x0 + 1, 0), 223);
  const float* ip = img + ((size_t)b * 3 + c) * 224 * 224;
  float v00 = ip[y0c * 224 + x0c], v01 = ip[y0c * 224 + x1c];
  float v10 = ip[y1c * 224 + x0c], v11 = ip[y1c * 224 + x1c];
  float v = (1.f - fy) * ((1.f - fx) * v00 + fx * v01) + fy * ((1.f - fx) * v10 + fx * v11);
  patch_out[idx] = v;
  patch_ws[idx] = v;
}

// ---------------- out_f = sigmoid([pool_g|pool_l] @ fw.T + fb); loss = weighted BCEs ----------------
__global__ __launch_bounds__(256) void k_final(const float* __restrict__ poolg,
                                               const float* __restrict__ pooll,
                                               const float* __restrict__ fw,
                                               const float* __restrict__ fb,
                                               const float* __restrict__ target,
                                               float* __restrict__ dout) {
  __shared__ float outf[56];
  __shared__ float red[256];
  const int tid = threadIdx.x;
  int pair = tid >> 2, l4 = tid & 3;
  if (pair < 56) {
    int bb = pair / 14, c = pair % 14;
    const float* w = fw + (size_t)c * 4096;
    float s = 0.f;
    for (int k = l4; k < 2048; k += 4) s += poolg[bb * 2048 + k] * w[k];
    for (int k = l4; k < 2048; k += 4) s += pooll[bb * 2048 + k] * w[2048 + k];
    s += __shfl_down(s, 2, 4);
    s += __shfl_down(s, 1, 4);
    if (l4 == 0) {
      float o = 1.f / (1.f + expf(-(s + fb[c])));
      outf[pair] = o;
      dout[113 + pair] = o;
    }
  }
  __syncthreads();
  float term = 0.f;
  if (tid < 56) {
    float t = target[tid];
    float pg = dout[1 + tid], plo = dout[57 + tid], pf = outf[tid];
    auto bce1 = [&](float pp) {
      pp = fminf(fmaxf(pp, 1e-7f), 1.f - 1e-7f);
      return -(t * logf(pp) + (1.f - t) * log1pf(-pp));
    };
    term = (0.8f * bce1(pg) + 0.1f * bce1(plo) + 0.1f * bce1(pf)) * (1.f / 56.f);
  }
  red[tid] = term;
  __syncthreads();
  for (int st = 128; st > 0; st >>= 1) {
    if (tid < st) red[tid] += red[tid + st];
    __syncthreads();
  }
  if (tid == 0) dout[0] = red[0];
}

extern "C" void kernel_launch(void* const* d_in, const int* in_sizes, int n_in,
                              void* d_out, int out_size, void* d_ws, size_t ws_size,
                              hipStream_t stream) {
  const float* img = (const float*)d_in[0];
  const float* target = (const float*)d_in[1];
  const float* gw0 = (const float*)d_in[2];
  const float* gw1 = (const float*)d_in[3];
  const float* gw2 = (const float*)d_in[4];
  const float* gw3 = (const float*)d_in[5];
  const float* gfw = (const float*)d_in[6];
  const float* gfb = (const float*)d_in[7];
  const float* lw0 = (const float*)d_in[8];
  const float* lw1 = (const float*)d_in[9];
  const float* lw2 = (const float*)d_in[10];
  const float* lw3 = (const float*)d_in[11];
  const float* lfw = (const float*)d_in[12];
  const float* lfb = (const float*)d_in[13];
  const float* fw = (const float*)d_in[14];
  const float* fb = (const float*)d_in[15];
  float* out = (float*)d_out;
  float* ws = (float*)d_ws;

  float* c1 = ws;                    // 802816   [4,64,56,56]
  float* c2 = c1 + 802816;           // 1605632  [4,512,28,28]
  float* c3 = c2 + 1605632;          // 802816   [4,1024,14,14]
  float* c4 = c3 + 802816;           // 401408   [4,2048,7,7]
  float* poolg = c4 + 401408;        // 8192
  float* pooll = poolg + 8192;       // 8192
  float* hm7 = pooll + 8192;         // 196
  float* bbox = hm7 + 196;           // 16
  float* patch = ws + 3629312;       // 602112 (16B aligned)

  dim3 g7(13, 256);
  // global backbone
  k_conv7<<<g7, 256, 0, stream>>>(img, gw0, c1);
  k_conv3<64, 56, 56, 512, 28, 28><<<dim3(49, 8), 256, 0, stream>>>(c1, gw1, c2);
  k_conv3<512, 28, 28, 1024, 14, 14><<<dim3(13, 16), 256, 0, stream>>>(c2, gw2, c3);
  k_conv3<1024, 14, 14, 2048, 7, 7><<<dim3(4, 32), 256, 0, stream>>>(c3, gw3, c4);
  k_poolfc<<<4, 256, 0, stream>>>(c4, gfw, gfb, poolg, out + 1);
  // attention patch generation
  k_hm7<<<4, 256, 0, stream>>>(c4, hm7);
  k_ccl<<<4, 256, 0, stream>>>(hm7, bbox);
  k_sample<<<2352, 256, 0, stream>>>(img, bbox, out + 169, patch);
  // local backbone
  k_conv7<<<g7, 256, 0, stream>>>(patch, lw0, c1);
  k_conv3<64, 56, 56, 512, 28, 28><<<dim3(49, 8), 256, 0, stream>>>(c1, lw1, c2);
  k_conv3<512, 28, 28, 1024, 14, 14><<<dim3(13, 16), 256, 0, stream>>>(c2, lw2, c3);
  k_conv3<1024, 14, 14, 2048, 7, 7><<<dim3(4, 32), 256, 0, stream>>>(c3, lw3, c4);
  k_poolfc<<<4, 256, 0, stream>>>(c4, lfw, lfb, pooll, out + 57);
  // fusion + losses
  k_final<<<1, 256, 0, stream>>>(poolg, pooll, fw, fb, target, out);
}

// Round 6
// 1626.766 us; speedup vs baseline: 2.4486x; 2.4486x over previous
//
#include <hip/hip_runtime.h>
#include <math.h>

// ---------------- conv 7x7 stride4 pad3, Cin=3, 224->56, fused ReLU ----------------
__global__ __launch_bounds__(256) void k_conv7(const float* __restrict__ x,
                                               const float* __restrict__ w,
                                               float* __restrict__ y) {
  __shared__ float ws[147];
  const int boc = blockIdx.y;              // b*64 + oc
  const int oc = boc & 63;
  const int b = boc >> 6;
  for (int i = threadIdx.x; i < 147; i += 256) ws[i] = w[oc * 147 + i];
  __syncthreads();
  int px = blockIdx.x * 256 + threadIdx.x;
  if (px >= 56 * 56) return;
  int oy = px / 56, ox = px % 56;
  int iy0 = oy * 4 - 3, ix0 = ox * 4 - 3;
  float acc = 0.f;
  for (int c = 0; c < 3; ++c) {
    const float* xp = x + ((size_t)(b * 3 + c)) * 224 * 224;
    #pragma unroll
    for (int ky = 0; ky < 7; ++ky) {
      int iy = iy0 + ky;
      if ((unsigned)iy < 224u) {
        #pragma unroll
        for (int kx = 0; kx < 7; ++kx) {
          int ix = ix0 + kx;
          if ((unsigned)ix < 224u)
            acc += xp[iy * 224 + ix] * ws[c * 49 + ky * 7 + kx];
        }
      }
    }
  }
  y[((size_t)boc * 56 + oy) * 56 + ox] = fmaxf(acc, 0.f);
}

// ---------------- generic 3x3 stride2 pad1 conv, f32, split-K partials ----------------
// Block tile: 64 oc x 64 px, thread tile 4x4. grid.z = SPLIT over input-channel chunks.
// Each split writes a raw partial sum (no ReLU) to part[spl * N + out_idx].
template <int CIN, int HIN, int WIN, int COUT, int HOUT, int WOUT, int SPLIT>
__global__ __launch_bounds__(256) void k_conv3s(const float* __restrict__ x,
                                                const float* __restrict__ w,
                                                float* __restrict__ part) {
  constexpr int NPX = 4 * HOUT * WOUT;
  constexpr int CK = 8, KK = CK * 9, LDSW = 68;
  constexpr int CCHUNK = CIN / SPLIT;
  __shared__ float Ws[KK][LDSW];
  __shared__ float Xs[KK][LDSW];
  __shared__ int pb[64], pyA[64], pxA[64];
  const int tid = threadIdx.x;
  const int oc0 = blockIdx.y * 64, px0 = blockIdx.x * 64;
  const int spl = blockIdx.z;
  const int cbase = spl * CCHUNK;
  if (tid < 64) {
    int p = px0 + tid;
    if (p > NPX - 1) p = NPX - 1;
    int hw = HOUT * WOUT;
    pb[tid] = p / hw;
    int r = p % hw;
    pyA[tid] = r / WOUT;
    pxA[tid] = r % WOUT;
  }
  float acc[4][4] = {};
  const int tx = tid & 15, ty = tid >> 4;
  __syncthreads();
  for (int c0 = cbase; c0 < cbase + CCHUNK; c0 += CK) {
    // stage weights: Ws[kk][oc]
    {
      int oc = tid >> 2, kb = (tid & 3) * 18;
      const float* wp = w + (size_t)(oc0 + oc) * CIN * 9 + c0 * 9 + kb;
      #pragma unroll
      for (int i = 0; i < 18; ++i) Ws[kb + i][oc] = wp[i];
    }
    // stage im2col X: Xs[kk][px]
    for (int e = tid; e < KK * 64; e += 256) {
      int kk = e >> 6, p = e & 63;
      int ci = kk / 9, tap = kk % 9, ky = tap / 3, kx = tap % 3;
      int iy = pyA[p] * 2 - 1 + ky, ix = pxA[p] * 2 - 1 + kx;
      float v = 0.f;
      if ((unsigned)iy < (unsigned)HIN && (unsigned)ix < (unsigned)WIN)
        v = x[(((size_t)pb[p] * CIN + c0 + ci) * HIN + iy) * WIN + ix];
      Xs[kk][p] = v;
    }
    __syncthreads();
    #pragma unroll 4
    for (int k = 0; k < KK; ++k) {
      float4 wv = *(const float4*)&Ws[k][ty * 4];
      float4 xv = *(const float4*)&Xs[k][tx * 4];
      float wr[4] = {wv.x, wv.y, wv.z, wv.w};
      float xr[4] = {xv.x, xv.y, xv.z, xv.w};
      #pragma unroll
      for (int i = 0; i < 4; ++i)
        #pragma unroll
        for (int j = 0; j < 4; ++j) acc[i][j] += wr[i] * xr[j];
    }
    __syncthreads();
  }
  const size_t N = (size_t)4 * COUT * HOUT * WOUT;
  #pragma unroll
  for (int i = 0; i < 4; ++i) {
    int oc = oc0 + ty * 4 + i;
    #pragma unroll
    for (int j = 0; j < 4; ++j) {
      int pidx = px0 + tx * 4 + j;
      if (pidx < NPX) {
        int t = tx * 4 + j;
        part[(size_t)spl * N + (((size_t)pb[t] * COUT + oc) * HOUT + pyA[t]) * WOUT + pxA[t]] =
            acc[i][j];
      }
    }
  }
}

// ---------------- split-K reduction + ReLU ----------------
template <int SPLIT>
__global__ __launch_bounds__(256) void k_red(const float* __restrict__ part,
                                             float* __restrict__ y, int n) {
  for (int i = blockIdx.x * 256 + threadIdx.x; i < n; i += gridDim.x * 256) {
    float s = 0.f;
    #pragma unroll
    for (int sp = 0; sp < SPLIT; ++sp) s += part[(size_t)sp * n + i];
    y[i] = fmaxf(s, 0.f);
  }
}

// ---------------- global-max-pool (7x7): one thread per (b,ch) ----------------
__global__ __launch_bounds__(256) void k_pool(const float* __restrict__ feat,
                                              float* __restrict__ pool) {
  int idx = blockIdx.x * 256 + threadIdx.x;
  if (idx >= 8192) return;
  const float* fp = feat + (size_t)idx * 49;
  float m = fp[0];
  #pragma unroll
  for (int i = 1; i < 49; ++i) m = fmaxf(m, fp[i]);
  pool[idx] = m;
}

// ---------------- FC(2048->14) + sigmoid: one block per (b,c) ----------------
__global__ __launch_bounds__(256) void k_fcsig(const float* __restrict__ pool,
                                               const float* __restrict__ fw,
                                               const float* __restrict__ fb,
                                               float* __restrict__ outp) {
  __shared__ float red[256];
  const int blk = blockIdx.x;       // b*14 + c
  const int b = blk / 14, c = blk % 14;
  const int tid = threadIdx.x;
  float s = 0.f;
  for (int k = tid; k < 2048; k += 256) s += pool[b * 2048 + k] * fw[c * 2048 + k];
  red[tid] = s;
  __syncthreads();
  for (int st = 128; st > 0; st >>= 1) {
    if (tid < st) red[tid] += red[tid + st];
    __syncthreads();
  }
  if (tid == 0) outp[b * 14 + c] = 1.f / (1.f + expf(-(red[0] + fb[c])));
}

// ---------------- heatmap stage A: per-(b,cell) channel max|.| ----------------
__global__ __launch_bounds__(256) void k_hm7a(const float* __restrict__ feat,
                                              float* __restrict__ hmr) {
  __shared__ float red[256];
  const int b = blockIdx.x / 49, cell = blockIdx.x % 49;
  const int tid = threadIdx.x;
  float m = 0.f;
  for (int ch = tid; ch < 2048; ch += 256)
    m = fmaxf(m, fabsf(feat[((size_t)b * 2048 + ch) * 49 + cell]));
  red[tid] = m;
  __syncthreads();
  for (int st = 128; st > 0; st >>= 1) {
    if (tid < st) red[tid] = fmaxf(red[tid], red[tid + st]);
    __syncthreads();
  }
  if (tid == 0) hmr[b * 49 + cell] = red[0];
}

// ---------------- heatmap stage B: per-sample min-max normalize ----------------
__global__ __launch_bounds__(64) void k_hm7b(const float* __restrict__ hmr,
                                             float* __restrict__ hm7) {
  __shared__ float h[49];
  const int b = blockIdx.x, tid = threadIdx.x;
  if (tid < 49) h[tid] = hmr[b * 49 + tid];
  __syncthreads();
  if (tid == 0) {
    float mn = h[0], mx = h[0];
    for (int i = 1; i < 49; ++i) {
      mn = fminf(mn, h[i]);
      mx = fmaxf(mx, h[i]);
    }
    for (int i = 0; i < 49; ++i) hm7[b * 49 + i] = (h[i] - mn) / (mx - mn);
  }
}

// ---------------- mask runs + union-find CCL + bbox of largest component ----------------
// mask(y,x) = bilerp(hm7, halfpixel 7->224) > 0.7 ; label of a component after the
// reference's 448 max-dilations == max linear id in component. Winner: max count, tie -> min label.
#define MAXR 8
__global__ __launch_bounds__(256) void k_ccl(const float* __restrict__ hm7, float* __restrict__ bbox) {
  const int b = blockIdx.x, tid = threadIdx.x;
  __shared__ float h7[49];
  __shared__ short ci0[224];
  __shared__ float cf[224];
  __shared__ short rx0[224 * MAXR], rx1[224 * MAXR];
  __shared__ short nr[224];
  __shared__ unsigned short par[224 * MAXR];
  __shared__ int cnt[224 * MAXR];
  __shared__ int mid[224 * MAXR];
  __shared__ short rmn[224 * MAXR], rmx[224 * MAXR], cmn[224 * MAXR], cmx[224 * MAXR];

  if (tid < 49) h7[tid] = hm7[b * 49 + tid];
  for (int i = tid; i < 224; i += 256) {
    float p = ((float)i + 0.5f) * (7.f / 224.f) - 0.5f;
    p = fminf(fmaxf(p, 0.f), 6.f);
    int i0 = (int)floorf(p);
    if (i0 > 5) i0 = 5;
    ci0[i] = (short)i0;
    cf[i] = p - (float)i0;
  }
  for (int i = tid; i < 224 * MAXR; i += 256) {
    par[i] = (unsigned short)i; cnt[i] = 0; mid[i] = -1;
    rmn[i] = 32767; rmx[i] = -1; cmn[i] = 32767; cmx[i] = -1;
  }
  __syncthreads();
  if (tid < 224) {
    int yy = tid;
    int y0 = ci0[yy];
    float fy = cf[yy];
    const float* h0 = &h7[y0 * 7];
    const float* h1 = &h7[(y0 + 1) * 7];
    int n = 0, start = -1;
    for (int xx = 0; xx < 224; ++xx) {
      int x0 = ci0[xx];
      float fx = cf[xx];
      float v = (1.f - fy) * ((1.f - fx) * h0[x0] + fx * h0[x0 + 1]) +
                fy * ((1.f - fx) * h1[x0] + fx * h1[x0 + 1]);
      bool m = v > 0.7f;
      if (m && start < 0) start = xx;
      if (!m && start >= 0) {
        if (n < MAXR) { rx0[yy * MAXR + n] = (short)start; rx1[yy * MAXR + n] = (short)(xx - 1); n++; }
        start = -1;
      }
    }
    if (start >= 0 && n < MAXR) { rx0[yy * MAXR + n] = (short)start; rx1[yy * MAXR + n] = 223; n++; }
    nr[yy] = (short)n;
  }
  __syncthreads();
  if (tid == 0) {
    auto find = [&](int r) {
      while (par[r] != r) { par[r] = par[par[r]]; r = par[r]; }
      return r;
    };
    for (int yy = 1; yy < 224; ++yy)
      for (int k = 0; k < nr[yy]; ++k) {
        int r = yy * MAXR + k;
        int a0 = rx0[r], a1 = rx1[r];
        for (int kk = 0; kk < nr[yy - 1]; ++kk) {
          int q = (yy - 1) * MAXR + kk;
          if (a0 <= rx1[q] + 1 && a1 >= rx0[q] - 1) {   // 8-connected overlap
            int ra = find(r), rb = find(q);
            if (ra != rb) { par[ra > rb ? ra : rb] = (unsigned short)(ra < rb ? ra : rb); }
          }
        }
      }
    for (int yy = 0; yy < 224; ++yy)
      for (int k = 0; k < nr[yy]; ++k) {
        int r = yy * MAXR + k, rt = find(r);
        int a0 = rx0[r], a1 = rx1[r];
        cnt[rt] += a1 - a0 + 1;
        int idm = yy * 224 + a1 + 1;
        if (idm > mid[rt]) mid[rt] = idm;
        if (yy < rmn[rt]) rmn[rt] = (short)yy;
        if (yy > rmx[rt]) rmx[rt] = (short)yy;
        if (a0 < cmn[rt]) cmn[rt] = (short)a0;
        if (a1 > cmx[rt]) cmx[rt] = (short)a1;
      }
    int bc = -1, bm = 0x7fffffff, bi = -1;
    for (int yy = 0; yy < 224; ++yy)
      for (int k = 0; k < nr[yy]; ++k) {
        int r = yy * MAXR + k;
        if (par[r] != r) continue;
        if (cnt[r] > bc || (cnt[r] == bc && mid[r] < bm)) { bc = cnt[r]; bm = mid[r]; bi = r; }
      }
    float fy0, chf, fx0, cwf;
    if (bi < 0) { fy0 = 224.f; chf = 1.f; fx0 = 224.f; cwf = 1.f; }
    else {
      int dr = (int)rmx[bi] - (int)rmn[bi]; if (dr < 1) dr = 1;
      int dc = (int)cmx[bi] - (int)cmn[bi]; if (dc < 1) dc = 1;
      fy0 = (float)rmn[bi]; chf = (float)dr;
      fx0 = (float)cmn[bi]; cwf = (float)dc;
    }
    bbox[b * 4 + 0] = fy0; bbox[b * 4 + 1] = chf;
    bbox[b * 4 + 2] = fx0; bbox[b * 4 + 3] = cwf;
  }
}

// ---------------- bilinear crop-resize back to 224x224 ----------------
__global__ __launch_bounds__(256) void k_sample(const float* __restrict__ img,
                                                const float* __restrict__ bbox,
                                                float* __restrict__ patch_out,
                                                float* __restrict__ patch_ws) {
  int idx = blockIdx.x * 256 + threadIdx.x;
  if (idx >= 4 * 3 * 224 * 224) return;
  int b = idx / (3 * 224 * 224);
  int r = idx % (3 * 224 * 224);
  int c = r / (224 * 224);
  int p = r % (224 * 224);
  int oy = p / 224, ox = p % 224;
  float fy0 = bbox[b * 4 + 0], chf = bbox[b * 4 + 1];
  float fx0 = bbox[b * 4 + 2], cwf = bbox[b * 4 + 3];
  float gy = ((float)oy + 0.5f) * (chf / 224.f) + fy0 - 0.5f;
  float gx = ((float)ox + 0.5f) * (cwf / 224.f) + fx0 - 0.5f;
  gy = fminf(fmaxf(gy, fy0), fmaxf(fy0 + chf - 1.f, fy0));
  gx = fminf(fmaxf(gx, fx0), fmaxf(fx0 + cwf - 1.f, fx0));
  int y0 = (int)floorf(gy);
  int x0 = (int)floorf(gx);
  float fy = gy - (float)y0, fx = gx - (float)x0;
  int y0c = min(max(y0, 0), 223), y1c = min(max(y0 + 1, 0), 223);
  int x0c = min(max(x0, 0), 223), x1c = min(max(x0 + 1, 0), 223);
  const float* ip = img + ((size_t)b * 3 + c) * 224 * 224;
  float v00 = ip[y0c * 224 + x0c], v01 = ip[y0c * 224 + x1c];
  float v10 = ip[y1c * 224 + x0c], v11 = ip[y1c * 224 + x1c];
  float v = (1.f - fy) * ((1.f - fx) * v00 + fx * v01) + fy * ((1.f - fx) * v10 + fx * v11);
  patch_out[idx] = v;
  patch_ws[idx] = v;
}

// ---------------- out_f = sigmoid([pool_g|pool_l] @ fw.T + fb); loss = weighted BCEs ----------------
__global__ __launch_bounds__(256) void k_final(const float* __restrict__ poolg,
                                               const float* __restrict__ pooll,
                                               const float* __restrict__ fw,
                                               const float* __restrict__ fb,
                                               const float* __restrict__ target,
                                               float* __restrict__ dout) {
  __shared__ float outf[56];
  __shared__ float red[256];
  const int tid = threadIdx.x;
  int pair = tid >> 2, l4 = tid & 3;
  if (pair < 56) {
    int bb = pair / 14, c = pair % 14;
    const float* w = fw + (size_t)c * 4096;
    float s = 0.f;
    for (int k = l4; k < 2048; k += 4) s += poolg[bb * 2048 + k] * w[k];
    for (int k = l4; k < 2048; k += 4) s += pooll[bb * 2048 + k] * w[2048 + k];
    s += __shfl_down(s, 2, 4);
    s += __shfl_down(s, 1, 4);
    if (l4 == 0) {
      float o = 1.f / (1.f + expf(-(s + fb[c])));
      outf[pair] = o;
      dout[113 + pair] = o;
    }
  }
  __syncthreads();
  float term = 0.f;
  if (tid < 56) {
    float t = target[tid];
    float pg = dout[1 + tid], plo = dout[57 + tid], pf = outf[tid];
    auto bce1 = [&](float pp) {
      pp = fminf(fmaxf(pp, 1e-7f), 1.f - 1e-7f);
      return -(t * logf(pp) + (1.f - t) * log1pf(-pp));
    };
    term = (0.8f * bce1(pg) + 0.1f * bce1(plo) + 0.1f * bce1(pf)) * (1.f / 56.f);
  }
  red[tid] = term;
  __syncthreads();
  for (int st = 128; st > 0; st >>= 1) {
    if (tid < st) red[tid] += red[tid + st];
    __syncthreads();
  }
  if (tid == 0) dout[0] = red[0];
}

extern "C" void kernel_launch(void* const* d_in, const int* in_sizes, int n_in,
                              void* d_out, int out_size, void* d_ws, size_t ws_size,
                              hipStream_t stream) {
  const float* img = (const float*)d_in[0];
  const float* target = (const float*)d_in[1];
  const float* gw0 = (const float*)d_in[2];
  const float* gw1 = (const float*)d_in[3];
  const float* gw2 = (const float*)d_in[4];
  const float* gw3 = (const float*)d_in[5];
  const float* gfw = (const float*)d_in[6];
  const float* gfb = (const float*)d_in[7];
  const float* lw0 = (const float*)d_in[8];
  const float* lw1 = (const float*)d_in[9];
  const float* lw2 = (const float*)d_in[10];
  const float* lw3 = (const float*)d_in[11];
  const float* lfw = (const float*)d_in[12];
  const float* lfb = (const float*)d_in[13];
  const float* fw = (const float*)d_in[14];
  const float* fb = (const float*)d_in[15];
  float* out = (float*)d_out;
  float* ws = (float*)d_ws;

  float* c1 = ws;                    // 802816   [4,64,56,56]
  float* c2 = c1 + 802816;           // 1605632  [4,512,28,28]
  float* c3 = c2 + 1605632;          // 802816   [4,1024,14,14]
  float* c4 = c3 + 802816;           // 401408   [4,2048,7,7]
  float* poolg = c4 + 401408;        // 8192
  float* pooll = poolg + 8192;       // 8192
  float* hm7 = pooll + 8192;         // 196
  float* hmr = hm7 + 196;            // 196
  float* bbox = hmr + 196;           // 16
  float* patch = ws + 3629568;       // 602112 (16B aligned)
  float* part = ws + 4231680;        // 3211264 split-K partials (29.8 MB total ws)

  dim3 g7(13, 256);
  const int rg2 = 2048, rg3 = 2048, rg4 = 1568;  // k_red grids (grid-stride)

  // ---- global backbone ----
  k_conv7<<<g7, 256, 0, stream>>>(img, gw0, c1);
  k_conv3s<64, 56, 56, 512, 28, 28, 2><<<dim3(49, 8, 2), 256, 0, stream>>>(c1, gw1, part);
  k_red<2><<<rg2, 256, 0, stream>>>(part, c2, 1605632);
  k_conv3s<512, 28, 28, 1024, 14, 14, 4><<<dim3(13, 16, 4), 256, 0, stream>>>(c2, gw2, part);
  k_red<4><<<rg3, 256, 0, stream>>>(part, c3, 802816);
  k_conv3s<1024, 14, 14, 2048, 7, 7, 8><<<dim3(4, 32, 8), 256, 0, stream>>>(c3, gw3, part);
  k_red<8><<<rg4, 256, 0, stream>>>(part, c4, 401408);
  k_pool<<<32, 256, 0, stream>>>(c4, poolg);
  k_fcsig<<<56, 256, 0, stream>>>(poolg, gfw, gfb, out + 1);
  // ---- attention patch generation ----
  k_hm7a<<<196, 256, 0, stream>>>(c4, hmr);
  k_hm7b<<<4, 64, 0, stream>>>(hmr, hm7);
  k_ccl<<<4, 256, 0, stream>>>(hm7, bbox);
  k_sample<<<2352, 256, 0, stream>>>(img, bbox, out + 169, patch);
  // ---- local backbone ----
  k_conv7<<<g7, 256, 0, stream>>>(patch, lw0, c1);
  k_conv3s<64, 56, 56, 512, 28, 28, 2><<<dim3(49, 8, 2), 256, 0, stream>>>(c1, lw1, part);
  k_red<2><<<rg2, 256, 0, stream>>>(part, c2, 1605632);
  k_conv3s<512, 28, 28, 1024, 14, 14, 4><<<dim3(13, 16, 4), 256, 0, stream>>>(c2, lw2, part);
  k_red<4><<<rg3, 256, 0, stream>>>(part, c3, 802816);
  k_conv3s<1024, 14, 14, 2048, 7, 7, 8><<<dim3(4, 32, 8), 256, 0, stream>>>(c3, lw3, part);
  k_red<8><<<rg4, 256, 0, stream>>>(part, c4, 401408);
  k_pool<<<32, 256, 0, stream>>>(c4, pooll);
  k_fcsig<<<56, 256, 0, stream>>>(pooll, lfw, lfb, out + 57);
  // ---- fusion + losses ----
  k_final<<<1, 256, 0, stream>>>(poolg, pooll, fw, fb, target, out);
}

// Round 7
// 1615.280 us; speedup vs baseline: 2.4661x; 1.0071x over previous
//
#include <hip/hip_runtime.h>
#include <math.h>

// ---------------- conv 7x7 stride4 pad3, Cin=3, 224->56, fused ReLU ----------------
__global__ __launch_bounds__(256) void k_conv7(const float* __restrict__ x,
                                               const float* __restrict__ w,
                                               float* __restrict__ y) {
  __shared__ float ws[147];
  const int boc = blockIdx.y;              // b*64 + oc
  const int oc = boc & 63;
  const int b = boc >> 6;
  for (int i = threadIdx.x; i < 147; i += 256) ws[i] = w[oc * 147 + i];
  __syncthreads();
  int px = blockIdx.x * 256 + threadIdx.x;
  if (px >= 56 * 56) return;
  int oy = px / 56, ox = px % 56;
  int iy0 = oy * 4 - 3, ix0 = ox * 4 - 3;
  float acc = 0.f;
  for (int c = 0; c < 3; ++c) {
    const float* xp = x + ((size_t)(b * 3 + c)) * 224 * 224;
    #pragma unroll
    for (int ky = 0; ky < 7; ++ky) {
      int iy = iy0 + ky;
      if ((unsigned)iy < 224u) {
        #pragma unroll
        for (int kx = 0; kx < 7; ++kx) {
          int ix = ix0 + kx;
          if ((unsigned)ix < 224u)
            acc += xp[iy * 224 + ix] * ws[c * 49 + ky * 7 + kx];
        }
      }
    }
  }
  y[((size_t)boc * 56 + oy) * 56 + ox] = fmaxf(acc, 0.f);
}

// ---------------- generic 3x3 stride2 pad1 conv, f32, split-K partials ----------------
template <int CIN, int HIN, int WIN, int COUT, int HOUT, int WOUT, int SPLIT>
__global__ __launch_bounds__(256) void k_conv3s(const float* __restrict__ x,
                                                const float* __restrict__ w,
                                                float* __restrict__ part) {
  constexpr int NPX = 4 * HOUT * WOUT;
  constexpr int CK = 8, KK = CK * 9, LDSW = 68;
  constexpr int CCHUNK = CIN / SPLIT;
  __shared__ float Ws[KK][LDSW];
  __shared__ float Xs[KK][LDSW];
  __shared__ int pb[64], pyA[64], pxA[64];
  const int tid = threadIdx.x;
  const int oc0 = blockIdx.y * 64, px0 = blockIdx.x * 64;
  const int spl = blockIdx.z;
  const int cbase = spl * CCHUNK;
  if (tid < 64) {
    int p = px0 + tid;
    if (p > NPX - 1) p = NPX - 1;
    int hw = HOUT * WOUT;
    pb[tid] = p / hw;
    int r = p % hw;
    pyA[tid] = r / WOUT;
    pxA[tid] = r % WOUT;
  }
  float acc[4][4] = {};
  const int tx = tid & 15, ty = tid >> 4;
  __syncthreads();
  for (int c0 = cbase; c0 < cbase + CCHUNK; c0 += CK) {
    {
      int oc = tid >> 2, kb = (tid & 3) * 18;
      const float* wp = w + (size_t)(oc0 + oc) * CIN * 9 + c0 * 9 + kb;
      #pragma unroll
      for (int i = 0; i < 18; ++i) Ws[kb + i][oc] = wp[i];
    }
    for (int e = tid; e < KK * 64; e += 256) {
      int kk = e >> 6, p = e & 63;
      int ci = kk / 9, tap = kk % 9, ky = tap / 3, kx = tap % 3;
      int iy = pyA[p] * 2 - 1 + ky, ix = pxA[p] * 2 - 1 + kx;
      float v = 0.f;
      if ((unsigned)iy < (unsigned)HIN && (unsigned)ix < (unsigned)WIN)
        v = x[(((size_t)pb[p] * CIN + c0 + ci) * HIN + iy) * WIN + ix];
      Xs[kk][p] = v;
    }
    __syncthreads();
    #pragma unroll 4
    for (int k = 0; k < KK; ++k) {
      float4 wv = *(const float4*)&Ws[k][ty * 4];
      float4 xv = *(const float4*)&Xs[k][tx * 4];
      float wr[4] = {wv.x, wv.y, wv.z, wv.w};
      float xr[4] = {xv.x, xv.y, xv.z, xv.w};
      #pragma unroll
      for (int i = 0; i < 4; ++i)
        #pragma unroll
        for (int j = 0; j < 4; ++j) acc[i][j] += wr[i] * xr[j];
    }
    __syncthreads();
  }
  const size_t N = (size_t)4 * COUT * HOUT * WOUT;
  #pragma unroll
  for (int i = 0; i < 4; ++i) {
    int oc = oc0 + ty * 4 + i;
    #pragma unroll
    for (int j = 0; j < 4; ++j) {
      int pidx = px0 + tx * 4 + j;
      if (pidx < NPX) {
        int t = tx * 4 + j;
        part[(size_t)spl * N + (((size_t)pb[t] * COUT + oc) * HOUT + pyA[t]) * WOUT + pxA[t]] =
            acc[i][j];
      }
    }
  }
}

// ---------------- split-K reduction + ReLU ----------------
template <int SPLIT>
__global__ __launch_bounds__(256) void k_red(const float* __restrict__ part,
                                             float* __restrict__ y, int n) {
  for (int i = blockIdx.x * 256 + threadIdx.x; i < n; i += gridDim.x * 256) {
    float s = 0.f;
    #pragma unroll
    for (int sp = 0; sp < SPLIT; ++sp) s += part[(size_t)sp * n + i];
    y[i] = fmaxf(s, 0.f);
  }
}

// ---------------- global-max-pool (7x7): one thread per (b,ch) ----------------
__global__ __launch_bounds__(256) void k_pool(const float* __restrict__ feat,
                                              float* __restrict__ pool) {
  int idx = blockIdx.x * 256 + threadIdx.x;
  if (idx >= 8192) return;
  const float* fp = feat + (size_t)idx * 49;
  float m = fp[0];
  #pragma unroll
  for (int i = 1; i < 49; ++i) m = fmaxf(m, fp[i]);
  pool[idx] = m;
}

// ---------------- FC(2048->14) + sigmoid: one block per (b,c) ----------------
__global__ __launch_bounds__(256) void k_fcsig(const float* __restrict__ pool,
                                               const float* __restrict__ fw,
                                               const float* __restrict__ fb,
                                               float* __restrict__ outp) {
  __shared__ float red[256];
  const int blk = blockIdx.x;       // b*14 + c
  const int b = blk / 14, c = blk % 14;
  const int tid = threadIdx.x;
  float s = 0.f;
  for (int k = tid; k < 2048; k += 256) s += pool[b * 2048 + k] * fw[c * 2048 + k];
  red[tid] = s;
  __syncthreads();
  for (int st = 128; st > 0; st >>= 1) {
    if (tid < st) red[tid] += red[tid + st];
    __syncthreads();
  }
  if (tid == 0) outp[b * 14 + c] = 1.f / (1.f + expf(-(red[0] + fb[c])));
}

// ---------------- heatmap stage A: per-(b,cell) channel max|.| ----------------
__global__ __launch_bounds__(256) void k_hm7a(const float* __restrict__ feat,
                                              float* __restrict__ hmr) {
  __shared__ float red[256];
  const int b = blockIdx.x / 49, cell = blockIdx.x % 49;
  const int tid = threadIdx.x;
  float m = 0.f;
  for (int ch = tid; ch < 2048; ch += 256)
    m = fmaxf(m, fabsf(feat[((size_t)b * 2048 + ch) * 49 + cell]));
  red[tid] = m;
  __syncthreads();
  for (int st = 128; st > 0; st >>= 1) {
    if (tid < st) red[tid] = fmaxf(red[tid], red[tid + st]);
    __syncthreads();
  }
  if (tid == 0) hmr[b * 49 + cell] = red[0];
}

// ---------------- heatmap stage B: per-sample min-max normalize ----------------
__global__ __launch_bounds__(64) void k_hm7b(const float* __restrict__ hmr,
                                             float* __restrict__ hm7) {
  __shared__ float h[49];
  const int b = blockIdx.x, tid = threadIdx.x;
  if (tid < 49) h[tid] = hmr[b * 49 + tid];
  __syncthreads();
  if (tid == 0) {
    float mn = h[0], mx = h[0];
    for (int i = 1; i < 49; ++i) {
      mn = fminf(mn, h[i]);
      mx = fmaxf(mx, h[i]);
    }
    for (int i = 0; i < 49; ++i) hm7[b * 49 + i] = (h[i] - mn) / (mx - mn);
  }
}

// ---------------- parallel CCL on mask runs + bbox of largest component ----------------
// mask(y,x) = bilerp(hm7, halfpixel 7->224) > 0.7.
// Runs per row (<=8); components found by parallel min-label propagation (FastSV-style):
// labels monotone-decrease toward the unique fixpoint (component-min run index), so the
// result is deterministic despite benign LDS races. Stats via LDS int atomics (exact).
// Winner semantics identical to reference argmax: max count, tie -> min label(=max pixel id).
#define MAXR 8
#define NRUNS (224 * MAXR)
__global__ __launch_bounds__(256) void k_ccl(const float* __restrict__ hm7, float* __restrict__ bbox) {
  const int b = blockIdx.x, tid = threadIdx.x;
  __shared__ float h7[49];
  __shared__ short ci0[224];
  __shared__ float cf[224];
  __shared__ short rx0[NRUNS], rx1[NRUNS];
  __shared__ short nr[224];
  __shared__ int lab[NRUNS];
  __shared__ int cnt[NRUNS], mid[NRUNS];
  __shared__ int rmn[NRUNS], rmx[NRUNS], cmn[NRUNS], cmx[NRUNS];
  __shared__ int changed;
  __shared__ int bestC[256], bestM[256], bestI[256];

  if (tid < 49) h7[tid] = hm7[b * 49 + tid];
  if (tid < 224) {
    float p = ((float)tid + 0.5f) * (7.f / 224.f) - 0.5f;
    p = fminf(fmaxf(p, 0.f), 6.f);
    int i0 = (int)floorf(p);
    if (i0 > 5) i0 = 5;
    ci0[tid] = (short)i0;
    cf[tid] = p - (float)i0;
  }
  for (int i = tid; i < NRUNS; i += 256) {
    cnt[i] = 0; mid[i] = -1;
    rmn[i] = 1 << 30; rmx[i] = -1; cmn[i] = 1 << 30; cmx[i] = -1;
    lab[i] = i;
  }
  __syncthreads();
  // per-row run extraction (identical mask arithmetic to the verified serial version)
  if (tid < 224) {
    int yy = tid;
    int y0 = ci0[yy];
    float fy = cf[yy];
    const float* h0 = &h7[y0 * 7];
    const float* h1 = &h7[(y0 + 1) * 7];
    int n = 0, start = -1;
    for (int xx = 0; xx < 224; ++xx) {
      int x0 = ci0[xx];
      float fx = cf[xx];
      float v = (1.f - fy) * ((1.f - fx) * h0[x0] + fx * h0[x0 + 1]) +
                fy * ((1.f - fx) * h1[x0] + fx * h1[x0 + 1]);
      bool m = v > 0.7f;
      if (m && start < 0) start = xx;
      if (!m && start >= 0) {
        if (n < MAXR) { rx0[yy * MAXR + n] = (short)start; rx1[yy * MAXR + n] = (short)(xx - 1); n++; }
        start = -1;
      }
    }
    if (start >= 0 && n < MAXR) { rx0[yy * MAXR + n] = (short)start; rx1[yy * MAXR + n] = 223; n++; }
    nr[yy] = (short)n;
  }
  __syncthreads();
  // parallel min-label propagation to fixpoint
  for (int iter = 0; iter < NRUNS; ++iter) {
    if (tid == 0) changed = 0;
    __syncthreads();
    for (int i = tid; i < NRUNS; i += 256) {
      int yy = i >> 3, k = i & 7;
      if (k >= (int)nr[yy]) continue;
      int a0 = rx0[i], a1 = rx1[i];
      int m = lab[i];
      if (yy > 0) {
        int n1 = nr[yy - 1];
        for (int kk = 0; kk < n1; ++kk) {
          int q = ((yy - 1) << 3) + kk;
          if (a0 <= rx1[q] + 1 && a1 >= rx0[q] - 1) { int l = lab[q]; if (l < m) m = l; }
        }
      }
      if (yy < 223) {
        int n1 = nr[yy + 1];
        for (int kk = 0; kk < n1; ++kk) {
          int q = ((yy + 1) << 3) + kk;
          if (a0 <= rx1[q] + 1 && a1 >= rx0[q] - 1) { int l = lab[q]; if (l < m) m = l; }
        }
      }
      if (m < lab[i]) { lab[i] = m; changed = 1; }
    }
    __syncthreads();
    if (!changed) break;
    // path halving (labels only decrease; safe under races)
    for (int i = tid; i < NRUNS; i += 256) {
      int l = lab[i];
      int l2 = lab[l];
      if (l2 < l) lab[i] = l2;
    }
    __syncthreads();
  }
  // component stats via LDS atomics (ints -> exact, deterministic)
  for (int i = tid; i < NRUNS; i += 256) {
    int yy = i >> 3, k = i & 7;
    if (k >= (int)nr[yy]) continue;
    int r = lab[i];
    int a0 = rx0[i], a1 = rx1[i];
    atomicAdd(&cnt[r], a1 - a0 + 1);
    atomicMax(&mid[r], yy * 224 + a1 + 1);
    atomicMin(&rmn[r], yy);
    atomicMax(&rmx[r], yy);
    atomicMin(&cmn[r], a0);
    atomicMax(&cmx[r], a1);
  }
  __syncthreads();
  // winner: max count, tie -> min label(mid)
  int bc = -1, bm = 0x7fffffff, bi = -1;
  for (int i = tid; i < NRUNS; i += 256) {
    if (cnt[i] > 0 && lab[i] == i) {
      if (cnt[i] > bc || (cnt[i] == bc && mid[i] < bm)) { bc = cnt[i]; bm = mid[i]; bi = i; }
    }
  }
  bestC[tid] = bc; bestM[tid] = bm; bestI[tid] = bi;
  __syncthreads();
  for (int st = 128; st > 0; st >>= 1) {
    if (tid < st) {
      if (bestC[tid + st] > bestC[tid] ||
          (bestC[tid + st] == bestC[tid] && bestM[tid + st] < bestM[tid])) {
        bestC[tid] = bestC[tid + st]; bestM[tid] = bestM[tid + st]; bestI[tid] = bestI[tid + st];
      }
    }
    __syncthreads();
  }
  if (tid == 0) {
    int bw = bestI[0];
    float fy0, chf, fx0, cwf;
    if (bw < 0) { fy0 = 224.f; chf = 1.f; fx0 = 224.f; cwf = 1.f; }
    else {
      int dr = rmx[bw] - rmn[bw]; if (dr < 1) dr = 1;
      int dc = cmx[bw] - cmn[bw]; if (dc < 1) dc = 1;
      fy0 = (float)rmn[bw]; chf = (float)dr;
      fx0 = (float)cmn[bw]; cwf = (float)dc;
    }
    bbox[b * 4 + 0] = fy0; bbox[b * 4 + 1] = chf;
    bbox[b * 4 + 2] = fx0; bbox[b * 4 + 3] = cwf;
  }
}

// ---------------- bilinear crop-resize back to 224x224 ----------------
__global__ __launch_bounds__(256) void k_sample(const float* __restrict__ img,
                                                const float* __restrict__ bbox,
                                                float* __restrict__ patch_out,
                                                float* __restrict__ patch_ws) {
  int idx = blockIdx.x * 256 + threadIdx.x;
  if (idx >= 4 * 3 * 224 * 224) return;
  int b = idx / (3 * 224 * 224);
  int r = idx % (3 * 224 * 224);
  int c = r / (224 * 224);
  int p = r % (224 * 224);
  int oy = p / 224, ox = p % 224;
  float fy0 = bbox[b * 4 + 0], chf = bbox[b * 4 + 1];
  float fx0 = bbox[b * 4 + 2], cwf = bbox[b * 4 + 3];
  float gy = ((float)oy + 0.5f) * (chf / 224.f) + fy0 - 0.5f;
  float gx = ((float)ox + 0.5f) * (cwf / 224.f) + fx0 - 0.5f;
  gy = fminf(fmaxf(gy, fy0), fmaxf(fy0 + chf - 1.f, fy0));
  gx = fminf(fmaxf(gx, fx0), fmaxf(fx0 + cwf - 1.f, fx0));
  int y0 = (int)floorf(gy);
  int x0 = (int)floorf(gx);
  float fy = gy - (float)y0, fx = gx - (float)x0;
  int y0c = min(max(y0, 0), 223), y1c = min(max(y0 + 1, 0), 223);
  int x0c = min(max(x0, 0), 223), x1c = min(max(x0 + 1, 0), 223);
  const float* ip = img + ((size_t)b * 3 + c) * 224 * 224;
  float v00 = ip[y0c * 224 + x0c], v01 = ip[y0c * 224 + x1c];
  float v10 = ip[y1c * 224 + x0c], v11 = ip[y1c * 224 + x1c];
  float v = (1.f - fy) * ((1.f - fx) * v00 + fx * v01) + fy * ((1.f - fx) * v10 + fx * v11);
  patch_out[idx] = v;
  patch_ws[idx] = v;
}

// ---------------- out_f = sigmoid([pool_g|pool_l] @ fw.T + fb); loss = weighted BCEs ----------------
__global__ __launch_bounds__(256) void k_final(const float* __restrict__ poolg,
                                               const float* __restrict__ pooll,
                                               const float* __restrict__ fw,
                                               const float* __restrict__ fb,
                                               const float* __restrict__ target,
                                               float* __restrict__ dout) {
  __shared__ float outf[56];
  __shared__ float red[256];
  const int tid = threadIdx.x;
  int pair = tid >> 2, l4 = tid & 3;
  if (pair < 56) {
    int bb = pair / 14, c = pair % 14;
    const float* w = fw + (size_t)c * 4096;
    float s = 0.f;
    for (int k = l4; k < 2048; k += 4) s += poolg[bb * 2048 + k] * w[k];
    for (int k = l4; k < 2048; k += 4) s += pooll[bb * 2048 + k] * w[2048 + k];
    s += __shfl_down(s, 2, 4);
    s += __shfl_down(s, 1, 4);
    if (l4 == 0) {
      float o = 1.f / (1.f + expf(-(s + fb[c])));
      outf[pair] = o;
      dout[113 + pair] = o;
    }
  }
  __syncthreads();
  float term = 0.f;
  if (tid < 56) {
    float t = target[tid];
    float pg = dout[1 + tid], plo = dout[57 + tid], pf = outf[tid];
    auto bce1 = [&](float pp) {
      pp = fminf(fmaxf(pp, 1e-7f), 1.f - 1e-7f);
      return -(t * logf(pp) + (1.f - t) * log1pf(-pp));
    };
    term = (0.8f * bce1(pg) + 0.1f * bce1(plo) + 0.1f * bce1(pf)) * (1.f / 56.f);
  }
  red[tid] = term;
  __syncthreads();
  for (int st = 128; st > 0; st >>= 1) {
    if (tid < st) red[tid] += red[tid + st];
    __syncthreads();
  }
  if (tid == 0) dout[0] = red[0];
}

extern "C" void kernel_launch(void* const* d_in, const int* in_sizes, int n_in,
                              void* d_out, int out_size, void* d_ws, size_t ws_size,
                              hipStream_t stream) {
  const float* img = (const float*)d_in[0];
  const float* target = (const float*)d_in[1];
  const float* gw0 = (const float*)d_in[2];
  const float* gw1 = (const float*)d_in[3];
  const float* gw2 = (const float*)d_in[4];
  const float* gw3 = (const float*)d_in[5];
  const float* gfw = (const float*)d_in[6];
  const float* gfb = (const float*)d_in[7];
  const float* lw0 = (const float*)d_in[8];
  const float* lw1 = (const float*)d_in[9];
  const float* lw2 = (const float*)d_in[10];
  const float* lw3 = (const float*)d_in[11];
  const float* lfw = (const float*)d_in[12];
  const float* lfb = (const float*)d_in[13];
  const float* fw = (const float*)d_in[14];
  const float* fb = (const float*)d_in[15];
  float* out = (float*)d_out;
  float* ws = (float*)d_ws;

  float* c1 = ws;                    // 802816   [4,64,56,56]
  float* c2 = c1 + 802816;           // 1605632  [4,512,28,28]
  float* c3 = c2 + 1605632;          // 802816   [4,1024,14,14]
  float* c4 = c3 + 802816;           // 401408   [4,2048,7,7]
  float* poolg = c4 + 401408;        // 8192
  float* pooll = poolg + 8192;       // 8192
  float* hm7 = pooll + 8192;         // 196
  float* hmr = hm7 + 196;            // 196
  float* bbox = hmr + 196;           // 16
  float* patch = ws + 3629568;       // 602112 (16B aligned)
  float* part = ws + 4231680;        // 3211264 split-K partials (29.8 MB total ws)

  dim3 g7(13, 256);
  const int rg2 = 2048, rg3 = 2048, rg4 = 1568;  // k_red grids (grid-stride)

  // ---- global backbone ----
  k_conv7<<<g7, 256, 0, stream>>>(img, gw0, c1);
  k_conv3s<64, 56, 56, 512, 28, 28, 2><<<dim3(49, 8, 2), 256, 0, stream>>>(c1, gw1, part);
  k_red<2><<<rg2, 256, 0, stream>>>(part, c2, 1605632);
  k_conv3s<512, 28, 28, 1024, 14, 14, 4><<<dim3(13, 16, 4), 256, 0, stream>>>(c2, gw2, part);
  k_red<4><<<rg3, 256, 0, stream>>>(part, c3, 802816);
  k_conv3s<1024, 14, 14, 2048, 7, 7, 8><<<dim3(4, 32, 8), 256, 0, stream>>>(c3, gw3, part);
  k_red<8><<<rg4, 256, 0, stream>>>(part, c4, 401408);
  k_pool<<<32, 256, 0, stream>>>(c4, poolg);
  k_fcsig<<<56, 256, 0, stream>>>(poolg, gfw, gfb, out + 1);
  // ---- attention patch generation ----
  k_hm7a<<<196, 256, 0, stream>>>(c4, hmr);
  k_hm7b<<<4, 64, 0, stream>>>(hmr, hm7);
  k_ccl<<<4, 256, 0, stream>>>(hm7, bbox);
  k_sample<<<2352, 256, 0, stream>>>(img, bbox, out + 169, patch);
  // ---- local backbone ----
  k_conv7<<<g7, 256, 0, stream>>>(patch, lw0, c1);
  k_conv3s<64, 56, 56, 512, 28, 28, 2><<<dim3(49, 8, 2), 256, 0, stream>>>(c1, lw1, part);
  k_red<2><<<rg2, 256, 0, stream>>>(part, c2, 1605632);
  k_conv3s<512, 28, 28, 1024, 14, 14, 4><<<dim3(13, 16, 4), 256, 0, stream>>>(c2, lw2, part);
  k_red<4><<<rg3, 256, 0, stream>>>(part, c3, 802816);
  k_conv3s<1024, 14, 14, 2048, 7, 7, 8><<<dim3(4, 32, 8), 256, 0, stream>>>(c3, lw3, part);
  k_red<8><<<rg4, 256, 0, stream>>>(part, c4, 401408);
  k_pool<<<32, 256, 0, stream>>>(c4, pooll);
  k_fcsig<<<56, 256, 0, stream>>>(pooll, lfw, lfb, out + 57);
  // ---- fusion + losses ----
  k_final<<<1, 256, 0, stream>>>(poolg, pooll, fw, fb, target, out);
}

// Round 8
// 1584.562 us; speedup vs baseline: 2.5139x; 1.0194x over previous
//
#include <hip/hip_runtime.h>
#include <math.h>

// ---------------- conv 7x7 stride4 pad3, Cin=3, 224->56, fused ReLU ----------------
__global__ __launch_bounds__(256) void k_conv7(const float* __restrict__ x,
                                               const float* __restrict__ w,
                                               float* __restrict__ y) {
  __shared__ float ws[147];
  const int boc = blockIdx.y;              // b*64 + oc
  const int oc = boc & 63;
  const int b = boc >> 6;
  for (int i = threadIdx.x; i < 147; i += 256) ws[i] = w[oc * 147 + i];
  __syncthreads();
  int px = blockIdx.x * 256 + threadIdx.x;
  if (px >= 56 * 56) return;
  int oy = px / 56, ox = px % 56;
  int iy0 = oy * 4 - 3, ix0 = ox * 4 - 3;
  float acc = 0.f;
  for (int c = 0; c < 3; ++c) {
    const float* xp = x + ((size_t)(b * 3 + c)) * 224 * 224;
    #pragma unroll
    for (int ky = 0; ky < 7; ++ky) {
      int iy = iy0 + ky;
      if ((unsigned)iy < 224u) {
        #pragma unroll
        for (int kx = 0; kx < 7; ++kx) {
          int ix = ix0 + kx;
          if ((unsigned)ix < 224u)
            acc += xp[iy * 224 + ix] * ws[c * 49 + ky * 7 + kx];
        }
      }
    }
  }
  y[((size_t)boc * 56 + oy) * 56 + ox] = fmaxf(acc, 0.f);
}

// ---------------- generic 3x3 stride2 pad1 conv, f32, split-K partials ----------------
template <int CIN, int HIN, int WIN, int COUT, int HOUT, int WOUT, int SPLIT>
__global__ __launch_bounds__(256) void k_conv3s(const float* __restrict__ x,
                                                const float* __restrict__ w,
                                                float* __restrict__ part) {
  constexpr int NPX = 4 * HOUT * WOUT;
  constexpr int CK = 8, KK = CK * 9, LDSW = 68;
  constexpr int CCHUNK = CIN / SPLIT;
  __shared__ float Ws[KK][LDSW];
  __shared__ float Xs[KK][LDSW];
  __shared__ int pb[64], pyA[64], pxA[64];
  const int tid = threadIdx.x;
  const int oc0 = blockIdx.y * 64, px0 = blockIdx.x * 64;
  const int spl = blockIdx.z;
  const int cbase = spl * CCHUNK;
  if (tid < 64) {
    int p = px0 + tid;
    if (p > NPX - 1) p = NPX - 1;
    int hw = HOUT * WOUT;
    pb[tid] = p / hw;
    int r = p % hw;
    pyA[tid] = r / WOUT;
    pxA[tid] = r % WOUT;
  }
  float acc[4][4] = {};
  const int tx = tid & 15, ty = tid >> 4;
  __syncthreads();
  for (int c0 = cbase; c0 < cbase + CCHUNK; c0 += CK) {
    {
      int oc = tid >> 2, kb = (tid & 3) * 18;
      const float* wp = w + (size_t)(oc0 + oc) * CIN * 9 + c0 * 9 + kb;
      #pragma unroll
      for (int i = 0; i < 18; ++i) Ws[kb + i][oc] = wp[i];
    }
    for (int e = tid; e < KK * 64; e += 256) {
      int kk = e >> 6, p = e & 63;
      int ci = kk / 9, tap = kk % 9, ky = tap / 3, kx = tap % 3;
      int iy = pyA[p] * 2 - 1 + ky, ix = pxA[p] * 2 - 1 + kx;
      float v = 0.f;
      if ((unsigned)iy < (unsigned)HIN && (unsigned)ix < (unsigned)WIN)
        v = x[(((size_t)pb[p] * CIN + c0 + ci) * HIN + iy) * WIN + ix];
      Xs[kk][p] = v;
    }
    __syncthreads();
    #pragma unroll 4
    for (int k = 0; k < KK; ++k) {
      float4 wv = *(const float4*)&Ws[k][ty * 4];
      float4 xv = *(const float4*)&Xs[k][tx * 4];
      float wr[4] = {wv.x, wv.y, wv.z, wv.w};
      float xr[4] = {xv.x, xv.y, xv.z, xv.w};
      #pragma unroll
      for (int i = 0; i < 4; ++i)
        #pragma unroll
        for (int j = 0; j < 4; ++j) acc[i][j] += wr[i] * xr[j];
    }
    __syncthreads();
  }
  const size_t N = (size_t)4 * COUT * HOUT * WOUT;
  #pragma unroll
  for (int i = 0; i < 4; ++i) {
    int oc = oc0 + ty * 4 + i;
    #pragma unroll
    for (int j = 0; j < 4; ++j) {
      int pidx = px0 + tx * 4 + j;
      if (pidx < NPX) {
        int t = tx * 4 + j;
        part[(size_t)spl * N + (((size_t)pb[t] * COUT + oc) * HOUT + pyA[t]) * WOUT + pxA[t]] =
            acc[i][j];
      }
    }
  }
}

// ---------------- split-K reduction + ReLU ----------------
template <int SPLIT>
__global__ __launch_bounds__(256) void k_red(const float* __restrict__ part,
                                             float* __restrict__ y, int n) {
  for (int i = blockIdx.x * 256 + threadIdx.x; i < n; i += gridDim.x * 256) {
    float s = 0.f;
    #pragma unroll
    for (int sp = 0; sp < SPLIT; ++sp) s += part[(size_t)sp * n + i];
    y[i] = fmaxf(s, 0.f);
  }
}

// ---------------- global-max-pool (7x7): one thread per (b,ch) ----------------
__global__ __launch_bounds__(256) void k_pool(const float* __restrict__ feat,
                                              float* __restrict__ pool) {
  int idx = blockIdx.x * 256 + threadIdx.x;
  if (idx >= 8192) return;
  const float* fp = feat + (size_t)idx * 49;
  float m = fp[0];
  #pragma unroll
  for (int i = 1; i < 49; ++i) m = fmaxf(m, fp[i]);
  pool[idx] = m;
}

// ---------------- FC(2048->14) + sigmoid: one block per (b,c) ----------------
__global__ __launch_bounds__(256) void k_fcsig(const float* __restrict__ pool,
                                               const float* __restrict__ fw,
                                               const float* __restrict__ fb,
                                               float* __restrict__ outp) {
  __shared__ float red[256];
  const int blk = blockIdx.x;       // b*14 + c
  const int b = blk / 14, c = blk % 14;
  const int tid = threadIdx.x;
  float s = 0.f;
  for (int k = tid; k < 2048; k += 256) s += pool[b * 2048 + k] * fw[c * 2048 + k];
  red[tid] = s;
  __syncthreads();
  for (int st = 128; st > 0; st >>= 1) {
    if (tid < st) red[tid] += red[tid + st];
    __syncthreads();
  }
  if (tid == 0) outp[b * 14 + c] = 1.f / (1.f + expf(-(red[0] + fb[c])));
}

// ---------------- heatmap stage A: per-(b,cell) channel max|.| ----------------
__global__ __launch_bounds__(256) void k_hm7a(const float* __restrict__ feat,
                                              float* __restrict__ hmr) {
  __shared__ float red[256];
  const int b = blockIdx.x / 49, cell = blockIdx.x % 49;
  const int tid = threadIdx.x;
  float m = 0.f;
  for (int ch = tid; ch < 2048; ch += 256)
    m = fmaxf(m, fabsf(feat[((size_t)b * 2048 + ch) * 49 + cell]));
  red[tid] = m;
  __syncthreads();
  for (int st = 128; st > 0; st >>= 1) {
    if (tid < st) red[tid] = fmaxf(red[tid], red[tid + st]);
    __syncthreads();
  }
  if (tid == 0) hmr[b * 49 + cell] = red[0];
}

// ---------------- heatmap stage B: per-sample min-max normalize ----------------
__global__ __launch_bounds__(64) void k_hm7b(const float* __restrict__ hmr,
                                             float* __restrict__ hm7) {
  __shared__ float h[49];
  const int b = blockIdx.x, tid = threadIdx.x;
  if (tid < 49) h[tid] = hmr[b * 49 + tid];
  __syncthreads();
  if (tid == 0) {
    float mn = h[0], mx = h[0];
    for (int i = 1; i < 49; ++i) {
      mn = fminf(mn, h[i]);
      mx = fmaxf(mx, h[i]);
    }
    for (int i = 0; i < 49; ++i) hm7[b * 49 + i] = (h[i] - mn) / (mx - mn);
  }
}

// ---------------- parallel CCL on mask runs + bbox of largest component ----------------
// FastSV: hook (neighbor min) + shortcut-to-convergence (lab[i]=lab[lab[i]] until stable).
// Labels monotone-decrease to the unique fixpoint (component-min run id) -> deterministic.
// Outer iters ~ log(#basins) (<=223 by distance bound; cap 256 unreachable). Stats via LDS
// int atomics; winner: max count, tie -> min mid (identical to verified serial semantics).
#define MAXR 8
#define NRUNS (224 * MAXR)
__global__ __launch_bounds__(256) void k_ccl(const float* __restrict__ hm7, float* __restrict__ bbox) {
  const int b = blockIdx.x, tid = threadIdx.x;
  __shared__ float h7[49];
  __shared__ short ci0[224];
  __shared__ float cf[224];
  __shared__ short rx0[NRUNS], rx1[NRUNS];
  __shared__ short nr[224];
  __shared__ int lab[NRUNS];
  __shared__ int cnt[NRUNS], mid[NRUNS];
  __shared__ int rmn[NRUNS], rmx[NRUNS], cmn[NRUNS], cmx[NRUNS];
  __shared__ int chg, chg2;
  __shared__ int bestC[256], bestM[256], bestI[256];

  if (tid < 49) h7[tid] = hm7[b * 49 + tid];
  if (tid < 224) {
    float p = ((float)tid + 0.5f) * (7.f / 224.f) - 0.5f;
    p = fminf(fmaxf(p, 0.f), 6.f);
    int i0 = (int)floorf(p);
    if (i0 > 5) i0 = 5;
    ci0[tid] = (short)i0;
    cf[tid] = p - (float)i0;
  }
  for (int i = tid; i < NRUNS; i += 256) {
    cnt[i] = 0; mid[i] = -1;
    rmn[i] = 1 << 30; rmx[i] = -1; cmn[i] = 1 << 30; cmx[i] = -1;
    lab[i] = i;
  }
  __syncthreads();
  // per-row run extraction (identical mask arithmetic to the verified version)
  if (tid < 224) {
    int yy = tid;
    int y0 = ci0[yy];
    float fy = cf[yy];
    const float* h0 = &h7[y0 * 7];
    const float* h1 = &h7[(y0 + 1) * 7];
    int n = 0, start = -1;
    for (int xx = 0; xx < 224; ++xx) {
      int x0 = ci0[xx];
      float fx = cf[xx];
      float v = (1.f - fy) * ((1.f - fx) * h0[x0] + fx * h0[x0 + 1]) +
                fy * ((1.f - fx) * h1[x0] + fx * h1[x0 + 1]);
      bool m = v > 0.7f;
      if (m && start < 0) start = xx;
      if (!m && start >= 0) {
        if (n < MAXR) { rx0[yy * MAXR + n] = (short)start; rx1[yy * MAXR + n] = (short)(xx - 1); n++; }
        start = -1;
      }
    }
    if (start >= 0 && n < MAXR) { rx0[yy * MAXR + n] = (short)start; rx1[yy * MAXR + n] = 223; n++; }
    nr[yy] = (short)n;
  }
  __syncthreads();
  // preload own slots into registers (constant across iterations)
  int myA0[7], myA1[7];
  bool myV[7];
  #pragma unroll
  for (int j = 0; j < 7; ++j) {
    int i = tid + j * 256;
    int yy = i >> 3, k = i & 7;
    bool v = (k < (int)nr[yy]);
    myV[j] = v;
    myA0[j] = v ? (int)rx0[i] : 0;
    myA1[j] = v ? (int)rx1[i] : 0;
  }
  // hook + shortcut-to-convergence
  for (int outer = 0; outer < 256; ++outer) {
    if (tid == 0) chg = 0;
    __syncthreads();
    bool any = false;
    #pragma unroll
    for (int j = 0; j < 7; ++j) {
      if (!myV[j]) continue;
      int i = tid + j * 256;
      int yy = i >> 3;
      int a0 = myA0[j], a1 = myA1[j];
      int m = lab[i];
      if (yy > 0) {
        int n1 = nr[yy - 1];
        for (int kk = 0; kk < n1; ++kk) {
          int q = ((yy - 1) << 3) + kk;
          if (a0 <= rx1[q] + 1 && a1 >= rx0[q] - 1) { int l = lab[q]; if (l < m) m = l; }
        }
      }
      if (yy < 223) {
        int n1 = nr[yy + 1];
        for (int kk = 0; kk < n1; ++kk) {
          int q = ((yy + 1) << 3) + kk;
          if (a0 <= rx1[q] + 1 && a1 >= rx0[q] - 1) { int l = lab[q]; if (l < m) m = l; }
        }
      }
      if (m < lab[i]) { lab[i] = m; any = true; }
    }
    if (any) chg = 1;
    __syncthreads();
    if (!chg) break;
    // shortcut until stable (chain halves per pass; <= log2(NRUNS) ~ 11, cap 16)
    for (int sc = 0; sc < 16; ++sc) {
      if (tid == 0) chg2 = 0;
      __syncthreads();
      bool a2 = false;
      #pragma unroll
      for (int j = 0; j < 7; ++j) {
        int i = tid + j * 256;
        int l = lab[i];
        int l2 = lab[l];
        if (l2 < l) { lab[i] = l2; a2 = true; }
      }
      if (a2) chg2 = 1;
      __syncthreads();
      if (!chg2) break;
    }
  }
  // component stats via LDS atomics (ints -> exact, deterministic)
  for (int i = tid; i < NRUNS; i += 256) {
    int yy = i >> 3, k = i & 7;
    if (k >= (int)nr[yy]) continue;
    int r = lab[i];
    int a0 = rx0[i], a1 = rx1[i];
    atomicAdd(&cnt[r], a1 - a0 + 1);
    atomicMax(&mid[r], yy * 224 + a1 + 1);
    atomicMin(&rmn[r], yy);
    atomicMax(&rmx[r], yy);
    atomicMin(&cmn[r], a0);
    atomicMax(&cmx[r], a1);
  }
  __syncthreads();
  // winner: max count, tie -> min mid
  int bc = -1, bm = 0x7fffffff, bi = -1;
  for (int i = tid; i < NRUNS; i += 256) {
    if (cnt[i] > 0 && lab[i] == i) {
      if (cnt[i] > bc || (cnt[i] == bc && mid[i] < bm)) { bc = cnt[i]; bm = mid[i]; bi = i; }
    }
  }
  bestC[tid] = bc; bestM[tid] = bm; bestI[tid] = bi;
  __syncthreads();
  for (int st = 128; st > 0; st >>= 1) {
    if (tid < st) {
      if (bestC[tid + st] > bestC[tid] ||
          (bestC[tid + st] == bestC[tid] && bestM[tid + st] < bestM[tid])) {
        bestC[tid] = bestC[tid + st]; bestM[tid] = bestM[tid + st]; bestI[tid] = bestI[tid + st];
      }
    }
    __syncthreads();
  }
  if (tid == 0) {
    int bw = bestI[0];
    float fy0, chf, fx0, cwf;
    if (bw < 0) { fy0 = 224.f; chf = 1.f; fx0 = 224.f; cwf = 1.f; }
    else {
      int dr = rmx[bw] - rmn[bw]; if (dr < 1) dr = 1;
      int dc = cmx[bw] - cmn[bw]; if (dc < 1) dc = 1;
      fy0 = (float)rmn[bw]; chf = (float)dr;
      fx0 = (float)cmn[bw]; cwf = (float)dc;
    }
    bbox[b * 4 + 0] = fy0; bbox[b * 4 + 1] = chf;
    bbox[b * 4 + 2] = fx0; bbox[b * 4 + 3] = cwf;
  }
}

// ---------------- bilinear crop-resize back to 224x224 ----------------
__global__ __launch_bounds__(256) void k_sample(const float* __restrict__ img,
                                                const float* __restrict__ bbox,
                                                float* __restrict__ patch_out,
                                                float* __restrict__ patch_ws) {
  int idx = blockIdx.x * 256 + threadIdx.x;
  if (idx >= 4 * 3 * 224 * 224) return;
  int b = idx / (3 * 224 * 224);
  int r = idx % (3 * 224 * 224);
  int c = r / (224 * 224);
  int p = r % (224 * 224);
  int oy = p / 224, ox = p % 224;
  float fy0 = bbox[b * 4 + 0], chf = bbox[b * 4 + 1];
  float fx0 = bbox[b * 4 + 2], cwf = bbox[b * 4 + 3];
  float gy = ((float)oy + 0.5f) * (chf / 224.f) + fy0 - 0.5f;
  float gx = ((float)ox + 0.5f) * (cwf / 224.f) + fx0 - 0.5f;
  gy = fminf(fmaxf(gy, fy0), fmaxf(fy0 + chf - 1.f, fy0));
  gx = fminf(fmaxf(gx, fx0), fmaxf(fx0 + cwf - 1.f, fx0));
  int y0 = (int)floorf(gy);
  int x0 = (int)floorf(gx);
  float fy = gy - (float)y0, fx = gx - (float)x0;
  int y0c = min(max(y0, 0), 223), y1c = min(max(y0 + 1, 0), 223);
  int x0c = min(max(x0, 0), 223), x1c = min(max(x0 + 1, 0), 223);
  const float* ip = img + ((size_t)b * 3 + c) * 224 * 224;
  float v00 = ip[y0c * 224 + x0c], v01 = ip[y0c * 224 + x1c];
  float v10 = ip[y1c * 224 + x0c], v11 = ip[y1c * 224 + x1c];
  float v = (1.f - fy) * ((1.f - fx) * v00 + fx * v01) + fy * ((1.f - fx) * v10 + fx * v11);
  patch_out[idx] = v;
  patch_ws[idx] = v;
}

// ---------------- out_f = sigmoid([pool_g|pool_l] @ fw.T + fb); loss = weighted BCEs ----------------
__global__ __launch_bounds__(256) void k_final(const float* __restrict__ poolg,
                                               const float* __restrict__ pooll,
                                               const float* __restrict__ fw,
                                               const float* __restrict__ fb,
                                               const float* __restrict__ target,
                                               float* __restrict__ dout) {
  __shared__ float outf[56];
  __shared__ float red[256];
  const int tid = threadIdx.x;
  int pair = tid >> 2, l4 = tid & 3;
  if (pair < 56) {
    int bb = pair / 14, c = pair % 14;
    const float* w = fw + (size_t)c * 4096;
    float s = 0.f;
    for (int k = l4; k < 2048; k += 4) s += poolg[bb * 2048 + k] * w[k];
    for (int k = l4; k < 2048; k += 4) s += pooll[bb * 2048 + k] * w[2048 + k];
    s += __shfl_down(s, 2, 4);
    s += __shfl_down(s, 1, 4);
    if (l4 == 0) {
      float o = 1.f / (1.f + expf(-(s + fb[c])));
      outf[pair] = o;
      dout[113 + pair] = o;
    }
  }
  __syncthreads();
  float term = 0.f;
  if (tid < 56) {
    float t = target[tid];
    float pg = dout[1 + tid], plo = dout[57 + tid], pf = outf[tid];
    auto bce1 = [&](float pp) {
      pp = fminf(fmaxf(pp, 1e-7f), 1.f - 1e-7f);
      return -(t * logf(pp) + (1.f - t) * log1pf(-pp));
    };
    term = (0.8f * bce1(pg) + 0.1f * bce1(plo) + 0.1f * bce1(pf)) * (1.f / 56.f);
  }
  red[tid] = term;
  __syncthreads();
  for (int st = 128; st > 0; st >>= 1) {
    if (tid < st) red[tid] += red[tid + st];
    __syncthreads();
  }
  if (tid == 0) dout[0] = red[0];
}

extern "C" void kernel_launch(void* const* d_in, const int* in_sizes, int n_in,
                              void* d_out, int out_size, void* d_ws, size_t ws_size,
                              hipStream_t stream) {
  const float* img = (const float*)d_in[0];
  const float* target = (const float*)d_in[1];
  const float* gw0 = (const float*)d_in[2];
  const float* gw1 = (const float*)d_in[3];
  const float* gw2 = (const float*)d_in[4];
  const float* gw3 = (const float*)d_in[5];
  const float* gfw = (const float*)d_in[6];
  const float* gfb = (const float*)d_in[7];
  const float* lw0 = (const float*)d_in[8];
  const float* lw1 = (const float*)d_in[9];
  const float* lw2 = (const float*)d_in[10];
  const float* lw3 = (const float*)d_in[11];
  const float* lfw = (const float*)d_in[12];
  const float* lfb = (const float*)d_in[13];
  const float* fw = (const float*)d_in[14];
  const float* fb = (const float*)d_in[15];
  float* out = (float*)d_out;
  float* ws = (float*)d_ws;

  float* c1 = ws;                    // 802816   [4,64,56,56]
  float* c2 = c1 + 802816;           // 1605632  [4,512,28,28]
  float* c3 = c2 + 1605632;          // 802816   [4,1024,14,14]
  float* c4 = c3 + 802816;           // 401408   [4,2048,7,7]
  float* poolg = c4 + 401408;        // 8192
  float* pooll = poolg + 8192;       // 8192
  float* hm7 = pooll + 8192;         // 196
  float* hmr = hm7 + 196;            // 196
  float* bbox = hmr + 196;           // 16
  float* patch = ws + 3629568;       // 602112 (16B aligned)
  float* part = ws + 4231680;        // 3211264 split-K partials (29.8 MB total ws)

  dim3 g7(13, 256);
  const int rg2 = 2048, rg3 = 2048, rg4 = 1568;  // k_red grids (grid-stride)

  // ---- global backbone ----
  k_conv7<<<g7, 256, 0, stream>>>(img, gw0, c1);
  k_conv3s<64, 56, 56, 512, 28, 28, 2><<<dim3(49, 8, 2), 256, 0, stream>>>(c1, gw1, part);
  k_red<2><<<rg2, 256, 0, stream>>>(part, c2, 1605632);
  k_conv3s<512, 28, 28, 1024, 14, 14, 4><<<dim3(13, 16, 4), 256, 0, stream>>>(c2, gw2, part);
  k_red<4><<<rg3, 256, 0, stream>>>(part, c3, 802816);
  k_conv3s<1024, 14, 14, 2048, 7, 7, 8><<<dim3(4, 32, 8), 256, 0, stream>>>(c3, gw3, part);
  k_red<8><<<rg4, 256, 0, stream>>>(part, c4, 401408);
  k_pool<<<32, 256, 0, stream>>>(c4, poolg);
  k_fcsig<<<56, 256, 0, stream>>>(poolg, gfw, gfb, out + 1);
  // ---- attention patch generation ----
  k_hm7a<<<196, 256, 0, stream>>>(c4, hmr);
  k_hm7b<<<4, 64, 0, stream>>>(hmr, hm7);
  k_ccl<<<4, 256, 0, stream>>>(hm7, bbox);
  k_sample<<<2352, 256, 0, stream>>>(img, bbox, out + 169, patch);
  // ---- local backbone ----
  k_conv7<<<g7, 256, 0, stream>>>(patch, lw0, c1);
  k_conv3s<64, 56, 56, 512, 28, 28, 2><<<dim3(49, 8, 2), 256, 0, stream>>>(c1, lw1, part);
  k_red<2><<<rg2, 256, 0, stream>>>(part, c2, 1605632);
  k_conv3s<512, 28, 28, 1024, 14, 14, 4><<<dim3(13, 16, 4), 256, 0, stream>>>(c2, lw2, part);
  k_red<4><<<rg3, 256, 0, stream>>>(part, c3, 802816);
  k_conv3s<1024, 14, 14, 2048, 7, 7, 8><<<dim3(4, 32, 8), 256, 0, stream>>>(c3, lw3, part);
  k_red<8><<<rg4, 256, 0, stream>>>(part, c4, 401408);
  k_pool<<<32, 256, 0, stream>>>(c4, pooll);
  k_fcsig<<<56, 256, 0, stream>>>(pooll, lfw, lfb, out + 57);
  // ---- fusion + losses ----
  k_final<<<1, 256, 0, stream>>>(poolg, pooll, fw, fb, target, out);
}

// Round 9
// 1330.401 us; speedup vs baseline: 2.9941x; 1.1910x over previous
//
#include <hip/hip_runtime.h>
#include <math.h>

// ---------------- conv 7x7 stride4 pad3, Cin=3, 224->56, fused ReLU ----------------
__global__ __launch_bounds__(256) void k_conv7(const float* __restrict__ x,
                                               const float* __restrict__ w,
                                               float* __restrict__ y) {
  __shared__ float ws[147];
  const int boc = blockIdx.y;              // b*64 + oc
  const int oc = boc & 63;
  const int b = boc >> 6;
  for (int i = threadIdx.x; i < 147; i += 256) ws[i] = w[oc * 147 + i];
  __syncthreads();
  int px = blockIdx.x * 256 + threadIdx.x;
  if (px >= 56 * 56) return;
  int oy = px / 56, ox = px % 56;
  int iy0 = oy * 4 - 3, ix0 = ox * 4 - 3;
  float acc = 0.f;
  for (int c = 0; c < 3; ++c) {
    const float* xp = x + ((size_t)(b * 3 + c)) * 224 * 224;
    #pragma unroll
    for (int ky = 0; ky < 7; ++ky) {
      int iy = iy0 + ky;
      if ((unsigned)iy < 224u) {
        #pragma unroll
        for (int kx = 0; kx < 7; ++kx) {
          int ix = ix0 + kx;
          if ((unsigned)ix < 224u)
            acc += xp[iy * 224 + ix] * ws[c * 49 + ky * 7 + kx];
        }
      }
    }
  }
  y[((size_t)boc * 56 + oy) * 56 + ox] = fmaxf(acc, 0.f);
}

// ---------------- generic 3x3 stride2 pad1 conv, f32, split-K partials ----------------
template <int CIN, int HIN, int WIN, int COUT, int HOUT, int WOUT, int SPLIT>
__global__ __launch_bounds__(256) void k_conv3s(const float* __restrict__ x,
                                                const float* __restrict__ w,
                                                float* __restrict__ part) {
  constexpr int NPX = 4 * HOUT * WOUT;
  constexpr int CK = 8, KK = CK * 9, LDSW = 68;
  constexpr int CCHUNK = CIN / SPLIT;
  __shared__ float Ws[KK][LDSW];
  __shared__ float Xs[KK][LDSW];
  __shared__ int pb[64], pyA[64], pxA[64];
  const int tid = threadIdx.x;
  const int oc0 = blockIdx.y * 64, px0 = blockIdx.x * 64;
  const int spl = blockIdx.z;
  const int cbase = spl * CCHUNK;
  if (tid < 64) {
    int p = px0 + tid;
    if (p > NPX - 1) p = NPX - 1;
    int hw = HOUT * WOUT;
    pb[tid] = p / hw;
    int r = p % hw;
    pyA[tid] = r / WOUT;
    pxA[tid] = r % WOUT;
  }
  float acc[4][4] = {};
  const int tx = tid & 15, ty = tid >> 4;
  __syncthreads();
  for (int c0 = cbase; c0 < cbase + CCHUNK; c0 += CK) {
    {
      int oc = tid >> 2, kb = (tid & 3) * 18;
      const float* wp = w + (size_t)(oc0 + oc) * CIN * 9 + c0 * 9 + kb;
      #pragma unroll
      for (int i = 0; i < 18; ++i) Ws[kb + i][oc] = wp[i];
    }
    for (int e = tid; e < KK * 64; e += 256) {
      int kk = e >> 6, p = e & 63;
      int ci = kk / 9, tap = kk % 9, ky = tap / 3, kx = tap % 3;
      int iy = pyA[p] * 2 - 1 + ky, ix = pxA[p] * 2 - 1 + kx;
      float v = 0.f;
      if ((unsigned)iy < (unsigned)HIN && (unsigned)ix < (unsigned)WIN)
        v = x[(((size_t)pb[p] * CIN + c0 + ci) * HIN + iy) * WIN + ix];
      Xs[kk][p] = v;
    }
    __syncthreads();
    #pragma unroll 4
    for (int k = 0; k < KK; ++k) {
      float4 wv = *(const float4*)&Ws[k][ty * 4];
      float4 xv = *(const float4*)&Xs[k][tx * 4];
      float wr[4] = {wv.x, wv.y, wv.z, wv.w};
      float xr[4] = {xv.x, xv.y, xv.z, xv.w};
      #pragma unroll
      for (int i = 0; i < 4; ++i)
        #pragma unroll
        for (int j = 0; j < 4; ++j) acc[i][j] += wr[i] * xr[j];
    }
    __syncthreads();
  }
  const size_t N = (size_t)4 * COUT * HOUT * WOUT;
  #pragma unroll
  for (int i = 0; i < 4; ++i) {
    int oc = oc0 + ty * 4 + i;
    #pragma unroll
    for (int j = 0; j < 4; ++j) {
      int pidx = px0 + tx * 4 + j;
      if (pidx < NPX) {
        int t = tx * 4 + j;
        part[(size_t)spl * N + (((size_t)pb[t] * COUT + oc) * HOUT + pyA[t]) * WOUT + pxA[t]] =
            acc[i][j];
      }
    }
  }
}

// ---------------- split-K reduction + ReLU ----------------
template <int SPLIT>
__global__ __launch_bounds__(256) void k_red(const float* __restrict__ part,
                                             float* __restrict__ y, int n) {
  for (int i = blockIdx.x * 256 + threadIdx.x; i < n; i += gridDim.x * 256) {
    float s = 0.f;
    #pragma unroll
    for (int sp = 0; sp < SPLIT; ++sp) s += part[(size_t)sp * n + i];
    y[i] = fmaxf(s, 0.f);
  }
}

// ---------------- global-max-pool (7x7): one thread per (b,ch) ----------------
__global__ __launch_bounds__(256) void k_pool(const float* __restrict__ feat,
                                              float* __restrict__ pool) {
  int idx = blockIdx.x * 256 + threadIdx.x;
  if (idx >= 8192) return;
  const float* fp = feat + (size_t)idx * 49;
  float m = fp[0];
  #pragma unroll
  for (int i = 1; i < 49; ++i) m = fmaxf(m, fp[i]);
  pool[idx] = m;
}

// ---------------- FC(2048->14) + sigmoid: one block per (b,c) ----------------
__global__ __launch_bounds__(256) void k_fcsig(const float* __restrict__ pool,
                                               const float* __restrict__ fw,
                                               const float* __restrict__ fb,
                                               float* __restrict__ outp) {
  __shared__ float red[256];
  const int blk = blockIdx.x;       // b*14 + c
  const int b = blk / 14, c = blk % 14;
  const int tid = threadIdx.x;
  float s = 0.f;
  for (int k = tid; k < 2048; k += 256) s += pool[b * 2048 + k] * fw[c * 2048 + k];
  red[tid] = s;
  __syncthreads();
  for (int st = 128; st > 0; st >>= 1) {
    if (tid < st) red[tid] += red[tid + st];
    __syncthreads();
  }
  if (tid == 0) outp[b * 14 + c] = 1.f / (1.f + expf(-(red[0] + fb[c])));
}

// ---------------- heatmap stage A: per-(b,cell) channel max|.| ----------------
__global__ __launch_bounds__(256) void k_hm7a(const float* __restrict__ feat,
                                              float* __restrict__ hmr) {
  __shared__ float red[256];
  const int b = blockIdx.x / 49, cell = blockIdx.x % 49;
  const int tid = threadIdx.x;
  float m = 0.f;
  for (int ch = tid; ch < 2048; ch += 256)
    m = fmaxf(m, fabsf(feat[((size_t)b * 2048 + ch) * 49 + cell]));
  red[tid] = m;
  __syncthreads();
  for (int st = 128; st > 0; st >>= 1) {
    if (tid < st) red[tid] = fmaxf(red[tid], red[tid + st]);
    __syncthreads();
  }
  if (tid == 0) hmr[b * 49 + cell] = red[0];
}

// ---------------- heatmap stage B: per-sample min-max normalize ----------------
__global__ __launch_bounds__(64) void k_hm7b(const float* __restrict__ hmr,
                                             float* __restrict__ hm7) {
  __shared__ float h[49];
  const int b = blockIdx.x, tid = threadIdx.x;
  if (tid < 49) h[tid] = hmr[b * 49 + tid];
  __syncthreads();
  if (tid == 0) {
    float mn = h[0], mx = h[0];
    for (int i = 1; i < 49; ++i) {
      mn = fminf(mn, h[i]);
      mx = fmaxf(mx, h[i]);
    }
    for (int i = 0; i < 49; ++i) hm7[b * 49 + i] = (h[i] - mn) / (mx - mn);
  }
}

// ---------------- parallel CCL on mask runs + bbox of largest component ----------------
// Extraction: per-row, 6 static column-segments (ci0/cf are exact f32 functions of xx;
// 7/224 = 1/32), h-corners hoisted to registers -> pure-ALU pixel loop, same f32 expression.
// Union: root-hooking Shiloach-Vishkin: atomicMin(&lab[root], otherRoot) + compression to
// stability. Collapses root chains in one outer -> O(log) outers. Monotone lattice ->
// unique fixpoint (component-min id) -> deterministic. Stats/winner identical semantics.
#define MAXR 8
#define NRUNS (224 * MAXR)
__global__ __launch_bounds__(256) void k_ccl(const float* __restrict__ hm7, float* __restrict__ bbox) {
  const int b = blockIdx.x, tid = threadIdx.x;
  __shared__ float h7[49];
  __shared__ short rx0[NRUNS], rx1[NRUNS];
  __shared__ short nr[224];
  __shared__ int lab[NRUNS];
  __shared__ int cnt[NRUNS], mid[NRUNS];
  __shared__ int rmn[NRUNS], rmx[NRUNS], cmn[NRUNS], cmx[NRUNS];
  __shared__ int chg, chg2;
  __shared__ int bestC[256], bestM[256], bestI[256];

  if (tid < 49) h7[tid] = hm7[b * 49 + tid];
  for (int i = tid; i < NRUNS; i += 256) {
    cnt[i] = 0; mid[i] = -1;
    rmn[i] = 1 << 30; rmx[i] = -1; cmn[i] = 1 << 30; cmx[i] = -1;
    lab[i] = i;
  }
  __syncthreads();
  // per-row run extraction: 6 unrolled segments, register h-corners, ALU-only px/fx
  if (tid < 224) {
    int yy = tid;
    float py = ((float)yy + 0.5f) * (7.f / 224.f) - 0.5f;
    py = fminf(fmaxf(py, 0.f), 6.f);
    int y0 = (int)floorf(py);
    if (y0 > 5) y0 = 5;
    float fy = py - (float)y0;
    int n = 0, start = -1;
    const int segLo[6] = {0, 48, 80, 112, 144, 176};
    const int segHi[6] = {48, 80, 112, 144, 176, 224};
    #pragma unroll
    for (int s = 0; s < 6; ++s) {
      float A = h7[y0 * 7 + s], B = h7[y0 * 7 + s + 1];
      float C = h7[(y0 + 1) * 7 + s], D = h7[(y0 + 1) * 7 + s + 1];
      for (int xx = segLo[s]; xx < segHi[s]; ++xx) {
        float px = ((float)xx + 0.5f) * (7.f / 224.f) - 0.5f;
        px = fminf(fmaxf(px, 0.f), 6.f);
        float fx = px - (float)s;
        float v = (1.f - fy) * ((1.f - fx) * A + fx * B) +
                  fy * ((1.f - fx) * C + fx * D);
        bool m = v > 0.7f;
        if (m && start < 0) start = xx;
        if (!m && start >= 0) {
          if (n < MAXR) { rx0[yy * MAXR + n] = (short)start; rx1[yy * MAXR + n] = (short)(xx - 1); n++; }
          start = -1;
        }
      }
    }
    if (start >= 0 && n < MAXR) { rx0[yy * MAXR + n] = (short)start; rx1[yy * MAXR + n] = 223; n++; }
    nr[yy] = (short)n;
  }
  __syncthreads();
  // preload own slots into registers
  int myA0[7], myA1[7];
  bool myV[7];
  #pragma unroll
  for (int j = 0; j < 7; ++j) {
    int i = tid + j * 256;
    int yy = i >> 3, k = i & 7;
    bool v = (k < (int)nr[yy]);
    myV[j] = v;
    myA0[j] = v ? (int)rx0[i] : 0;
    myA1[j] = v ? (int)rx1[i] : 0;
  }
  // root-hooking SV: hook(atomicMin on roots) + compress-to-stability; O(log) outers
  for (int outer = 0; outer < 48; ++outer) {
    if (tid == 0) chg = 0;
    __syncthreads();
    bool any = false;
    #pragma unroll
    for (int j = 0; j < 7; ++j) {
      if (!myV[j]) continue;
      int i = tid + j * 256;
      int yy = i >> 3;
      int a0 = myA0[j], a1 = myA1[j];
      int ri = lab[i];
      if (yy > 0) {
        int n1 = nr[yy - 1];
        for (int kk = 0; kk < n1; ++kk) {
          int q = ((yy - 1) << 3) + kk;
          if (a0 <= rx1[q] + 1 && a1 >= rx0[q] - 1) {
            int rq = lab[q];
            if (rq < ri) { atomicMin(&lab[ri], rq); any = true; }
            else if (ri < rq) { atomicMin(&lab[rq], ri); any = true; }
          }
        }
      }
      if (yy < 223) {
        int n1 = nr[yy + 1];
        for (int kk = 0; kk < n1; ++kk) {
          int q = ((yy + 1) << 3) + kk;
          if (a0 <= rx1[q] + 1 && a1 >= rx0[q] - 1) {
            int rq = lab[q];
            if (rq < ri) { atomicMin(&lab[ri], rq); any = true; }
            else if (ri < rq) { atomicMin(&lab[rq], ri); any = true; }
          }
        }
      }
    }
    if (any) chg = 1;
    __syncthreads();
    // compression to stability (<= log2(NRUNS) ~ 11 passes, early exit)
    for (int sc = 0; sc < 12; ++sc) {
      if (tid == 0) chg2 = 0;
      __syncthreads();
      bool a2 = false;
      #pragma unroll
      for (int j = 0; j < 7; ++j) {
        int i = tid + j * 256;
        int l = lab[i];
        int l2 = lab[l];
        if (l2 < l) { lab[i] = l2; a2 = true; }
      }
      if (a2) chg2 = 1;
      __syncthreads();
      if (!chg2) break;
    }
    if (!chg) break;
  }
  // component stats via LDS atomics (ints -> exact, deterministic)
  for (int i = tid; i < NRUNS; i += 256) {
    int yy = i >> 3, k = i & 7;
    if (k >= (int)nr[yy]) continue;
    int r = lab[i];
    int a0 = rx0[i], a1 = rx1[i];
    atomicAdd(&cnt[r], a1 - a0 + 1);
    atomicMax(&mid[r], yy * 224 + a1 + 1);
    atomicMin(&rmn[r], yy);
    atomicMax(&rmx[r], yy);
    atomicMin(&cmn[r], a0);
    atomicMax(&cmx[r], a1);
  }
  __syncthreads();
  // winner: max count, tie -> min mid
  int bc = -1, bm = 0x7fffffff, bi = -1;
  for (int i = tid; i < NRUNS; i += 256) {
    if (cnt[i] > 0 && lab[i] == i) {
      if (cnt[i] > bc || (cnt[i] == bc && mid[i] < bm)) { bc = cnt[i]; bm = mid[i]; bi = i; }
    }
  }
  bestC[tid] = bc; bestM[tid] = bm; bestI[tid] = bi;
  __syncthreads();
  for (int st = 128; st > 0; st >>= 1) {
    if (tid < st) {
      if (bestC[tid + st] > bestC[tid] ||
          (bestC[tid + st] == bestC[tid] && bestM[tid + st] < bestM[tid])) {
        bestC[tid] = bestC[tid + st]; bestM[tid] = bestM[tid + st]; bestI[tid] = bestI[tid + st];
      }
    }
    __syncthreads();
  }
  if (tid == 0) {
    int bw = bestI[0];
    float fy0, chf, fx0, cwf;
    if (bw < 0) { fy0 = 224.f; chf = 1.f; fx0 = 224.f; cwf = 1.f; }
    else {
      int dr = rmx[bw] - rmn[bw]; if (dr < 1) dr = 1;
      int dc = cmx[bw] - cmn[bw]; if (dc < 1) dc = 1;
      fy0 = (float)rmn[bw]; chf = (float)dr;
      fx0 = (float)cmn[bw]; cwf = (float)dc;
    }
    bbox[b * 4 + 0] = fy0; bbox[b * 4 + 1] = chf;
    bbox[b * 4 + 2] = fx0; bbox[b * 4 + 3] = cwf;
  }
}

// ---------------- bilinear crop-resize back to 224x224 ----------------
__global__ __launch_bounds__(256) void k_sample(const float* __restrict__ img,
                                                const float* __restrict__ bbox,
                                                float* __restrict__ patch_out,
                                                float* __restrict__ patch_ws) {
  int idx = blockIdx.x * 256 + threadIdx.x;
  if (idx >= 4 * 3 * 224 * 224) return;
  int b = idx / (3 * 224 * 224);
  int r = idx % (3 * 224 * 224);
  int c = r / (224 * 224);
  int p = r % (224 * 224);
  int oy = p / 224, ox = p % 224;
  float fy0 = bbox[b * 4 + 0], chf = bbox[b * 4 + 1];
  float fx0 = bbox[b * 4 + 2], cwf = bbox[b * 4 + 3];
  float gy = ((float)oy + 0.5f) * (chf / 224.f) + fy0 - 0.5f;
  float gx = ((float)ox + 0.5f) * (cwf / 224.f) + fx0 - 0.5f;
  gy = fminf(fmaxf(gy, fy0), fmaxf(fy0 + chf - 1.f, fy0));
  gx = fminf(fmaxf(gx, fx0), fmaxf(fx0 + cwf - 1.f, fx0));
  int y0 = (int)floorf(gy);
  int x0 = (int)floorf(gx);
  float fy = gy - (float)y0, fx = gx - (float)x0;
  int y0c = min(max(y0, 0), 223), y1c = min(max(y0 + 1, 0), 223);
  int x0c = min(max(x0, 0), 223), x1c = min(max(x0 + 1, 0), 223);
  const float* ip = img + ((size_t)b * 3 + c) * 224 * 224;
  float v00 = ip[y0c * 224 + x0c], v01 = ip[y0c * 224 + x1c];
  float v10 = ip[y1c * 224 + x0c], v11 = ip[y1c * 224 + x1c];
  float v = (1.f - fy) * ((1.f - fx) * v00 + fx * v01) + fy * ((1.f - fx) * v10 + fx * v11);
  patch_out[idx] = v;
  patch_ws[idx] = v;
}

// ---------------- out_f = sigmoid([pool_g|pool_l] @ fw.T + fb); loss = weighted BCEs ----------------
__global__ __launch_bounds__(256) void k_final(const float* __restrict__ poolg,
                                               const float* __restrict__ pooll,
                                               const float* __restrict__ fw,
                                               const float* __restrict__ fb,
                                               const float* __restrict__ target,
                                               float* __restrict__ dout) {
  __shared__ float outf[56];
  __shared__ float red[256];
  const int tid = threadIdx.x;
  int pair = tid >> 2, l4 = tid & 3;
  if (pair < 56) {
    int bb = pair / 14, c = pair % 14;
    const float* w = fw + (size_t)c * 4096;
    float s = 0.f;
    for (int k = l4; k < 2048; k += 4) s += poolg[bb * 2048 + k] * w[k];
    for (int k = l4; k < 2048; k += 4) s += pooll[bb * 2048 + k] * w[2048 + k];
    s += __shfl_down(s, 2, 4);
    s += __shfl_down(s, 1, 4);
    if (l4 == 0) {
      float o = 1.f / (1.f + expf(-(s + fb[c])));
      outf[pair] = o;
      dout[113 + pair] = o;
    }
  }
  __syncthreads();
  float term = 0.f;
  if (tid < 56) {
    float t = target[tid];
    float pg = dout[1 + tid], plo = dout[57 + tid], pf = outf[tid];
    auto bce1 = [&](float pp) {
      pp = fminf(fmaxf(pp, 1e-7f), 1.f - 1e-7f);
      return -(t * logf(pp) + (1.f - t) * log1pf(-pp));
    };
    term = (0.8f * bce1(pg) + 0.1f * bce1(plo) + 0.1f * bce1(pf)) * (1.f / 56.f);
  }
  red[tid] = term;
  __syncthreads();
  for (int st = 128; st > 0; st >>= 1) {
    if (tid < st) red[tid] += red[tid + st];
    __syncthreads();
  }
  if (tid == 0) dout[0] = red[0];
}

extern "C" void kernel_launch(void* const* d_in, const int* in_sizes, int n_in,
                              void* d_out, int out_size, void* d_ws, size_t ws_size,
                              hipStream_t stream) {
  const float* img = (const float*)d_in[0];
  const float* target = (const float*)d_in[1];
  const float* gw0 = (const float*)d_in[2];
  const float* gw1 = (const float*)d_in[3];
  const float* gw2 = (const float*)d_in[4];
  const float* gw3 = (const float*)d_in[5];
  const float* gfw = (const float*)d_in[6];
  const float* gfb = (const float*)d_in[7];
  const float* lw0 = (const float*)d_in[8];
  const float* lw1 = (const float*)d_in[9];
  const float* lw2 = (const float*)d_in[10];
  const float* lw3 = (const float*)d_in[11];
  const float* lfw = (const float*)d_in[12];
  const float* lfb = (const float*)d_in[13];
  const float* fw = (const float*)d_in[14];
  const float* fb = (const float*)d_in[15];
  float* out = (float*)d_out;
  float* ws = (float*)d_ws;

  float* c1 = ws;                    // 802816   [4,64,56,56]
  float* c2 = c1 + 802816;           // 1605632  [4,512,28,28]
  float* c3 = c2 + 1605632;          // 802816   [4,1024,14,14]
  float* c4 = c3 + 802816;           // 401408   [4,2048,7,7]
  float* poolg = c4 + 401408;        // 8192
  float* pooll = poolg + 8192;       // 8192
  float* hm7 = pooll + 8192;         // 196
  float* hmr = hm7 + 196;            // 196
  float* bbox = hmr + 196;           // 16
  float* patch = ws + 3629568;       // 602112 (16B aligned)
  float* part = ws + 4231680;        // 3211264 split-K partials (29.8 MB total ws)

  dim3 g7(13, 256);
  const int rg2 = 2048, rg3 = 2048, rg4 = 1568;  // k_red grids (grid-stride)

  // ---- global backbone ----
  k_conv7<<<g7, 256, 0, stream>>>(img, gw0, c1);
  k_conv3s<64, 56, 56, 512, 28, 28, 2><<<dim3(49, 8, 2), 256, 0, stream>>>(c1, gw1, part);
  k_red<2><<<rg2, 256, 0, stream>>>(part, c2, 1605632);
  k_conv3s<512, 28, 28, 1024, 14, 14, 4><<<dim3(13, 16, 4), 256, 0, stream>>>(c2, gw2, part);
  k_red<4><<<rg3, 256, 0, stream>>>(part, c3, 802816);
  k_conv3s<1024, 14, 14, 2048, 7, 7, 8><<<dim3(4, 32, 8), 256, 0, stream>>>(c3, gw3, part);
  k_red<8><<<rg4, 256, 0, stream>>>(part, c4, 401408);
  k_pool<<<32, 256, 0, stream>>>(c4, poolg);
  k_fcsig<<<56, 256, 0, stream>>>(poolg, gfw, gfb, out + 1);
  // ---- attention patch generation ----
  k_hm7a<<<196, 256, 0, stream>>>(c4, hmr);
  k_hm7b<<<4, 64, 0, stream>>>(hmr, hm7);
  k_ccl<<<4, 256, 0, stream>>>(hm7, bbox);
  k_sample<<<2352, 256, 0, stream>>>(img, bbox, out + 169, patch);
  // ---- local backbone ----
  k_conv7<<<g7, 256, 0, stream>>>(patch, lw0, c1);
  k_conv3s<64, 56, 56, 512, 28, 28, 2><<<dim3(49, 8, 2), 256, 0, stream>>>(c1, lw1, part);
  k_red<2><<<rg2, 256, 0, stream>>>(part, c2, 1605632);
  k_conv3s<512, 28, 28, 1024, 14, 14, 4><<<dim3(13, 16, 4), 256, 0, stream>>>(c2, lw2, part);
  k_red<4><<<rg3, 256, 0, stream>>>(part, c3, 802816);
  k_conv3s<1024, 14, 14, 2048, 7, 7, 8><<<dim3(4, 32, 8), 256, 0, stream>>>(c3, lw3, part);
  k_red<8><<<rg4, 256, 0, stream>>>(part, c4, 401408);
  k_pool<<<32, 256, 0, stream>>>(c4, pooll);
  k_fcsig<<<56, 256, 0, stream>>>(pooll, lfw, lfb, out + 57);
  // ---- fusion + losses ----
  k_final<<<1, 256, 0, stream>>>(poolg, pooll, fw, fb, target, out);
}

// Round 10
// 1251.295 us; speedup vs baseline: 3.1834x; 1.0632x over previous
//
#include <hip/hip_runtime.h>
#include <math.h>

typedef __attribute__((ext_vector_type(8))) short short8m;   // 8 bf16 (4 VGPRs)
typedef __attribute__((ext_vector_type(4))) float f32x4;

__device__ inline unsigned short bf16_rte(float f) {
  unsigned u = __float_as_uint(f);
  u += 0x7fffu + ((u >> 16) & 1u);
  return (unsigned short)(u >> 16);
}
__device__ inline float bf16_tof(unsigned short h) {
  return __uint_as_float(((unsigned)h) << 16);
}
__device__ inline void bsplit3(float v, unsigned short& h, unsigned short& m, unsigned short& l) {
  h = bf16_rte(v);
  float r = v - bf16_tof(h);
  m = bf16_rte(r);
  float r2 = r - bf16_tof(m);
  l = bf16_rte(r2);
}
// LDS XOR-swizzle: row pitch 128B (64 bf16); byte ^= ((row&7)<<4) -> conflict-free b128 r/w
__device__ inline short8m* ldsPtr(unsigned short* base, int row, int byteInRow) {
  int off = (row * 128 + byteInRow) ^ ((row & 7) << 4);
  return (short8m*)((char*)base + off);
}

// ---------------- conv 7x7 stride4 pad3, Cin=3, 224->56, fused ReLU ----------------
__global__ __launch_bounds__(256) void k_conv7(const float* __restrict__ x,
                                               const float* __restrict__ w,
                                               float* __restrict__ y) {
  __shared__ float ws[147];
  const int boc = blockIdx.y;              // b*64 + oc
  const int oc = boc & 63;
  const int b = boc >> 6;
  for (int i = threadIdx.x; i < 147; i += 256) ws[i] = w[oc * 147 + i];
  __syncthreads();
  int px = blockIdx.x * 256 + threadIdx.x;
  if (px >= 56 * 56) return;
  int oy = px / 56, ox = px % 56;
  int iy0 = oy * 4 - 3, ix0 = ox * 4 - 3;
  float acc = 0.f;
  for (int c = 0; c < 3; ++c) {
    const float* xp = x + ((size_t)(b * 3 + c)) * 224 * 224;
    #pragma unroll
    for (int ky = 0; ky < 7; ++ky) {
      int iy = iy0 + ky;
      if ((unsigned)iy < 224u) {
        #pragma unroll
        for (int kx = 0; kx < 7; ++kx) {
          int ix = ix0 + kx;
          if ((unsigned)ix < 224u)
            acc += xp[iy * 224 + ix] * ws[c * 49 + ky * 7 + kx];
        }
      }
    }
  }
  y[((size_t)boc * 56 + oy) * 56 + ox] = fmaxf(acc, 0.f);
}

// ---------------- 3x3 stride2 pad1 conv as MFMA GEMM, bf16x3 emulated-f32 ----------------
// Block: 64oc x 64px, 4 waves (16oc x 64px each), mfma_f32_16x16x32_bf16.
// f32 = hi+mid+lo bf16 planes; 6 cross-products (HH,HM,MH,HL,MM,LH) -> ~2^-26 rel error.
// K chunked by 64 (2 MFMA k-steps), XOR-swizzled LDS, split-K partials (no ReLU).
template <int CIN, int HIN, int WIN, int COUT, int HOUT, int WOUT, int SPLIT>
__global__ __launch_bounds__(256) void k_convm(const float* __restrict__ x,
                                               const float* __restrict__ wsrc,
                                               float* __restrict__ part) {
  constexpr int NPX = 4 * HOUT * WOUT;
  constexpr int KTOT = (CIN / SPLIT) * 9;
  constexpr int NCH = KTOT / 64;
  __shared__ __align__(16) unsigned short Xs[3][64][64];
  __shared__ __align__(16) unsigned short Wsh[3][64][64];
  __shared__ int pb[64], pyA[64], pxA[64];
  const int tid = threadIdx.x;
  const int oc0 = blockIdx.y * 64, px0 = blockIdx.x * 64;
  const int spl = blockIdx.z;
  const int kg0 = spl * KTOT;
  if (tid < 64) {
    int p = px0 + tid;
    if (p > NPX - 1) p = NPX - 1;
    int hw = HOUT * WOUT;
    pb[tid] = p / hw;
    int r = p % hw;
    pyA[tid] = r / WOUT;
    pxA[tid] = r % WOUT;
  }
  f32x4 acc[4] = {};
  const int l = tid & 63, wv = tid >> 6;
  const int lr = l & 15, lh = l >> 4;
  __syncthreads();
  for (int ch = 0; ch < NCH; ++ch) {
    const int kbase = kg0 + ch * 64;
    // ---- stage W: 512 (oc, koct) b128 chunks, coalesced f32 loads, split to 3 planes ----
    #pragma unroll
    for (int j = 0; j < 2; ++j) {
      int c = tid + 256 * j;
      int oc = c >> 3, koct = c & 7;
      const float* wp = wsrc + (size_t)(oc0 + oc) * (CIN * 9) + kbase + koct * 8;
      float vv[8];
      *(float4*)&vv[0] = *(const float4*)wp;
      *(float4*)&vv[4] = *(const float4*)(wp + 4);
      short8m ph, pm, pl;
      #pragma unroll
      for (int i = 0; i < 8; ++i) {
        unsigned short hb, mb, lb;
        bsplit3(vv[i], hb, mb, lb);
        ph[i] = (short)hb; pm[i] = (short)mb; pl[i] = (short)lb;
      }
      *ldsPtr(&Wsh[0][0][0], oc, koct * 16) = ph;
      *ldsPtr(&Wsh[1][0][0], oc, koct * 16) = pm;
      *ldsPtr(&Wsh[2][0][0], oc, koct * 16) = pl;
    }
    // ---- stage X: im2col gather, split to 3 planes ----
    #pragma unroll
    for (int j = 0; j < 2; ++j) {
      int c = tid + 256 * j;
      int px = c >> 3, koct = c & 7;
      int pbv = pb[px], py = pyA[px], pxv = pxA[px];
      float vv[8];
      #pragma unroll
      for (int i = 0; i < 8; ++i) {
        int k = kbase + koct * 8 + i;
        int ci = k / 9, tap = k - ci * 9;
        int iy = py * 2 - 1 + tap / 3, ix = pxv * 2 - 1 + (tap % 3);
        float v = 0.f;
        if ((unsigned)iy < (unsigned)HIN && (unsigned)ix < (unsigned)WIN)
          v = x[(((size_t)pbv * CIN + ci) * HIN + iy) * WIN + ix];
        vv[i] = v;
      }
      short8m ph, pm, pl;
      #pragma unroll
      for (int i = 0; i < 8; ++i) {
        unsigned short hb, mb, lb;
        bsplit3(vv[i], hb, mb, lb);
        ph[i] = (short)hb; pm[i] = (short)mb; pl[i] = (short)lb;
      }
      *ldsPtr(&Xs[0][0][0], px, koct * 16) = ph;
      *ldsPtr(&Xs[1][0][0], px, koct * 16) = pm;
      *ldsPtr(&Xs[2][0][0], px, koct * 16) = pl;
    }
    __syncthreads();
    // ---- MFMA: 2 k-steps of 32; per wave: A = its 16 oc rows, B = 4 px groups ----
    #pragma unroll
    for (int ks = 0; ks < 2; ++ks) {
      const int kbyte = ks * 64 + lh * 16;
      short8m aH = *ldsPtr(&Wsh[0][0][0], wv * 16 + lr, kbyte);
      short8m aM = *ldsPtr(&Wsh[1][0][0], wv * 16 + lr, kbyte);
      short8m aL = *ldsPtr(&Wsh[2][0][0], wv * 16 + lr, kbyte);
      #pragma unroll
      for (int g = 0; g < 4; ++g) {
        short8m bH = *ldsPtr(&Xs[0][0][0], g * 16 + lr, kbyte);
        short8m bM = *ldsPtr(&Xs[1][0][0], g * 16 + lr, kbyte);
        short8m bL = *ldsPtr(&Xs[2][0][0], g * 16 + lr, kbyte);
        acc[g] = __builtin_amdgcn_mfma_f32_16x16x32_bf16(aH, bH, acc[g], 0, 0, 0);
        acc[g] = __builtin_amdgcn_mfma_f32_16x16x32_bf16(aH, bM, acc[g], 0, 0, 0);
        acc[g] = __builtin_amdgcn_mfma_f32_16x16x32_bf16(aM, bH, acc[g], 0, 0, 0);
        acc[g] = __builtin_amdgcn_mfma_f32_16x16x32_bf16(aH, bL, acc[g], 0, 0, 0);
        acc[g] = __builtin_amdgcn_mfma_f32_16x16x32_bf16(aM, bM, acc[g], 0, 0, 0);
        acc[g] = __builtin_amdgcn_mfma_f32_16x16x32_bf16(aL, bH, acc[g], 0, 0, 0);
      }
    }
    __syncthreads();
  }
  // ---- write partials: D col(l&15)=px, row((l>>4)*4+r)=oc [m89 layout] ----
  const size_t N = (size_t)4 * COUT * HOUT * WOUT;
  #pragma unroll
  for (int g = 0; g < 4; ++g) {
    int pxl = g * 16 + lr;
    int pidx = px0 + pxl;
    if (pidx < NPX) {
      #pragma unroll
      for (int r = 0; r < 4; ++r) {
        int ocl = wv * 16 + lh * 4 + r;
        part[(size_t)spl * N +
             (((size_t)pb[pxl] * COUT + (oc0 + ocl)) * HOUT + pyA[pxl]) * WOUT + pxA[pxl]] =
            acc[g][r];
      }
    }
  }
}

// ---------------- split-K reduction + ReLU ----------------
template <int SPLIT>
__global__ __launch_bounds__(256) void k_red(const float* __restrict__ part,
                                             float* __restrict__ y, int n) {
  for (int i = blockIdx.x * 256 + threadIdx.x; i < n; i += gridDim.x * 256) {
    float s = 0.f;
    #pragma unroll
    for (int sp = 0; sp < SPLIT; ++sp) s += part[(size_t)sp * n + i];
    y[i] = fmaxf(s, 0.f);
  }
}

// ---------------- global-max-pool (7x7): one thread per (b,ch) ----------------
__global__ __launch_bounds__(256) void k_pool(const float* __restrict__ feat,
                                              float* __restrict__ pool) {
  int idx = blockIdx.x * 256 + threadIdx.x;
  if (idx >= 8192) return;
  const float* fp = feat + (size_t)idx * 49;
  float m = fp[0];
  #pragma unroll
  for (int i = 1; i < 49; ++i) m = fmaxf(m, fp[i]);
  pool[idx] = m;
}

// ---------------- FC(2048->14) + sigmoid: one block per (b,c) ----------------
__global__ __launch_bounds__(256) void k_fcsig(const float* __restrict__ pool,
                                               const float* __restrict__ fw,
                                               const float* __restrict__ fb,
                                               float* __restrict__ outp) {
  __shared__ float red[256];
  const int blk = blockIdx.x;       // b*14 + c
  const int b = blk / 14, c = blk % 14;
  const int tid = threadIdx.x;
  float s = 0.f;
  for (int k = tid; k < 2048; k += 256) s += pool[b * 2048 + k] * fw[c * 2048 + k];
  red[tid] = s;
  __syncthreads();
  for (int st = 128; st > 0; st >>= 1) {
    if (tid < st) red[tid] += red[tid + st];
    __syncthreads();
  }
  if (tid == 0) outp[b * 14 + c] = 1.f / (1.f + expf(-(red[0] + fb[c])));
}

// ---------------- heatmap stage A: per-(b,cell) channel max|.| ----------------
__global__ __launch_bounds__(256) void k_hm7a(const float* __restrict__ feat,
                                              float* __restrict__ hmr) {
  __shared__ float red[256];
  const int b = blockIdx.x / 49, cell = blockIdx.x % 49;
  const int tid = threadIdx.x;
  float m = 0.f;
  for (int ch = tid; ch < 2048; ch += 256)
    m = fmaxf(m, fabsf(feat[((size_t)b * 2048 + ch) * 49 + cell]));
  red[tid] = m;
  __syncthreads();
  for (int st = 128; st > 0; st >>= 1) {
    if (tid < st) red[tid] = fmaxf(red[tid], red[tid + st]);
    __syncthreads();
  }
  if (tid == 0) hmr[b * 49 + cell] = red[0];
}

// ---------------- heatmap stage B: per-sample min-max normalize ----------------
__global__ __launch_bounds__(64) void k_hm7b(const float* __restrict__ hmr,
                                             float* __restrict__ hm7) {
  __shared__ float h[49];
  const int b = blockIdx.x, tid = threadIdx.x;
  if (tid < 49) h[tid] = hmr[b * 49 + tid];
  __syncthreads();
  if (tid == 0) {
    float mn = h[0], mx = h[0];
    for (int i = 1; i < 49; ++i) {
      mn = fminf(mn, h[i]);
      mx = fmaxf(mx, h[i]);
    }
    for (int i = 0; i < 49; ++i) hm7[b * 49 + i] = (h[i] - mn) / (mx - mn);
  }
}

// ---------------- parallel CCL on mask runs + bbox of largest component ----------------
#define MAXR 8
#define NRUNS (224 * MAXR)
__global__ __launch_bounds__(256) void k_ccl(const float* __restrict__ hm7, float* __restrict__ bbox) {
  const int b = blockIdx.x, tid = threadIdx.x;
  __shared__ float h7[49];
  __shared__ short rx0[NRUNS], rx1[NRUNS];
  __shared__ short nr[224];
  __shared__ int lab[NRUNS];
  __shared__ int cnt[NRUNS], mid[NRUNS];
  __shared__ int rmn[NRUNS], rmx[NRUNS], cmn[NRUNS], cmx[NRUNS];
  __shared__ int chg, chg2;
  __shared__ int bestC[256], bestM[256], bestI[256];

  if (tid < 49) h7[tid] = hm7[b * 49 + tid];
  for (int i = tid; i < NRUNS; i += 256) {
    cnt[i] = 0; mid[i] = -1;
    rmn[i] = 1 << 30; rmx[i] = -1; cmn[i] = 1 << 30; cmx[i] = -1;
    lab[i] = i;
  }
  __syncthreads();
  if (tid < 224) {
    int yy = tid;
    float py = ((float)yy + 0.5f) * (7.f / 224.f) - 0.5f;
    py = fminf(fmaxf(py, 0.f), 6.f);
    int y0 = (int)floorf(py);
    if (y0 > 5) y0 = 5;
    float fy = py - (float)y0;
    int n = 0, start = -1;
    const int segLo[6] = {0, 48, 80, 112, 144, 176};
    const int segHi[6] = {48, 80, 112, 144, 176, 224};
    #pragma unroll
    for (int s = 0; s < 6; ++s) {
      float A = h7[y0 * 7 + s], B = h7[y0 * 7 + s + 1];
      float C = h7[(y0 + 1) * 7 + s], D = h7[(y0 + 1) * 7 + s + 1];
      for (int xx = segLo[s]; xx < segHi[s]; ++xx) {
        float px = ((float)xx + 0.5f) * (7.f / 224.f) - 0.5f;
        px = fminf(fmaxf(px, 0.f), 6.f);
        float fx = px - (float)s;
        float v = (1.f - fy) * ((1.f - fx) * A + fx * B) +
                  fy * ((1.f - fx) * C + fx * D);
        bool m = v > 0.7f;
        if (m && start < 0) start = xx;
        if (!m && start >= 0) {
          if (n < MAXR) { rx0[yy * MAXR + n] = (short)start; rx1[yy * MAXR + n] = (short)(xx - 1); n++; }
          start = -1;
        }
      }
    }
    if (start >= 0 && n < MAXR) { rx0[yy * MAXR + n] = (short)start; rx1[yy * MAXR + n] = 223; n++; }
    nr[yy] = (short)n;
  }
  __syncthreads();
  int myA0[7], myA1[7];
  bool myV[7];
  #pragma unroll
  for (int j = 0; j < 7; ++j) {
    int i = tid + j * 256;
    int yy = i >> 3, k = i & 7;
    bool v = (k < (int)nr[yy]);
    myV[j] = v;
    myA0[j] = v ? (int)rx0[i] : 0;
    myA1[j] = v ? (int)rx1[i] : 0;
  }
  for (int outer = 0; outer < 48; ++outer) {
    if (tid == 0) chg = 0;
    __syncthreads();
    bool any = false;
    #pragma unroll
    for (int j = 0; j < 7; ++j) {
      if (!myV[j]) continue;
      int i = tid + j * 256;
      int yy = i >> 3;
      int a0 = myA0[j], a1 = myA1[j];
      int ri = lab[i];
      if (yy > 0) {
        int n1 = nr[yy - 1];
        for (int kk = 0; kk < n1; ++kk) {
          int q = ((yy - 1) << 3) + kk;
          if (a0 <= rx1[q] + 1 && a1 >= rx0[q] - 1) {
            int rq = lab[q];
            if (rq < ri) { atomicMin(&lab[ri], rq); any = true; }
            else if (ri < rq) { atomicMin(&lab[rq], ri); any = true; }
          }
        }
      }
      if (yy < 223) {
        int n1 = nr[yy + 1];
        for (int kk = 0; kk < n1; ++kk) {
          int q = ((yy + 1) << 3) + kk;
          if (a0 <= rx1[q] + 1 && a1 >= rx0[q] - 1) {
            int rq = lab[q];
            if (rq < ri) { atomicMin(&lab[ri], rq); any = true; }
            else if (ri < rq) { atomicMin(&lab[rq], ri); any = true; }
          }
        }
      }
    }
    if (any) chg = 1;
    __syncthreads();
    for (int sc = 0; sc < 12; ++sc) {
      if (tid == 0) chg2 = 0;
      __syncthreads();
      bool a2 = false;
      #pragma unroll
      for (int j = 0; j < 7; ++j) {
        int i = tid + j * 256;
        int ll = lab[i];
        int l2 = lab[ll];
        if (l2 < ll) { lab[i] = l2; a2 = true; }
      }
      if (a2) chg2 = 1;
      __syncthreads();
      if (!chg2) break;
    }
    if (!chg) break;
  }
  for (int i = tid; i < NRUNS; i += 256) {
    int yy = i >> 3, k = i & 7;
    if (k >= (int)nr[yy]) continue;
    int r = lab[i];
    int a0 = rx0[i], a1 = rx1[i];
    atomicAdd(&cnt[r], a1 - a0 + 1);
    atomicMax(&mid[r], yy * 224 + a1 + 1);
    atomicMin(&rmn[r], yy);
    atomicMax(&rmx[r], yy);
    atomicMin(&cmn[r], a0);
    atomicMax(&cmx[r], a1);
  }
  __syncthreads();
  int bc = -1, bm = 0x7fffffff, bi = -1;
  for (int i = tid; i < NRUNS; i += 256) {
    if (cnt[i] > 0 && lab[i] == i) {
      if (cnt[i] > bc || (cnt[i] == bc && mid[i] < bm)) { bc = cnt[i]; bm = mid[i]; bi = i; }
    }
  }
  bestC[tid] = bc; bestM[tid] = bm; bestI[tid] = bi;
  __syncthreads();
  for (int st = 128; st > 0; st >>= 1) {
    if (tid < st) {
      if (bestC[tid + st] > bestC[tid] ||
          (bestC[tid + st] == bestC[tid] && bestM[tid + st] < bestM[tid])) {
        bestC[tid] = bestC[tid + st]; bestM[tid] = bestM[tid + st]; bestI[tid] = bestI[tid + st];
      }
    }
    __syncthreads();
  }
  if (tid == 0) {
    int bw = bestI[0];
    float fy0, chf, fx0, cwf;
    if (bw < 0) { fy0 = 224.f; chf = 1.f; fx0 = 224.f; cwf = 1.f; }
    else {
      int dr = rmx[bw] - rmn[bw]; if (dr < 1) dr = 1;
      int dc = cmx[bw] - cmn[bw]; if (dc < 1) dc = 1;
      fy0 = (float)rmn[bw]; chf = (float)dr;
      fx0 = (float)cmn[bw]; cwf = (float)dc;
    }
    bbox[b * 4 + 0] = fy0; bbox[b * 4 + 1] = chf;
    bbox[b * 4 + 2] = fx0; bbox[b * 4 + 3] = cwf;
  }
}

// ---------------- bilinear crop-resize back to 224x224 ----------------
__global__ __launch_bounds__(256) void k_sample(const float* __restrict__ img,
                                                const float* __restrict__ bbox,
                                                float* __restrict__ patch_out,
                                                float* __restrict__ patch_ws) {
  int idx = blockIdx.x * 256 + threadIdx.x;
  if (idx >= 4 * 3 * 224 * 224) return;
  int b = idx / (3 * 224 * 224);
  int r = idx % (3 * 224 * 224);
  int c = r / (224 * 224);
  int p = r % (224 * 224);
  int oy = p / 224, ox = p % 224;
  float fy0 = bbox[b * 4 + 0], chf = bbox[b * 4 + 1];
  float fx0 = bbox[b * 4 + 2], cwf = bbox[b * 4 + 3];
  float gy = ((float)oy + 0.5f) * (chf / 224.f) + fy0 - 0.5f;
  float gx = ((float)ox + 0.5f) * (cwf / 224.f) + fx0 - 0.5f;
  gy = fminf(fmaxf(gy, fy0), fmaxf(fy0 + chf - 1.f, fy0));
  gx = fminf(fmaxf(gx, fx0), fmaxf(fx0 + cwf - 1.f, fx0));
  int y0 = (int)floorf(gy);
  int x0 = (int)floorf(gx);
  float fy = gy - (float)y0, fx = gx - (float)x0;
  int y0c = min(max(y0, 0), 223), y1c = min(max(y0 + 1, 0), 223);
  int x0c = min(max(x0, 0), 223), x1c = min(max(x0 + 1, 0), 223);
  const float* ip = img + ((size_t)b * 3 + c) * 224 * 224;
  float v00 = ip[y0c * 224 + x0c], v01 = ip[y0c * 224 + x1c];
  float v10 = ip[y1c * 224 + x0c], v11 = ip[y1c * 224 + x1c];
  float v = (1.f - fy) * ((1.f - fx) * v00 + fx * v01) + fy * ((1.f - fx) * v10 + fx * v11);
  patch_out[idx] = v;
  patch_ws[idx] = v;
}

// ---------------- out_f = sigmoid([pool_g|pool_l] @ fw.T + fb); loss = weighted BCEs ----------------
__global__ __launch_bounds__(256) void k_final(const float* __restrict__ poolg,
                                               const float* __restrict__ pooll,
                                               const float* __restrict__ fw,
                                               const float* __restrict__ fb,
                                               const float* __restrict__ target,
                                               float* __restrict__ dout) {
  __shared__ float outf[56];
  __shared__ float red[256];
  const int tid = threadIdx.x;
  int pair = tid >> 2, l4 = tid & 3;
  if (pair < 56) {
    int bb = pair / 14, c = pair % 14;
    const float* w = fw + (size_t)c * 4096;
    float s = 0.f;
    for (int k = l4; k < 2048; k += 4) s += poolg[bb * 2048 + k] * w[k];
    for (int k = l4; k < 2048; k += 4) s += pooll[bb * 2048 + k] * w[2048 + k];
    s += __shfl_down(s, 2, 4);
    s += __shfl_down(s, 1, 4);
    if (l4 == 0) {
      float o = 1.f / (1.f + expf(-(s + fb[c])));
      outf[pair] = o;
      dout[113 + pair] = o;
    }
  }
  __syncthreads();
  float term = 0.f;
  if (tid < 56) {
    float t = target[tid];
    float pg = dout[1 + tid], plo = dout[57 + tid], pf = outf[tid];
    auto bce1 = [&](float pp) {
      pp = fminf(fmaxf(pp, 1e-7f), 1.f - 1e-7f);
      return -(t * logf(pp) + (1.f - t) * log1pf(-pp));
    };
    term = (0.8f * bce1(pg) + 0.1f * bce1(plo) + 0.1f * bce1(pf)) * (1.f / 56.f);
  }
  red[tid] = term;
  __syncthreads();
  for (int st = 128; st > 0; st >>= 1) {
    if (tid < st) red[tid] += red[tid + st];
    __syncthreads();
  }
  if (tid == 0) dout[0] = red[0];
}

extern "C" void kernel_launch(void* const* d_in, const int* in_sizes, int n_in,
                              void* d_out, int out_size, void* d_ws, size_t ws_size,
                              hipStream_t stream) {
  const float* img = (const float*)d_in[0];
  const float* target = (const float*)d_in[1];
  const float* gw0 = (const float*)d_in[2];
  const float* gw1 = (const float*)d_in[3];
  const float* gw2 = (const float*)d_in[4];
  const float* gw3 = (const float*)d_in[5];
  const float* gfw = (const float*)d_in[6];
  const float* gfb = (const float*)d_in[7];
  const float* lw0 = (const float*)d_in[8];
  const float* lw1 = (const float*)d_in[9];
  const float* lw2 = (const float*)d_in[10];
  const float* lw3 = (const float*)d_in[11];
  const float* lfw = (const float*)d_in[12];
  const float* lfb = (const float*)d_in[13];
  const float* fw = (const float*)d_in[14];
  const float* fb = (const float*)d_in[15];
  float* out = (float*)d_out;
  float* ws = (float*)d_ws;

  float* c1 = ws;                    // 802816   [4,64,56,56]
  float* c2 = c1 + 802816;           // 1605632  [4,512,28,28]
  float* c3 = c2 + 1605632;          // 802816   [4,1024,14,14]
  float* c4 = c3 + 802816;           // 401408   [4,2048,7,7]
  float* poolg = c4 + 401408;        // 8192
  float* pooll = poolg + 8192;       // 8192
  float* hm7 = pooll + 8192;         // 196
  float* hmr = hm7 + 196;            // 196
  float* bbox = hmr + 196;           // 16
  float* patch = ws + 3629568;       // 602112 (16B aligned)
  float* part = ws + 4231680;        // split-K partials

  dim3 g7(13, 256);
  const int rg2 = 2048, rg3 = 2048, rg4 = 1568;

  // ---- global backbone ----
  k_conv7<<<g7, 256, 0, stream>>>(img, gw0, c1);
  k_convm<64, 56, 56, 512, 28, 28, 1><<<dim3(49, 8, 1), 256, 0, stream>>>(c1, gw1, part);
  k_red<1><<<rg2, 256, 0, stream>>>(part, c2, 1605632);
  k_convm<512, 28, 28, 1024, 14, 14, 2><<<dim3(13, 16, 2), 256, 0, stream>>>(c2, gw2, part);
  k_red<2><<<rg3, 256, 0, stream>>>(part, c3, 802816);
  k_convm<1024, 14, 14, 2048, 7, 7, 2><<<dim3(4, 32, 2), 256, 0, stream>>>(c3, gw3, part);
  k_red<2><<<rg4, 256, 0, stream>>>(part, c4, 401408);
  k_pool<<<32, 256, 0, stream>>>(c4, poolg);
  k_fcsig<<<56, 256, 0, stream>>>(poolg, gfw, gfb, out + 1);
  // ---- attention patch generation ----
  k_hm7a<<<196, 256, 0, stream>>>(c4, hmr);
  k_hm7b<<<4, 64, 0, stream>>>(hmr, hm7);
  k_ccl<<<4, 256, 0, stream>>>(hm7, bbox);
  k_sample<<<2352, 256, 0, stream>>>(img, bbox, out + 169, patch);
  // ---- local backbone ----
  k_conv7<<<g7, 256, 0, stream>>>(patch, lw0, c1);
  k_convm<64, 56, 56, 512, 28, 28, 1><<<dim3(49, 8, 1), 256, 0, stream>>>(c1, lw1, part);
  k_red<1><<<rg2, 256, 0, stream>>>(part, c2, 1605632);
  k_convm<512, 28, 28, 1024, 14, 14, 2><<<dim3(13, 16, 2), 256, 0, stream>>>(c2, lw2, part);
  k_red<2><<<rg3, 256, 0, stream>>>(part, c3, 802816);
  k_convm<1024, 14, 14, 2048, 7, 7, 2><<<dim3(4, 32, 2), 256, 0, stream>>>(c3, lw3, part);
  k_red<2><<<rg4, 256, 0, stream>>>(part, c4, 401408);
  k_pool<<<32, 256, 0, stream>>>(c4, pooll);
  k_fcsig<<<56, 256, 0, stream>>>(pooll, lfw, lfb, out + 57);
  // ---- fusion + losses ----
  k_final<<<1, 256, 0, stream>>>(poolg, pooll, fw, fb, target, out);
}

// Round 11
// 983.332 us; speedup vs baseline: 4.0509x; 1.2725x over previous
//
#include <hip/hip_runtime.h>
#include <math.h>

typedef __attribute__((ext_vector_type(8))) short short8m;   // 8 bf16 (4 VGPRs)
typedef __attribute__((ext_vector_type(4))) float f32x4;

__device__ inline unsigned short bf16_trunc(float f) {
  return (unsigned short)(__float_as_uint(f) >> 16);
}
__device__ inline unsigned short bf16_rte(float f) {
  unsigned u = __float_as_uint(f);
  u += 0x7fffu + ((u >> 16) & 1u);
  return (unsigned short)(u >> 16);
}
__device__ inline float bf16_tof(unsigned short h) {
  return __uint_as_float(((unsigned)h) << 16);
}
// LDS XOR-swizzle: row pitch 128B (64 bf16); byte ^= ((row&7)<<4) -> conflict-free b128 r/w
__device__ inline short8m* ldsPtr(unsigned short* base, int row, int byteInRow) {
  int off = (row * 128 + byteInRow) ^ ((row & 7) << 4);
  return (short8m*)((char*)base + off);
}

// ---------------- conv 7x7 stride4 pad3, Cin=3, 224->56, fused ReLU ----------------
__global__ __launch_bounds__(256) void k_conv7(const float* __restrict__ x,
                                               const float* __restrict__ w,
                                               float* __restrict__ y) {
  __shared__ float ws[147];
  const int boc = blockIdx.y;              // b*64 + oc
  const int oc = boc & 63;
  const int b = boc >> 6;
  for (int i = threadIdx.x; i < 147; i += 256) ws[i] = w[oc * 147 + i];
  __syncthreads();
  int px = blockIdx.x * 256 + threadIdx.x;
  if (px >= 56 * 56) return;
  int oy = px / 56, ox = px % 56;
  int iy0 = oy * 4 - 3, ix0 = ox * 4 - 3;
  float acc = 0.f;
  for (int c = 0; c < 3; ++c) {
    const float* xp = x + ((size_t)(b * 3 + c)) * 224 * 224;
    #pragma unroll
    for (int ky = 0; ky < 7; ++ky) {
      int iy = iy0 + ky;
      if ((unsigned)iy < 224u) {
        #pragma unroll
        for (int kx = 0; kx < 7; ++kx) {
          int ix = ix0 + kx;
          if ((unsigned)ix < 224u)
            acc += xp[iy * 224 + ix] * ws[c * 49 + ky * 7 + kx];
        }
      }
    }
  }
  y[((size_t)boc * 56 + oy) * 56 + ox] = fmaxf(acc, 0.f);
}

// ---------------- 3x3 stride2 pad1 conv as MFMA GEMM, bf16-split emulated-f32 ----------------
// Block: 64oc x 64px, 4 waves (16oc x 64px each), mfma_f32_16x16x32_bf16.
// W = 3 planes (h trunc, m rte, l rte); X = 2 planes (h trunc, m rte, |res|<=2^-17).
// 5 products: WhXh, WhXm, WmXh, WmXm, WlXh -> ~2^-16 rel error (mask budget 1e-3).
// K chunked by 64, XOR-swizzled LDS, split over linear k axis (KTOT%64==0), partials out.
template <int CIN, int HIN, int WIN, int COUT, int HOUT, int WOUT, int SPLIT>
__global__ __launch_bounds__(256) void k_convm(const float* __restrict__ x,
                                               const float* __restrict__ wsrc,
                                               float* __restrict__ part) {
  constexpr int NPX = 4 * HOUT * WOUT;
  constexpr int KTOT = (CIN * 9) / SPLIT;
  constexpr int NCH = KTOT / 64;
  __shared__ __align__(16) unsigned short Xs[2][64][64];
  __shared__ __align__(16) unsigned short Wsh[3][64][64];
  __shared__ int pb[64], pyA[64], pxA[64];
  const int tid = threadIdx.x;
  const int oc0 = blockIdx.y * 64, px0 = blockIdx.x * 64;
  const int spl = blockIdx.z;
  const int kg0 = spl * KTOT;
  if (tid < 64) {
    int p = px0 + tid;
    if (p > NPX - 1) p = NPX - 1;
    int hw = HOUT * WOUT;
    pb[tid] = p / hw;
    int r = p % hw;
    pyA[tid] = r / WOUT;
    pxA[tid] = r % WOUT;
  }
  f32x4 acc[4] = {};
  const int l = tid & 63, wv = tid >> 6;
  const int lr = l & 15, lh = l >> 4;
  __syncthreads();
  for (int ch = 0; ch < NCH; ++ch) {
    const int kbase = kg0 + ch * 64;
    // ---- stage W: (oc, koct) chunks, float4 loads, 3-plane split ----
    #pragma unroll
    for (int j = 0; j < 2; ++j) {
      int c = tid + 256 * j;
      int oc = c >> 3, koct = c & 7;
      const float* wp = wsrc + (size_t)(oc0 + oc) * (CIN * 9) + kbase + koct * 8;
      float vv[8];
      *(float4*)&vv[0] = *(const float4*)wp;
      *(float4*)&vv[4] = *(const float4*)(wp + 4);
      short8m ph, pm, pl;
      #pragma unroll
      for (int i = 0; i < 8; ++i) {
        unsigned short hb = bf16_trunc(vv[i]);
        float r = vv[i] - bf16_tof(hb);
        unsigned short mb = bf16_rte(r);
        float r2 = r - bf16_tof(mb);
        unsigned short lb = bf16_rte(r2);
        ph[i] = (short)hb; pm[i] = (short)mb; pl[i] = (short)lb;
      }
      *ldsPtr(&Wsh[0][0][0], oc, koct * 16) = ph;
      *ldsPtr(&Wsh[1][0][0], oc, koct * 16) = pm;
      *ldsPtr(&Wsh[2][0][0], oc, koct * 16) = pl;
    }
    // ---- stage X: im2col gather, lane=px (coalesced per-k across wave), 2-plane split ----
    #pragma unroll
    for (int j = 0; j < 2; ++j) {
      int c = tid + 256 * j;
      int px = c & 63, koct = c >> 6;            // adjacent lanes -> adjacent px
      int pbv = pb[px], py = pyA[px], pxv = pxA[px];
      float vv[8];
      #pragma unroll
      for (int i = 0; i < 8; ++i) {
        int k = kbase + koct * 8 + i;
        int ci = k / 9, tap = k - ci * 9;
        int iy = py * 2 - 1 + tap / 3, ix = pxv * 2 - 1 + (tap % 3);
        float v = 0.f;
        if ((unsigned)iy < (unsigned)HIN && (unsigned)ix < (unsigned)WIN)
          v = x[(((size_t)pbv * CIN + ci) * HIN + iy) * WIN + ix];
        vv[i] = v;
      }
      short8m ph, pm;
      #pragma unroll
      for (int i = 0; i < 8; ++i) {
        unsigned short hb = bf16_trunc(vv[i]);
        float r = vv[i] - bf16_tof(hb);
        unsigned short mb = bf16_rte(r);
        ph[i] = (short)hb; pm[i] = (short)mb;
      }
      *ldsPtr(&Xs[0][0][0], px, koct * 16) = ph;
      *ldsPtr(&Xs[1][0][0], px, koct * 16) = pm;
    }
    __syncthreads();
    // ---- MFMA: 2 k-steps of 32; per wave: A = its 16 oc rows, B = 4 px groups ----
    #pragma unroll
    for (int ks = 0; ks < 2; ++ks) {
      const int kbyte = ks * 64 + lh * 16;
      short8m aH = *ldsPtr(&Wsh[0][0][0], wv * 16 + lr, kbyte);
      short8m aM = *ldsPtr(&Wsh[1][0][0], wv * 16 + lr, kbyte);
      short8m aL = *ldsPtr(&Wsh[2][0][0], wv * 16 + lr, kbyte);
      #pragma unroll
      for (int g = 0; g < 4; ++g) {
        short8m bH = *ldsPtr(&Xs[0][0][0], g * 16 + lr, kbyte);
        short8m bM = *ldsPtr(&Xs[1][0][0], g * 16 + lr, kbyte);
        acc[g] = __builtin_amdgcn_mfma_f32_16x16x32_bf16(aH, bH, acc[g], 0, 0, 0);
        acc[g] = __builtin_amdgcn_mfma_f32_16x16x32_bf16(aH, bM, acc[g], 0, 0, 0);
        acc[g] = __builtin_amdgcn_mfma_f32_16x16x32_bf16(aM, bH, acc[g], 0, 0, 0);
        acc[g] = __builtin_amdgcn_mfma_f32_16x16x32_bf16(aM, bM, acc[g], 0, 0, 0);
        acc[g] = __builtin_amdgcn_mfma_f32_16x16x32_bf16(aL, bH, acc[g], 0, 0, 0);
      }
    }
    __syncthreads();
  }
  // ---- write partials: D col(l&15)=px, row((l>>4)*4+r)=oc [m89 layout] ----
  const size_t N = (size_t)4 * COUT * HOUT * WOUT;
  #pragma unroll
  for (int g = 0; g < 4; ++g) {
    int pxl = g * 16 + lr;
    int pidx = px0 + pxl;
    if (pidx < NPX) {
      #pragma unroll
      for (int r = 0; r < 4; ++r) {
        int ocl = wv * 16 + lh * 4 + r;
        part[(size_t)spl * N +
             (((size_t)pb[pxl] * COUT + (oc0 + ocl)) * HOUT + pyA[pxl]) * WOUT + pxA[pxl]] =
            acc[g][r];
      }
    }
  }
}

// ---------------- split-K reduction + ReLU ----------------
template <int SPLIT>
__global__ __launch_bounds__(256) void k_red(const float* __restrict__ part,
                                             float* __restrict__ y, int n) {
  for (int i = blockIdx.x * 256 + threadIdx.x; i < n; i += gridDim.x * 256) {
    float s = 0.f;
    #pragma unroll
    for (int sp = 0; sp < SPLIT; ++sp) s += part[(size_t)sp * n + i];
    y[i] = fmaxf(s, 0.f);
  }
}

// ---------------- global-max-pool (7x7): one thread per (b,ch) ----------------
__global__ __launch_bounds__(256) void k_pool(const float* __restrict__ feat,
                                              float* __restrict__ pool) {
  int idx = blockIdx.x * 256 + threadIdx.x;
  if (idx >= 8192) return;
  const float* fp = feat + (size_t)idx * 49;
  float m = fp[0];
  #pragma unroll
  for (int i = 1; i < 49; ++i) m = fmaxf(m, fp[i]);
  pool[idx] = m;
}

// ---------------- FC(2048->14) + sigmoid: one block per (b,c) ----------------
__global__ __launch_bounds__(256) void k_fcsig(const float* __restrict__ pool,
                                               const float* __restrict__ fw,
                                               const float* __restrict__ fb,
                                               float* __restrict__ outp) {
  __shared__ float red[256];
  const int blk = blockIdx.x;       // b*14 + c
  const int b = blk / 14, c = blk % 14;
  const int tid = threadIdx.x;
  float s = 0.f;
  for (int k = tid; k < 2048; k += 256) s += pool[b * 2048 + k] * fw[c * 2048 + k];
  red[tid] = s;
  __syncthreads();
  for (int st = 128; st > 0; st >>= 1) {
    if (tid < st) red[tid] += red[tid + st];
    __syncthreads();
  }
  if (tid == 0) outp[b * 14 + c] = 1.f / (1.f + expf(-(red[0] + fb[c])));
}

// ---------------- heatmap stage A: per-(b,cell) channel max|.| ----------------
__global__ __launch_bounds__(256) void k_hm7a(const float* __restrict__ feat,
                                              float* __restrict__ hmr) {
  __shared__ float red[256];
  const int b = blockIdx.x / 49, cell = blockIdx.x % 49;
  const int tid = threadIdx.x;
  float m = 0.f;
  for (int ch = tid; ch < 2048; ch += 256)
    m = fmaxf(m, fabsf(feat[((size_t)b * 2048 + ch) * 49 + cell]));
  red[tid] = m;
  __syncthreads();
  for (int st = 128; st > 0; st >>= 1) {
    if (tid < st) red[tid] = fmaxf(red[tid], red[tid + st]);
    __syncthreads();
  }
  if (tid == 0) hmr[b * 49 + cell] = red[0];
}

// ---------------- heatmap stage B: per-sample min-max normalize ----------------
__global__ __launch_bounds__(64) void k_hm7b(const float* __restrict__ hmr,
                                             float* __restrict__ hm7) {
  __shared__ float h[49];
  const int b = blockIdx.x, tid = threadIdx.x;
  if (tid < 49) h[tid] = hmr[b * 49 + tid];
  __syncthreads();
  if (tid == 0) {
    float mn = h[0], mx = h[0];
    for (int i = 1; i < 49; ++i) {
      mn = fminf(mn, h[i]);
      mx = fmaxf(mx, h[i]);
    }
    for (int i = 0; i < 49; ++i) hm7[b * 49 + i] = (h[i] - mn) / (mx - mn);
  }
}

// ---------------- parallel CCL on mask runs + bbox of largest component ----------------
#define MAXR 8
#define NRUNS (224 * MAXR)
__global__ __launch_bounds__(256) void k_ccl(const float* __restrict__ hm7, float* __restrict__ bbox) {
  const int b = blockIdx.x, tid = threadIdx.x;
  __shared__ float h7[49];
  __shared__ short rx0[NRUNS], rx1[NRUNS];
  __shared__ short nr[224];
  __shared__ int lab[NRUNS];
  __shared__ int cnt[NRUNS], mid[NRUNS];
  __shared__ int rmn[NRUNS], rmx[NRUNS], cmn[NRUNS], cmx[NRUNS];
  __shared__ int chg, chg2;
  __shared__ int bestC[256], bestM[256], bestI[256];

  if (tid < 49) h7[tid] = hm7[b * 49 + tid];
  for (int i = tid; i < NRUNS; i += 256) {
    cnt[i] = 0; mid[i] = -1;
    rmn[i] = 1 << 30; rmx[i] = -1; cmn[i] = 1 << 30; cmx[i] = -1;
    lab[i] = i;
  }
  __syncthreads();
  if (tid < 224) {
    int yy = tid;
    float py = ((float)yy + 0.5f) * (7.f / 224.f) - 0.5f;
    py = fminf(fmaxf(py, 0.f), 6.f);
    int y0 = (int)floorf(py);
    if (y0 > 5) y0 = 5;
    float fy = py - (float)y0;
    int n = 0, start = -1;
    const int segLo[6] = {0, 48, 80, 112, 144, 176};
    const int segHi[6] = {48, 80, 112, 144, 176, 224};
    #pragma unroll
    for (int s = 0; s < 6; ++s) {
      float A = h7[y0 * 7 + s], B = h7[y0 * 7 + s + 1];
      float C = h7[(y0 + 1) * 7 + s], D = h7[(y0 + 1) * 7 + s + 1];
      for (int xx = segLo[s]; xx < segHi[s]; ++xx) {
        float px = ((float)xx + 0.5f) * (7.f / 224.f) - 0.5f;
        px = fminf(fmaxf(px, 0.f), 6.f);
        float fx = px - (float)s;
        float v = (1.f - fy) * ((1.f - fx) * A + fx * B) +
                  fy * ((1.f - fx) * C + fx * D);
        bool m = v > 0.7f;
        if (m && start < 0) start = xx;
        if (!m && start >= 0) {
          if (n < MAXR) { rx0[yy * MAXR + n] = (short)start; rx1[yy * MAXR + n] = (short)(xx - 1); n++; }
          start = -1;
        }
      }
    }
    if (start >= 0 && n < MAXR) { rx0[yy * MAXR + n] = (short)start; rx1[yy * MAXR + n] = 223; n++; }
    nr[yy] = (short)n;
  }
  __syncthreads();
  int myA0[7], myA1[7];
  bool myV[7];
  #pragma unroll
  for (int j = 0; j < 7; ++j) {
    int i = tid + j * 256;
    int yy = i >> 3, k = i & 7;
    bool v = (k < (int)nr[yy]);
    myV[j] = v;
    myA0[j] = v ? (int)rx0[i] : 0;
    myA1[j] = v ? (int)rx1[i] : 0;
  }
  for (int outer = 0; outer < 48; ++outer) {
    if (tid == 0) chg = 0;
    __syncthreads();
    bool any = false;
    #pragma unroll
    for (int j = 0; j < 7; ++j) {
      if (!myV[j]) continue;
      int i = tid + j * 256;
      int yy = i >> 3;
      int a0 = myA0[j], a1 = myA1[j];
      int ri = lab[i];
      if (yy > 0) {
        int n1 = nr[yy - 1];
        for (int kk = 0; kk < n1; ++kk) {
          int q = ((yy - 1) << 3) + kk;
          if (a0 <= rx1[q] + 1 && a1 >= rx0[q] - 1) {
            int rq = lab[q];
            if (rq < ri) { atomicMin(&lab[ri], rq); any = true; }
            else if (ri < rq) { atomicMin(&lab[rq], ri); any = true; }
          }
        }
      }
      if (yy < 223) {
        int n1 = nr[yy + 1];
        for (int kk = 0; kk < n1; ++kk) {
          int q = ((yy + 1) << 3) + kk;
          if (a0 <= rx1[q] + 1 && a1 >= rx0[q] - 1) {
            int rq = lab[q];
            if (rq < ri) { atomicMin(&lab[ri], rq); any = true; }
            else if (ri < rq) { atomicMin(&lab[rq], ri); any = true; }
          }
        }
      }
    }
    if (any) chg = 1;
    __syncthreads();
    for (int sc = 0; sc < 12; ++sc) {
      if (tid == 0) chg2 = 0;
      __syncthreads();
      bool a2 = false;
      #pragma unroll
      for (int j = 0; j < 7; ++j) {
        int i = tid + j * 256;
        int ll = lab[i];
        int l2 = lab[ll];
        if (l2 < ll) { lab[i] = l2; a2 = true; }
      }
      if (a2) chg2 = 1;
      __syncthreads();
      if (!chg2) break;
    }
    if (!chg) break;
  }
  for (int i = tid; i < NRUNS; i += 256) {
    int yy = i >> 3, k = i & 7;
    if (k >= (int)nr[yy]) continue;
    int r = lab[i];
    int a0 = rx0[i], a1 = rx1[i];
    atomicAdd(&cnt[r], a1 - a0 + 1);
    atomicMax(&mid[r], yy * 224 + a1 + 1);
    atomicMin(&rmn[r], yy);
    atomicMax(&rmx[r], yy);
    atomicMin(&cmn[r], a0);
    atomicMax(&cmx[r], a1);
  }
  __syncthreads();
  int bc = -1, bm = 0x7fffffff, bi = -1;
  for (int i = tid; i < NRUNS; i += 256) {
    if (cnt[i] > 0 && lab[i] == i) {
      if (cnt[i] > bc || (cnt[i] == bc && mid[i] < bm)) { bc = cnt[i]; bm = mid[i]; bi = i; }
    }
  }
  bestC[tid] = bc; bestM[tid] = bm; bestI[tid] = bi;
  __syncthreads();
  for (int st = 128; st > 0; st >>= 1) {
    if (tid < st) {
      if (bestC[tid + st] > bestC[tid] ||
          (bestC[tid + st] == bestC[tid] && bestM[tid + st] < bestM[tid])) {
        bestC[tid] = bestC[tid + st]; bestM[tid] = bestM[tid + st]; bestI[tid] = bestI[tid + st];
      }
    }
    __syncthreads();
  }
  if (tid == 0) {
    int bw = bestI[0];
    float fy0, chf, fx0, cwf;
    if (bw < 0) { fy0 = 224.f; chf = 1.f; fx0 = 224.f; cwf = 1.f; }
    else {
      int dr = rmx[bw] - rmn[bw]; if (dr < 1) dr = 1;
      int dc = cmx[bw] - cmn[bw]; if (dc < 1) dc = 1;
      fy0 = (float)rmn[bw]; chf = (float)dr;
      fx0 = (float)cmn[bw]; cwf = (float)dc;
    }
    bbox[b * 4 + 0] = fy0; bbox[b * 4 + 1] = chf;
    bbox[b * 4 + 2] = fx0; bbox[b * 4 + 3] = cwf;
  }
}

// ---------------- bilinear crop-resize back to 224x224 ----------------
__global__ __launch_bounds__(256) void k_sample(const float* __restrict__ img,
                                                const float* __restrict__ bbox,
                                                float* __restrict__ patch_out,
                                                float* __restrict__ patch_ws) {
  int idx = blockIdx.x * 256 + threadIdx.x;
  if (idx >= 4 * 3 * 224 * 224) return;
  int b = idx / (3 * 224 * 224);
  int r = idx % (3 * 224 * 224);
  int c = r / (224 * 224);
  int p = r % (224 * 224);
  int oy = p / 224, ox = p % 224;
  float fy0 = bbox[b * 4 + 0], chf = bbox[b * 4 + 1];
  float fx0 = bbox[b * 4 + 2], cwf = bbox[b * 4 + 3];
  float gy = ((float)oy + 0.5f) * (chf / 224.f) + fy0 - 0.5f;
  float gx = ((float)ox + 0.5f) * (cwf / 224.f) + fx0 - 0.5f;
  gy = fminf(fmaxf(gy, fy0), fmaxf(fy0 + chf - 1.f, fy0));
  gx = fminf(fmaxf(gx, fx0), fmaxf(fx0 + cwf - 1.f, fx0));
  int y0 = (int)floorf(gy);
  int x0 = (int)floorf(gx);
  float fy = gy - (float)y0, fx = gx - (float)x0;
  int y0c = min(max(y0, 0), 223), y1c = min(max(y0 + 1, 0), 223);
  int x0c = min(max(x0, 0), 223), x1c = min(max(x0 + 1, 0), 223);
  const float* ip = img + ((size_t)b * 3 + c) * 224 * 224;
  float v00 = ip[y0c * 224 + x0c], v01 = ip[y0c * 224 + x1c];
  float v10 = ip[y1c * 224 + x0c], v11 = ip[y1c * 224 + x1c];
  float v = (1.f - fy) * ((1.f - fx) * v00 + fx * v01) + fy * ((1.f - fx) * v10 + fx * v11);
  patch_out[idx] = v;
  patch_ws[idx] = v;
}

// ---------------- out_f = sigmoid([pool_g|pool_l] @ fw.T + fb); loss = weighted BCEs ----------------
__global__ __launch_bounds__(256) void k_final(const float* __restrict__ poolg,
                                               const float* __restrict__ pooll,
                                               const float* __restrict__ fw,
                                               const float* __restrict__ fb,
                                               const float* __restrict__ target,
                                               float* __restrict__ dout) {
  __shared__ float outf[56];
  __shared__ float red[256];
  const int tid = threadIdx.x;
  int pair = tid >> 2, l4 = tid & 3;
  if (pair < 56) {
    int bb = pair / 14, c = pair % 14;
    const float* w = fw + (size_t)c * 4096;
    float s = 0.f;
    for (int k = l4; k < 2048; k += 4) s += poolg[bb * 2048 + k] * w[k];
    for (int k = l4; k < 2048; k += 4) s += pooll[bb * 2048 + k] * w[2048 + k];
    s += __shfl_down(s, 2, 4);
    s += __shfl_down(s, 1, 4);
    if (l4 == 0) {
      float o = 1.f / (1.f + expf(-(s + fb[c])));
      outf[pair] = o;
      dout[113 + pair] = o;
    }
  }
  __syncthreads();
  float term = 0.f;
  if (tid < 56) {
    float t = target[tid];
    float pg = dout[1 + tid], plo = dout[57 + tid], pf = outf[tid];
    auto bce1 = [&](float pp) {
      pp = fminf(fmaxf(pp, 1e-7f), 1.f - 1e-7f);
      return -(t * logf(pp) + (1.f - t) * log1pf(-pp));
    };
    term = (0.8f * bce1(pg) + 0.1f * bce1(plo) + 0.1f * bce1(pf)) * (1.f / 56.f);
  }
  red[tid] = term;
  __syncthreads();
  for (int st = 128; st > 0; st >>= 1) {
    if (tid < st) red[tid] += red[tid + st];
    __syncthreads();
  }
  if (tid == 0) dout[0] = red[0];
}

extern "C" void kernel_launch(void* const* d_in, const int* in_sizes, int n_in,
                              void* d_out, int out_size, void* d_ws, size_t ws_size,
                              hipStream_t stream) {
  const float* img = (const float*)d_in[0];
  const float* target = (const float*)d_in[1];
  const float* gw0 = (const float*)d_in[2];
  const float* gw1 = (const float*)d_in[3];
  const float* gw2 = (const float*)d_in[4];
  const float* gw3 = (const float*)d_in[5];
  const float* gfw = (const float*)d_in[6];
  const float* gfb = (const float*)d_in[7];
  const float* lw0 = (const float*)d_in[8];
  const float* lw1 = (const float*)d_in[9];
  const float* lw2 = (const float*)d_in[10];
  const float* lw3 = (const float*)d_in[11];
  const float* lfw = (const float*)d_in[12];
  const float* lfb = (const float*)d_in[13];
  const float* fw = (const float*)d_in[14];
  const float* fb = (const float*)d_in[15];
  float* out = (float*)d_out;
  float* ws = (float*)d_ws;

  float* c1 = ws;                    // 802816   [4,64,56,56]
  float* c2 = c1 + 802816;           // 1605632  [4,512,28,28]
  float* c3 = c2 + 1605632;          // 802816   [4,1024,14,14]
  float* c4 = c3 + 802816;           // 401408   [4,2048,7,7]
  float* poolg = c4 + 401408;        // 8192
  float* pooll = poolg + 8192;       // 8192
  float* hm7 = pooll + 8192;         // 196
  float* hmr = hm7 + 196;            // 196
  float* bbox = hmr + 196;           // 16
  float* patch = ws + 3629568;       // 602112 (16B aligned)
  float* part = ws + 4231680;        // <=3211264 split-K partials (29.8 MB total ws)

  dim3 g7(13, 256);
  const int rg2 = 2048, rg3 = 2048, rg4 = 1568;

  // ---- global backbone ----
  k_conv7<<<g7, 256, 0, stream>>>(img, gw0, c1);
  k_convm<64, 56, 56, 512, 28, 28, 1><<<dim3(49, 8, 1), 256, 0, stream>>>(c1, gw1, part);
  k_red<1><<<rg2, 256, 0, stream>>>(part, c2, 1605632);
  k_convm<512, 28, 28, 1024, 14, 14, 4><<<dim3(13, 16, 4), 256, 0, stream>>>(c2, gw2, part);
  k_red<4><<<rg3, 256, 0, stream>>>(part, c3, 802816);
  k_convm<1024, 14, 14, 2048, 7, 7, 8><<<dim3(4, 32, 8), 256, 0, stream>>>(c3, gw3, part);
  k_red<8><<<rg4, 256, 0, stream>>>(part, c4, 401408);
  k_pool<<<32, 256, 0, stream>>>(c4, poolg);
  k_fcsig<<<56, 256, 0, stream>>>(poolg, gfw, gfb, out + 1);
  // ---- attention patch generation ----
  k_hm7a<<<196, 256, 0, stream>>>(c4, hmr);
  k_hm7b<<<4, 64, 0, stream>>>(hmr, hm7);
  k_ccl<<<4, 256, 0, stream>>>(hm7, bbox);
  k_sample<<<2352, 256, 0, stream>>>(img, bbox, out + 169, patch);
  // ---- local backbone ----
  k_conv7<<<g7, 256, 0, stream>>>(patch, lw0, c1);
  k_convm<64, 56, 56, 512, 28, 28, 1><<<dim3(49, 8, 1), 256, 0, stream>>>(c1, lw1, part);
  k_red<1><<<rg2, 256, 0, stream>>>(part, c2, 1605632);
  k_convm<512, 28, 28, 1024, 14, 14, 4><<<dim3(13, 16, 4), 256, 0, stream>>>(c2, lw2, part);
  k_red<4><<<rg3, 256, 0, stream>>>(part, c3, 802816);
  k_convm<1024, 14, 14, 2048, 7, 7, 8><<<dim3(4, 32, 8), 256, 0, stream>>>(c3, lw3, part);
  k_red<8><<<rg4, 256, 0, stream>>>(part, c4, 401408);
  k_pool<<<32, 256, 0, stream>>>(c4, pooll);
  k_fcsig<<<56, 256, 0, stream>>>(pooll, lfw, lfb, out + 57);
  // ---- fusion + losses ----
  k_final<<<1, 256, 0, stream>>>(poolg, pooll, fw, fb, target, out);
}

// Round 12
// 725.485 us; speedup vs baseline: 5.4906x; 1.3554x over previous
//
#include <hip/hip_runtime.h>
#include <math.h>

typedef __attribute__((ext_vector_type(8))) short short8m;   // 8 bf16 (4 VGPRs)
typedef __attribute__((ext_vector_type(4))) float f32x4;

__device__ inline unsigned short bf16_trunc(float f) {
  return (unsigned short)(__float_as_uint(f) >> 16);
}
__device__ inline unsigned short bf16_rte(float f) {
  unsigned u = __float_as_uint(f);
  u += 0x7fffu + ((u >> 16) & 1u);
  return (unsigned short)(u >> 16);
}
__device__ inline float bf16_tof(unsigned short h) {
  return __uint_as_float(((unsigned)h) << 16);
}
// LDS XOR-swizzle for W tiles: row pitch 128B; byte ^= ((row&7)<<4) -> conflict-free b128 r/w
__device__ inline short8m* ldsPtr(unsigned short* base, int row, int byteInRow) {
  int off = (row * 128 + byteInRow) ^ ((row & 7) << 4);
  return (short8m*)((char*)base + off);
}
__device__ inline void gload16_lds(const void* g, void* d) {
  __builtin_amdgcn_global_load_lds((const __attribute__((address_space(1))) unsigned int*)g,
                                   (__attribute__((address_space(3))) unsigned int*)d, 16, 0, 0);
}

// ---------------- conv 7x7 stride4 pad3, Cin=3, 224->56, fused ReLU ----------------
__global__ __launch_bounds__(256) void k_conv7(const float* __restrict__ x,
                                               const float* __restrict__ w,
                                               float* __restrict__ y) {
  __shared__ float ws[147];
  const int boc = blockIdx.y;              // b*64 + oc
  const int oc = boc & 63;
  const int b = boc >> 6;
  for (int i = threadIdx.x; i < 147; i += 256) ws[i] = w[oc * 147 + i];
  __syncthreads();
  int px = blockIdx.x * 256 + threadIdx.x;
  if (px >= 56 * 56) return;
  int oy = px / 56, ox = px % 56;
  int iy0 = oy * 4 - 3, ix0 = ox * 4 - 3;
  float acc = 0.f;
  for (int c = 0; c < 3; ++c) {
    const float* xp = x + ((size_t)(b * 3 + c)) * 224 * 224;
    #pragma unroll
    for (int ky = 0; ky < 7; ++ky) {
      int iy = iy0 + ky;
      if ((unsigned)iy < 224u) {
        #pragma unroll
        for (int kx = 0; kx < 7; ++kx) {
          int ix = ix0 + kx;
          if ((unsigned)ix < 224u)
            acc += xp[iy * 224 + ix] * ws[c * 49 + ky * 7 + kx];
        }
      }
    }
  }
  y[((size_t)boc * 56 + oy) * 56 + ox] = fmaxf(acc, 0.f);
}

// ---------------- im2col + 2-plane bf16 split, block-tiled layout ----------------
// Xg element (px,k) at  pxblk*KTOT*64 + (k>>3)*512 + pxin*8 + (k&7)   (ushort units)
// -> GEMM stages 64px x 8k slabs as contiguous 1KB, perfect for global_load_lds.
template <int CIN, int HIN, int WIN, int HOUT, int WOUT>
__global__ __launch_bounds__(256) void k_im2col(const float* __restrict__ x,
                                                unsigned short* __restrict__ XgH,
                                                unsigned short* __restrict__ XgM) {
  constexpr int NPX = 4 * HOUT * WOUT;
  constexpr int KTOT = CIN * 9;
  constexpr int K8 = KTOT / 8;
  int u = blockIdx.x * 256 + threadIdx.x;
  int pxin = u & 63;
  int k8 = (u >> 6) % K8;
  int pxblk = (u >> 6) / K8;
  int px = pxblk * 64 + pxin;
  if (px > NPX - 1) px = NPX - 1;          // pad replication
  const int hw = HOUT * WOUT;
  int pbv = px / hw;
  int r = px % hw;
  int py = r / WOUT, pxv = r % WOUT;
  short8m ph, pm;
  #pragma unroll
  for (int i = 0; i < 8; ++i) {
    int k = k8 * 8 + i;
    int ci = k / 9, tap = k - ci * 9;
    int iy = py * 2 - 1 + tap / 3, ix = pxv * 2 - 1 + (tap % 3);
    float v = 0.f;
    if ((unsigned)iy < (unsigned)HIN && (unsigned)ix < (unsigned)WIN)
      v = x[(((size_t)pbv * CIN + ci) * HIN + iy) * WIN + ix];
    unsigned short hb = bf16_trunc(v);
    unsigned short mb = bf16_rte(v - bf16_tof(hb));
    ph[i] = (short)hb; pm[i] = (short)mb;
  }
  size_t off = (size_t)u * 8;
  *(short8m*)(XgH + off) = ph;
  *(short8m*)(XgM + off) = pm;
}

// ---------------- GEMM on pre-im2col'd X: bf16 2x2-plane emulated f32 ----------------
// Block 64oc x 64px, 4 waves, mfma_f32_16x16x32_bf16, 4 products (HH,HM,MH,MM).
// X staged via global_load_lds (no VALU); W split in-kernel (trunc+rte).
template <int COUT, int HOUT, int WOUT, int KTOT, int SPLIT>
__global__ __launch_bounds__(256) void k_gemmx(const unsigned short* __restrict__ XgH,
                                               const unsigned short* __restrict__ XgM,
                                               const float* __restrict__ wsrc,
                                               float* __restrict__ part) {
  constexpr int NPX = 4 * HOUT * WOUT;
  constexpr int KCH = KTOT / SPLIT;
  constexpr int NCH = KCH / 64;
  __shared__ __align__(16) unsigned short XsH[4096];   // [8 koct][64 px][8 k] linear image
  __shared__ __align__(16) unsigned short XsM[4096];
  __shared__ __align__(16) unsigned short WsH[4096];   // swizzled [64 oc][64 k]
  __shared__ __align__(16) unsigned short WsM[4096];
  __shared__ int pb[64], pyA[64], pxA[64];
  const int tid = threadIdx.x;
  const int oc0 = blockIdx.y * 64;
  const int pxblk = blockIdx.x;
  const int spl = blockIdx.z;
  if (tid < 64) {
    int p = pxblk * 64 + tid;
    if (p > NPX - 1) p = NPX - 1;
    int hw = HOUT * WOUT;
    pb[tid] = p / hw;
    int r = p % hw;
    pyA[tid] = r / WOUT;
    pxA[tid] = r % WOUT;
  }
  f32x4 acc[4] = {};
  const int l = tid & 63, wv = tid >> 6;
  const int lr = l & 15, lh = l >> 4;
  __syncthreads();
  for (int ch = 0; ch < NCH; ++ch) {
    const int kbase = spl * KCH + ch * 64;
    // ---- X: 16 async 1KB slabs (2 planes x 8 koct), 4 per wave ----
    const size_t tileOff = (size_t)pxblk * KTOT * 64 + (size_t)kbase * 64;
    #pragma unroll
    for (int t = 0; t < 4; ++t) {
      int ins = wv * 4 + t;
      int pl = ins >> 3, ko = ins & 7;
      const unsigned short* g = (pl ? XgM : XgH) + tileOff + ko * 512 + l * 8;
      unsigned short* d = (pl ? XsM : XsH) + ko * 512;
      gload16_lds(g, d);
    }
    // ---- W: 2-plane split, swizzled LDS ----
    #pragma unroll
    for (int j = 0; j < 2; ++j) {
      int c = tid + 256 * j;
      int oc = c >> 3, koct = c & 7;
      const float* wp = wsrc + (size_t)(oc0 + oc) * KTOT + kbase + koct * 8;
      float vv[8];
      *(float4*)&vv[0] = *(const float4*)wp;
      *(float4*)&vv[4] = *(const float4*)(wp + 4);
      short8m ph, pm;
      #pragma unroll
      for (int i = 0; i < 8; ++i) {
        unsigned short hb = bf16_trunc(vv[i]);
        unsigned short mb = bf16_rte(vv[i] - bf16_tof(hb));
        ph[i] = (short)hb; pm[i] = (short)mb;
      }
      *ldsPtr(WsH, oc, koct * 16) = ph;
      *ldsPtr(WsM, oc, koct * 16) = pm;
    }
    __syncthreads();                       // drains vmcnt (global_load_lds) + lgkm
    // ---- MFMA: 2 k-steps of 32, 4 px groups, 4 products ----
    #pragma unroll
    for (int ks = 0; ks < 2; ++ks) {
      const int kbyte = ks * 64 + lh * 16;
      short8m aH = *ldsPtr(WsH, wv * 16 + lr, kbyte);
      short8m aM = *ldsPtr(WsM, wv * 16 + lr, kbyte);
      const int xoff = (ks * 4 + lh) * 512;
      #pragma unroll
      for (int g4 = 0; g4 < 4; ++g4) {
        short8m bH = *(const short8m*)(XsH + xoff + (g4 * 16 + lr) * 8);
        short8m bM = *(const short8m*)(XsM + xoff + (g4 * 16 + lr) * 8);
        acc[g4] = __builtin_amdgcn_mfma_f32_16x16x32_bf16(aH, bH, acc[g4], 0, 0, 0);
        acc[g4] = __builtin_amdgcn_mfma_f32_16x16x32_bf16(aH, bM, acc[g4], 0, 0, 0);
        acc[g4] = __builtin_amdgcn_mfma_f32_16x16x32_bf16(aM, bH, acc[g4], 0, 0, 0);
        acc[g4] = __builtin_amdgcn_mfma_f32_16x16x32_bf16(aM, bM, acc[g4], 0, 0, 0);
      }
    }
    __syncthreads();
  }
  const size_t N = (size_t)4 * COUT * HOUT * WOUT;
  #pragma unroll
  for (int g4 = 0; g4 < 4; ++g4) {
    int pxl = g4 * 16 + lr;
    int pidx = pxblk * 64 + pxl;
    if (pidx < NPX) {
      #pragma unroll
      for (int r = 0; r < 4; ++r) {
        int ocl = wv * 16 + lh * 4 + r;
        part[(size_t)spl * N +
             (((size_t)pb[pxl] * COUT + (oc0 + ocl)) * HOUT + pyA[pxl]) * WOUT + pxA[pxl]] =
            acc[g4][r];
      }
    }
  }
}

// ---------------- fallback conv (round-11 proven path) ----------------
template <int CIN, int HIN, int WIN, int COUT, int HOUT, int WOUT, int SPLIT>
__global__ __launch_bounds__(256) void k_convm(const float* __restrict__ x,
                                               const float* __restrict__ wsrc,
                                               float* __restrict__ part) {
  constexpr int NPX = 4 * HOUT * WOUT;
  constexpr int KTOT = (CIN * 9) / SPLIT;
  constexpr int NCH = KTOT / 64;
  __shared__ __align__(16) unsigned short Xs[2][64][64];
  __shared__ __align__(16) unsigned short Wsh[3][64][64];
  __shared__ int pb[64], pyA[64], pxA[64];
  const int tid = threadIdx.x;
  const int oc0 = blockIdx.y * 64, px0 = blockIdx.x * 64;
  const int spl = blockIdx.z;
  const int kg0 = spl * KTOT;
  if (tid < 64) {
    int p = px0 + tid;
    if (p > NPX - 1) p = NPX - 1;
    int hw = HOUT * WOUT;
    pb[tid] = p / hw;
    int r = p % hw;
    pyA[tid] = r / WOUT;
    pxA[tid] = r % WOUT;
  }
  f32x4 acc[4] = {};
  const int l = tid & 63, wv = tid >> 6;
  const int lr = l & 15, lh = l >> 4;
  __syncthreads();
  for (int ch = 0; ch < NCH; ++ch) {
    const int kbase = kg0 + ch * 64;
    #pragma unroll
    for (int j = 0; j < 2; ++j) {
      int c = tid + 256 * j;
      int oc = c >> 3, koct = c & 7;
      const float* wp = wsrc + (size_t)(oc0 + oc) * (CIN * 9) + kbase + koct * 8;
      float vv[8];
      *(float4*)&vv[0] = *(const float4*)wp;
      *(float4*)&vv[4] = *(const float4*)(wp + 4);
      short8m ph, pm, pl2;
      #pragma unroll
      for (int i = 0; i < 8; ++i) {
        unsigned short hb = bf16_trunc(vv[i]);
        float r = vv[i] - bf16_tof(hb);
        unsigned short mb = bf16_rte(r);
        float r2 = r - bf16_tof(mb);
        unsigned short lb = bf16_rte(r2);
        ph[i] = (short)hb; pm[i] = (short)mb; pl2[i] = (short)lb;
      }
      *ldsPtr(&Wsh[0][0][0], oc, koct * 16) = ph;
      *ldsPtr(&Wsh[1][0][0], oc, koct * 16) = pm;
      *ldsPtr(&Wsh[2][0][0], oc, koct * 16) = pl2;
    }
    #pragma unroll
    for (int j = 0; j < 2; ++j) {
      int c = tid + 256 * j;
      int px = c & 63, koct = c >> 6;
      int pbv = pb[px], py = pyA[px], pxv = pxA[px];
      float vv[8];
      #pragma unroll
      for (int i = 0; i < 8; ++i) {
        int k = kbase + koct * 8 + i;
        int ci = k / 9, tap = k - ci * 9;
        int iy = py * 2 - 1 + tap / 3, ix = pxv * 2 - 1 + (tap % 3);
        float v = 0.f;
        if ((unsigned)iy < (unsigned)HIN && (unsigned)ix < (unsigned)WIN)
          v = x[(((size_t)pbv * CIN + ci) * HIN + iy) * WIN + ix];
        vv[i] = v;
      }
      short8m ph, pm;
      #pragma unroll
      for (int i = 0; i < 8; ++i) {
        unsigned short hb = bf16_trunc(vv[i]);
        unsigned short mb = bf16_rte(vv[i] - bf16_tof(hb));
        ph[i] = (short)hb; pm[i] = (short)mb;
      }
      *ldsPtr(&Xs[0][0][0], px, koct * 16) = ph;
      *ldsPtr(&Xs[1][0][0], px, koct * 16) = pm;
    }
    __syncthreads();
    #pragma unroll
    for (int ks = 0; ks < 2; ++ks) {
      const int kbyte = ks * 64 + lh * 16;
      short8m aH = *ldsPtr(&Wsh[0][0][0], wv * 16 + lr, kbyte);
      short8m aM = *ldsPtr(&Wsh[1][0][0], wv * 16 + lr, kbyte);
      short8m aL = *ldsPtr(&Wsh[2][0][0], wv * 16 + lr, kbyte);
      #pragma unroll
      for (int g = 0; g < 4; ++g) {
        short8m bH = *ldsPtr(&Xs[0][0][0], g * 16 + lr, kbyte);
        short8m bM = *ldsPtr(&Xs[1][0][0], g * 16 + lr, kbyte);
        acc[g] = __builtin_amdgcn_mfma_f32_16x16x32_bf16(aH, bH, acc[g], 0, 0, 0);
        acc[g] = __builtin_amdgcn_mfma_f32_16x16x32_bf16(aH, bM, acc[g], 0, 0, 0);
        acc[g] = __builtin_amdgcn_mfma_f32_16x16x32_bf16(aM, bH, acc[g], 0, 0, 0);
        acc[g] = __builtin_amdgcn_mfma_f32_16x16x32_bf16(aM, bM, acc[g], 0, 0, 0);
        acc[g] = __builtin_amdgcn_mfma_f32_16x16x32_bf16(aL, bH, acc[g], 0, 0, 0);
      }
    }
    __syncthreads();
  }
  const size_t N = (size_t)4 * COUT * HOUT * WOUT;
  #pragma unroll
  for (int g = 0; g < 4; ++g) {
    int pxl = g * 16 + lr;
    int pidx = px0 + pxl;
    if (pidx < NPX) {
      #pragma unroll
      for (int r = 0; r < 4; ++r) {
        int ocl = wv * 16 + lh * 4 + r;
        part[(size_t)spl * N +
             (((size_t)pb[pxl] * COUT + (oc0 + ocl)) * HOUT + pyA[pxl]) * WOUT + pxA[pxl]] =
            acc[g][r];
      }
    }
  }
}

// ---------------- split-K reduction + ReLU ----------------
template <int SPLIT>
__global__ __launch_bounds__(256) void k_red(const float* __restrict__ part,
                                             float* __restrict__ y, int n) {
  for (int i = blockIdx.x * 256 + threadIdx.x; i < n; i += gridDim.x * 256) {
    float s = 0.f;
    #pragma unroll
    for (int sp = 0; sp < SPLIT; ++sp) s += part[(size_t)sp * n + i];
    y[i] = fmaxf(s, 0.f);
  }
}

// ---------------- global-max-pool (7x7): one thread per (b,ch) ----------------
__global__ __launch_bounds__(256) void k_pool(const float* __restrict__ feat,
                                              float* __restrict__ pool) {
  int idx = blockIdx.x * 256 + threadIdx.x;
  if (idx >= 8192) return;
  const float* fp = feat + (size_t)idx * 49;
  float m = fp[0];
  #pragma unroll
  for (int i = 1; i < 49; ++i) m = fmaxf(m, fp[i]);
  pool[idx] = m;
}

// ---------------- FC(2048->14) + sigmoid: one block per (b,c) ----------------
__global__ __launch_bounds__(256) void k_fcsig(const float* __restrict__ pool,
                                               const float* __restrict__ fw,
                                               const float* __restrict__ fb,
                                               float* __restrict__ outp) {
  __shared__ float red[256];
  const int blk = blockIdx.x;       // b*14 + c
  const int b = blk / 14, c = blk % 14;
  const int tid = threadIdx.x;
  float s = 0.f;
  for (int k = tid; k < 2048; k += 256) s += pool[b * 2048 + k] * fw[c * 2048 + k];
  red[tid] = s;
  __syncthreads();
  for (int st = 128; st > 0; st >>= 1) {
    if (tid < st) red[tid] += red[tid + st];
    __syncthreads();
  }
  if (tid == 0) outp[b * 14 + c] = 1.f / (1.f + expf(-(red[0] + fb[c])));
}

// ---------------- heatmap stage A: per-(b,cell) channel max|.| ----------------
__global__ __launch_bounds__(256) void k_hm7a(const float* __restrict__ feat,
                                              float* __restrict__ hmr) {
  __shared__ float red[256];
  const int b = blockIdx.x / 49, cell = blockIdx.x % 49;
  const int tid = threadIdx.x;
  float m = 0.f;
  for (int ch = tid; ch < 2048; ch += 256)
    m = fmaxf(m, fabsf(feat[((size_t)b * 2048 + ch) * 49 + cell]));
  red[tid] = m;
  __syncthreads();
  for (int st = 128; st > 0; st >>= 1) {
    if (tid < st) red[tid] = fmaxf(red[tid], red[tid + st]);
    __syncthreads();
  }
  if (tid == 0) hmr[b * 49 + cell] = red[0];
}

// ---------------- heatmap stage B: per-sample min-max normalize ----------------
__global__ __launch_bounds__(64) void k_hm7b(const float* __restrict__ hmr,
                                             float* __restrict__ hm7) {
  __shared__ float h[49];
  const int b = blockIdx.x, tid = threadIdx.x;
  if (tid < 49) h[tid] = hmr[b * 49 + tid];
  __syncthreads();
  if (tid == 0) {
    float mn = h[0], mx = h[0];
    for (int i = 1; i < 49; ++i) {
      mn = fminf(mn, h[i]);
      mx = fmaxf(mx, h[i]);
    }
    for (int i = 0; i < 49; ++i) hm7[b * 49 + i] = (h[i] - mn) / (mx - mn);
  }
}

// ---------------- parallel CCL on mask runs + bbox of largest component ----------------
#define MAXR 8
#define NRUNS (224 * MAXR)
__global__ __launch_bounds__(256) void k_ccl(const float* __restrict__ hm7, float* __restrict__ bbox) {
  const int b = blockIdx.x, tid = threadIdx.x;
  __shared__ float h7[49];
  __shared__ short rx0[NRUNS], rx1[NRUNS];
  __shared__ short nr[224];
  __shared__ int lab[NRUNS];
  __shared__ int cnt[NRUNS], mid[NRUNS];
  __shared__ int rmn[NRUNS], rmx[NRUNS], cmn[NRUNS], cmx[NRUNS];
  __shared__ int chg, chg2;
  __shared__ int bestC[256], bestM[256], bestI[256];

  if (tid < 49) h7[tid] = hm7[b * 49 + tid];
  for (int i = tid; i < NRUNS; i += 256) {
    cnt[i] = 0; mid[i] = -1;
    rmn[i] = 1 << 30; rmx[i] = -1; cmn[i] = 1 << 30; cmx[i] = -1;
    lab[i] = i;
  }
  __syncthreads();
  if (tid < 224) {
    int yy = tid;
    float py = ((float)yy + 0.5f) * (7.f / 224.f) - 0.5f;
    py = fminf(fmaxf(py, 0.f), 6.f);
    int y0 = (int)floorf(py);
    if (y0 > 5) y0 = 5;
    float fy = py - (float)y0;
    int n = 0, start = -1;
    const int segLo[6] = {0, 48, 80, 112, 144, 176};
    const int segHi[6] = {48, 80, 112, 144, 176, 224};
    #pragma unroll
    for (int s = 0; s < 6; ++s) {
      float A = h7[y0 * 7 + s], B = h7[y0 * 7 + s + 1];
      float C = h7[(y0 + 1) * 7 + s], D = h7[(y0 + 1) * 7 + s + 1];
      for (int xx = segLo[s]; xx < segHi[s]; ++xx) {
        float px = ((float)xx + 0.5f) * (7.f / 224.f) - 0.5f;
        px = fminf(fmaxf(px, 0.f), 6.f);
        float fx = px - (float)s;
        float v = (1.f - fy) * ((1.f - fx) * A + fx * B) +
                  fy * ((1.f - fx) * C + fx * D);
        bool m = v > 0.7f;
        if (m && start < 0) start = xx;
        if (!m && start >= 0) {
          if (n < MAXR) { rx0[yy * MAXR + n] = (short)start; rx1[yy * MAXR + n] = (short)(xx - 1); n++; }
          start = -1;
        }
      }
    }
    if (start >= 0 && n < MAXR) { rx0[yy * MAXR + n] = (short)start; rx1[yy * MAXR + n] = 223; n++; }
    nr[yy] = (short)n;
  }
  __syncthreads();
  int myA0[7], myA1[7];
  bool myV[7];
  #pragma unroll
  for (int j = 0; j < 7; ++j) {
    int i = tid + j * 256;
    int yy = i >> 3, k = i & 7;
    bool v = (k < (int)nr[yy]);
    myV[j] = v;
    myA0[j] = v ? (int)rx0[i] : 0;
    myA1[j] = v ? (int)rx1[i] : 0;
  }
  for (int outer = 0; outer < 48; ++outer) {
    if (tid == 0) chg = 0;
    __syncthreads();
    bool any = false;
    #pragma unroll
    for (int j = 0; j < 7; ++j) {
      if (!myV[j]) continue;
      int i = tid + j * 256;
      int yy = i >> 3;
      int a0 = myA0[j], a1 = myA1[j];
      int ri = lab[i];
      if (yy > 0) {
        int n1 = nr[yy - 1];
        for (int kk = 0; kk < n1; ++kk) {
          int q = ((yy - 1) << 3) + kk;
          if (a0 <= rx1[q] + 1 && a1 >= rx0[q] - 1) {
            int rq = lab[q];
            if (rq < ri) { atomicMin(&lab[ri], rq); any = true; }
            else if (ri < rq) { atomicMin(&lab[rq], ri); any = true; }
          }
        }
      }
      if (yy < 223) {
        int n1 = nr[yy + 1];
        for (int kk = 0; kk < n1; ++kk) {
          int q = ((yy + 1) << 3) + kk;
          if (a0 <= rx1[q] + 1 && a1 >= rx0[q] - 1) {
            int rq = lab[q];
            if (rq < ri) { atomicMin(&lab[ri], rq); any = true; }
            else if (ri < rq) { atomicMin(&lab[rq], ri); any = true; }
          }
        }
      }
    }
    if (any) chg = 1;
    __syncthreads();
    for (int sc = 0; sc < 12; ++sc) {
      if (tid == 0) chg2 = 0;
      __syncthreads();
      bool a2 = false;
      #pragma unroll
      for (int j = 0; j < 7; ++j) {
        int i = tid + j * 256;
        int ll = lab[i];
        int l2 = lab[ll];
        if (l2 < ll) { lab[i] = l2; a2 = true; }
      }
      if (a2) chg2 = 1;
      __syncthreads();
      if (!chg2) break;
    }
    if (!chg) break;
  }
  for (int i = tid; i < NRUNS; i += 256) {
    int yy = i >> 3, k = i & 7;
    if (k >= (int)nr[yy]) continue;
    int r = lab[i];
    int a0 = rx0[i], a1 = rx1[i];
    atomicAdd(&cnt[r], a1 - a0 + 1);
    atomicMax(&mid[r], yy * 224 + a1 + 1);
    atomicMin(&rmn[r], yy);
    atomicMax(&rmx[r], yy);
    atomicMin(&cmn[r], a0);
    atomicMax(&cmx[r], a1);
  }
  __syncthreads();
  int bc = -1, bm = 0x7fffffff, bi = -1;
  for (int i = tid; i < NRUNS; i += 256) {
    if (cnt[i] > 0 && lab[i] == i) {
      if (cnt[i] > bc || (cnt[i] == bc && mid[i] < bm)) { bc = cnt[i]; bm = mid[i]; bi = i; }
    }
  }
  bestC[tid] = bc; bestM[tid] = bm; bestI[tid] = bi;
  __syncthreads();
  for (int st = 128; st > 0; st >>= 1) {
    if (tid < st) {
      if (bestC[tid + st] > bestC[tid] ||
          (bestC[tid + st] == bestC[tid] && bestM[tid + st] < bestM[tid])) {
        bestC[tid] = bestC[tid + st]; bestM[tid] = bestM[tid + st]; bestI[tid] = bestI[tid + st];
      }
    }
    __syncthreads();
  }
  if (tid == 0) {
    int bw = bestI[0];
    float fy0, chf, fx0, cwf;
    if (bw < 0) { fy0 = 224.f; chf = 1.f; fx0 = 224.f; cwf = 1.f; }
    else {
      int dr = rmx[bw] - rmn[bw]; if (dr < 1) dr = 1;
      int dc = cmx[bw] - cmn[bw]; if (dc < 1) dc = 1;
      fy0 = (float)rmn[bw]; chf = (float)dr;
      fx0 = (float)cmn[bw]; cwf = (float)dc;
    }
    bbox[b * 4 + 0] = fy0; bbox[b * 4 + 1] = chf;
    bbox[b * 4 + 2] = fx0; bbox[b * 4 + 3] = cwf;
  }
}

// ---------------- bilinear crop-resize back to 224x224 ----------------
__global__ __launch_bounds__(256) void k_sample(const float* __restrict__ img,
                                                const float* __restrict__ bbox,
                                                float* __restrict__ patch_out,
                                                float* __restrict__ patch_ws) {
  int idx = blockIdx.x * 256 + threadIdx.x;
  if (idx >= 4 * 3 * 224 * 224) return;
  int b = idx / (3 * 224 * 224);
  int r = idx % (3 * 224 * 224);
  int c = r / (224 * 224);
  int p = r % (224 * 224);
  int oy = p / 224, ox = p % 224;
  float fy0 = bbox[b * 4 + 0], chf = bbox[b * 4 + 1];
  float fx0 = bbox[b * 4 + 2], cwf = bbox[b * 4 + 3];
  float gy = ((float)oy + 0.5f) * (chf / 224.f) + fy0 - 0.5f;
  float gx = ((float)ox + 0.5f) * (cwf / 224.f) + fx0 - 0.5f;
  gy = fminf(fmaxf(gy, fy0), fmaxf(fy0 + chf - 1.f, fy0));
  gx = fminf(fmaxf(gx, fx0), fmaxf(fx0 + cwf - 1.f, fx0));
  int y0 = (int)floorf(gy);
  int x0 = (int)floorf(gx);
  float fy = gy - (float)y0, fx = gx - (float)x0;
  int y0c = min(max(y0, 0), 223), y1c = min(max(y0 + 1, 0), 223);
  int x0c = min(max(x0, 0), 223), x1c = min(max(x0 + 1, 0), 223);
  const float* ip = img + ((size_t)b * 3 + c) * 224 * 224;
  float v00 = ip[y0c * 224 + x0c], v01 = ip[y0c * 224 + x1c];
  float v10 = ip[y1c * 224 + x0c], v11 = ip[y1c * 224 + x1c];
  float v = (1.f - fy) * ((1.f - fx) * v00 + fx * v01) + fy * ((1.f - fx) * v10 + fx * v11);
  patch_out[idx] = v;
  patch_ws[idx] = v;
}

// ---------------- out_f = sigmoid([pool_g|pool_l] @ fw.T + fb); loss = weighted BCEs ----------------
__global__ __launch_bounds__(256) void k_final(const float* __restrict__ poolg,
                                               const float* __restrict__ pooll,
                                               const float* __restrict__ fw,
                                               const float* __restrict__ fb,
                                               const float* __restrict__ target,
                                               float* __restrict__ dout) {
  __shared__ float outf[56];
  __shared__ float red[256];
  const int tid = threadIdx.x;
  int pair = tid >> 2, l4 = tid & 3;
  if (pair < 56) {
    int bb = pair / 14, c = pair % 14;
    const float* w = fw + (size_t)c * 4096;
    float s = 0.f;
    for (int k = l4; k < 2048; k += 4) s += poolg[bb * 2048 + k] * w[k];
    for (int k = l4; k < 2048; k += 4) s += pooll[bb * 2048 + k] * w[2048 + k];
    s += __shfl_down(s, 2, 4);
    s += __shfl_down(s, 1, 4);
    if (l4 == 0) {
      float o = 1.f / (1.f + expf(-(s + fb[c])));
      outf[pair] = o;
      dout[113 + pair] = o;
    }
  }
  __syncthreads();
  float term = 0.f;
  if (tid < 56) {
    float t = target[tid];
    float pg = dout[1 + tid], plo = dout[57 + tid], pf = outf[tid];
    auto bce1 = [&](float pp) {
      pp = fminf(fmaxf(pp, 1e-7f), 1.f - 1e-7f);
      return -(t * logf(pp) + (1.f - t) * log1pf(-pp));
    };
    term = (0.8f * bce1(pg) + 0.1f * bce1(plo) + 0.1f * bce1(pf)) * (1.f / 56.f);
  }
  red[tid] = term;
  __syncthreads();
  for (int st = 128; st > 0; st >>= 1) {
    if (tid < st) red[tid] += red[tid + st];
    __syncthreads();
  }
  if (tid == 0) dout[0] = red[0];
}

extern "C" void kernel_launch(void* const* d_in, const int* in_sizes, int n_in,
                              void* d_out, int out_size, void* d_ws, size_t ws_size,
                              hipStream_t stream) {
  const float* img = (const float*)d_in[0];
  const float* target = (const float*)d_in[1];
  const float* gw0 = (const float*)d_in[2];
  const float* gw1 = (const float*)d_in[3];
  const float* gw2 = (const float*)d_in[4];
  const float* gw3 = (const float*)d_in[5];
  const float* gfw = (const float*)d_in[6];
  const float* gfb = (const float*)d_in[7];
  const float* lw0 = (const float*)d_in[8];
  const float* lw1 = (const float*)d_in[9];
  const float* lw2 = (const float*)d_in[10];
  const float* lw3 = (const float*)d_in[11];
  const float* lfw = (const float*)d_in[12];
  const float* lfb = (const float*)d_in[13];
  const float* fw = (const float*)d_in[14];
  const float* fb = (const float*)d_in[15];
  float* out = (float*)d_out;
  float* ws = (float*)d_ws;

  float* c1 = ws;                    // 802816   [4,64,56,56]
  float* c2 = c1 + 802816;           // 1605632  [4,512,28,28]
  float* c3 = c2 + 1605632;          // 802816   [4,1024,14,14]
  float* c4 = c3 + 802816;           // 401408   [4,2048,7,7]
  float* poolg = c4 + 401408;        // 8192
  float* pooll = poolg + 8192;       // 8192
  float* hm7 = pooll + 8192;         // 196
  float* hmr = hm7 + 196;            // 196
  float* bbox = hmr + 196;           // 16
  float* patch = ws + 3629568;       // 602112 (16B aligned)
  float* part = ws + 4231680;        // <=3211264 split-K partials
  unsigned short* XgH = (unsigned short*)(ws + 7442944);   // fast path only
  unsigned short* XgM = XgH + 3840000;

  const bool fast = ws_size >= (size_t)45131776;

  dim3 g7(13, 256);
  const int rg2 = 2048, rg3 = 2048, rg4 = 1568;

  for (int pass = 0; pass < 2; ++pass) {
    const float* w0 = pass ? lw0 : gw0;
    const float* w1 = pass ? lw1 : gw1;
    const float* w2 = pass ? lw2 : gw2;
    const float* w3 = pass ? lw3 : gw3;
    const float* fwp = pass ? lfw : gfw;
    const float* fbp = pass ? lfb : gfb;
    const float* inp = pass ? patch : img;
    float* pool = pass ? pooll : poolg;
    float* outp = pass ? (out + 57) : (out + 1);

    k_conv7<<<g7, 256, 0, stream>>>(inp, w0, c1);
    if (fast) {
      k_im2col<64, 56, 56, 28, 28><<<882, 256, 0, stream>>>(c1, XgH, XgM);
      k_gemmx<512, 28, 28, 576, 1><<<dim3(49, 8, 1), 256, 0, stream>>>(XgH, XgM, w1, part);
      k_red<1><<<rg2, 256, 0, stream>>>(part, c2, 1605632);
      k_im2col<512, 28, 28, 14, 14><<<1872, 256, 0, stream>>>(c2, XgH, XgM);
      k_gemmx<1024, 14, 14, 4608, 4><<<dim3(13, 16, 4), 256, 0, stream>>>(XgH, XgM, w2, part);
      k_red<4><<<rg3, 256, 0, stream>>>(part, c3, 802816);
      k_im2col<1024, 14, 14, 7, 7><<<1152, 256, 0, stream>>>(c3, XgH, XgM);
      k_gemmx<2048, 7, 7, 9216, 8><<<dim3(4, 32, 8), 256, 0, stream>>>(XgH, XgM, w3, part);
      k_red<8><<<rg4, 256, 0, stream>>>(part, c4, 401408);
    } else {
      k_convm<64, 56, 56, 512, 28, 28, 1><<<dim3(49, 8, 1), 256, 0, stream>>>(c1, w1, part);
      k_red<1><<<rg2, 256, 0, stream>>>(part, c2, 1605632);
      k_convm<512, 28, 28, 1024, 14, 14, 4><<<dim3(13, 16, 4), 256, 0, stream>>>(c2, w2, part);
      k_red<4><<<rg3, 256, 0, stream>>>(part, c3, 802816);
      k_convm<1024, 14, 14, 2048, 7, 7, 8><<<dim3(4, 32, 8), 256, 0, stream>>>(c3, w3, part);
      k_red<8><<<rg4, 256, 0, stream>>>(part, c4, 401408);
    }
    k_pool<<<32, 256, 0, stream>>>(c4, pool);
    k_fcsig<<<56, 256, 0, stream>>>(pool, fwp, fbp, outp);

    if (pass == 0) {
      k_hm7a<<<196, 256, 0, stream>>>(c4, hmr);
      k_hm7b<<<4, 64, 0, stream>>>(hmr, hm7);
      k_ccl<<<4, 256, 0, stream>>>(hm7, bbox);
      k_sample<<<2352, 256, 0, stream>>>(img, bbox, out + 169, patch);
    }
  }
  k_final<<<1, 256, 0, stream>>>(poolg, pooll, fw, fb, target, out);
}

// Round 13
// 517.969 us; speedup vs baseline: 7.6904x; 1.4006x over previous
//
#include <hip/hip_runtime.h>
#include <math.h>

typedef __attribute__((ext_vector_type(8))) short short8m;   // 8 bf16 (4 VGPRs)
typedef __attribute__((ext_vector_type(4))) float f32x4;

__device__ inline unsigned short bf16_trunc(float f) {
  return (unsigned short)(__float_as_uint(f) >> 16);
}
__device__ inline unsigned short bf16_rte(float f) {
  unsigned u = __float_as_uint(f);
  u += 0x7fffu + ((u >> 16) & 1u);
  return (unsigned short)(u >> 16);
}
__device__ inline float bf16_tof(unsigned short h) {
  return __uint_as_float(((unsigned)h) << 16);
}
// LDS XOR-swizzle for W tiles: row pitch 128B; byte ^= ((row&7)<<4) -> conflict-free b128 r/w
__device__ inline short8m* ldsPtr(unsigned short* base, int row, int byteInRow) {
  int off = (row * 128 + byteInRow) ^ ((row & 7) << 4);
  return (short8m*)((char*)base + off);
}
__device__ inline void gload16_lds(const void* g, void* d) {
  __builtin_amdgcn_global_load_lds((const __attribute__((address_space(1))) unsigned int*)g,
                                   (__attribute__((address_space(3))) unsigned int*)d, 16, 0, 0);
}

// ---------------- conv 7x7 direct (fallback path only) ----------------
__global__ __launch_bounds__(256) void k_conv7(const float* __restrict__ x,
                                               const float* __restrict__ w,
                                               float* __restrict__ y) {
  __shared__ float ws[147];
  const int boc = blockIdx.y;
  const int oc = boc & 63;
  const int b = boc >> 6;
  for (int i = threadIdx.x; i < 147; i += 256) ws[i] = w[oc * 147 + i];
  __syncthreads();
  int px = blockIdx.x * 256 + threadIdx.x;
  if (px >= 56 * 56) return;
  int oy = px / 56, ox = px % 56;
  int iy0 = oy * 4 - 3, ix0 = ox * 4 - 3;
  float acc = 0.f;
  for (int c = 0; c < 3; ++c) {
    const float* xp = x + ((size_t)(b * 3 + c)) * 224 * 224;
    #pragma unroll
    for (int ky = 0; ky < 7; ++ky) {
      int iy = iy0 + ky;
      if ((unsigned)iy < 224u) {
        #pragma unroll
        for (int kx = 0; kx < 7; ++kx) {
          int ix = ix0 + kx;
          if ((unsigned)ix < 224u)
            acc += xp[iy * 224 + ix] * ws[c * 49 + ky * 7 + kx];
        }
      }
    }
  }
  y[((size_t)boc * 56 + oy) * 56 + ox] = fmaxf(acc, 0.f);
}

// ---------------- zero-pad weights along K: wp[oc][KTOT], wp[k>=KREAL]=0 ----------------
__global__ __launch_bounds__(256) void k_padw(const float* __restrict__ w,
                                              float* __restrict__ wp,
                                              int kreal, int ktot, int noc) {
  int i = blockIdx.x * 256 + threadIdx.x;
  if (i >= noc * ktot) return;
  int oc = i / ktot, k = i % ktot;
  wp[i] = (k < kreal) ? w[oc * kreal + k] : 0.f;
}

// ---------------- generic im2col + 2-plane bf16 split, block-tiled layout ----------------
// Xg element (px,k) at pxblk*KTOT*64 + (k>>3)*512 + pxin*8 + (k&7) (ushort units).
// k = ci*KH*KW + tap (ci >= CIN -> zero pad, for KTOT rounded up to 64).
template <int CIN, int HIN, int WIN, int HOUT, int WOUT, int KH, int KW, int STR, int PAD, int KTOT>
__global__ __launch_bounds__(256) void k_im2col(const float* __restrict__ x,
                                                unsigned short* __restrict__ XgH,
                                                unsigned short* __restrict__ XgM) {
  constexpr int NPX = 4 * HOUT * WOUT;
  constexpr int K8 = KTOT / 8;
  constexpr int KK = KH * KW;
  int u = blockIdx.x * 256 + threadIdx.x;
  int pxin = u & 63;
  int k8 = (u >> 6) % K8;
  int pxblk = (u >> 6) / K8;
  int px = pxblk * 64 + pxin;
  if (px > NPX - 1) px = NPX - 1;          // pad replication
  const int hw = HOUT * WOUT;
  int pbv = px / hw;
  int r = px % hw;
  int py = r / WOUT, pxv = r % WOUT;
  short8m ph, pm;
  #pragma unroll
  for (int i = 0; i < 8; ++i) {
    int k = k8 * 8 + i;
    int ci = k / KK, tap = k - ci * KK;
    float v = 0.f;
    if (ci < CIN) {
      int iy = py * STR - PAD + tap / KW, ix = pxv * STR - PAD + (tap % KW);
      if ((unsigned)iy < (unsigned)HIN && (unsigned)ix < (unsigned)WIN)
        v = x[(((size_t)pbv * CIN + ci) * HIN + iy) * WIN + ix];
    }
    unsigned short hb = bf16_trunc(v);
    unsigned short mb = bf16_rte(v - bf16_tof(hb));
    ph[i] = (short)hb; pm[i] = (short)mb;
  }
  size_t off = (size_t)u * 8;
  *(short8m*)(XgH + off) = ph;
  *(short8m*)(XgM + off) = pm;
}

// ---------------- GEMM on pre-im2col'd X: bf16 2x2-plane emulated f32 ----------------
// Block 64oc x 64px, 4 waves, mfma_f32_16x16x32_bf16, 4 products (HH,HM,MH,MM).
// X staged via global_load_lds (no VALU); W split in-kernel (trunc+rte).
template <int COUT, int HOUT, int WOUT, int KTOT, int SPLIT>
__global__ __launch_bounds__(256) void k_gemmx(const unsigned short* __restrict__ XgH,
                                               const unsigned short* __restrict__ XgM,
                                               const float* __restrict__ wsrc,
                                               float* __restrict__ part) {
  constexpr int NPX = 4 * HOUT * WOUT;
  constexpr int KCH = KTOT / SPLIT;
  constexpr int NCH = KCH / 64;
  __shared__ __align__(16) unsigned short XsH[4096];   // [8 koct][64 px][8 k] linear image
  __shared__ __align__(16) unsigned short XsM[4096];
  __shared__ __align__(16) unsigned short WsH[4096];   // swizzled [64 oc][64 k]
  __shared__ __align__(16) unsigned short WsM[4096];
  __shared__ int pb[64], pyA[64], pxA[64];
  const int tid = threadIdx.x;
  const int oc0 = blockIdx.y * 64;
  const int pxblk = blockIdx.x;
  const int spl = blockIdx.z;
  if (tid < 64) {
    int p = pxblk * 64 + tid;
    if (p > NPX - 1) p = NPX - 1;
    int hw = HOUT * WOUT;
    pb[tid] = p / hw;
    int r = p % hw;
    pyA[tid] = r / WOUT;
    pxA[tid] = r % WOUT;
  }
  f32x4 acc[4] = {};
  const int l = tid & 63, wv = tid >> 6;
  const int lr = l & 15, lh = l >> 4;
  __syncthreads();
  for (int ch = 0; ch < NCH; ++ch) {
    const int kbase = spl * KCH + ch * 64;
    // ---- X: 16 async 1KB slabs (2 planes x 8 koct), 4 per wave ----
    const size_t tileOff = (size_t)pxblk * KTOT * 64 + (size_t)kbase * 64;
    #pragma unroll
    for (int t = 0; t < 4; ++t) {
      int ins = wv * 4 + t;
      int pl = ins >> 3, ko = ins & 7;
      const unsigned short* g = (pl ? XgM : XgH) + tileOff + ko * 512 + l * 8;
      unsigned short* d = (pl ? XsM : XsH) + ko * 512;
      gload16_lds(g, d);
    }
    // ---- W: 2-plane split, swizzled LDS ----
    #pragma unroll
    for (int j = 0; j < 2; ++j) {
      int c = tid + 256 * j;
      int oc = c >> 3, koct = c & 7;
      const float* wp = wsrc + (size_t)(oc0 + oc) * KTOT + kbase + koct * 8;
      float vv[8];
      *(float4*)&vv[0] = *(const float4*)wp;
      *(float4*)&vv[4] = *(const float4*)(wp + 4);
      short8m ph, pm;
      #pragma unroll
      for (int i = 0; i < 8; ++i) {
        unsigned short hb = bf16_trunc(vv[i]);
        unsigned short mb = bf16_rte(vv[i] - bf16_tof(hb));
        ph[i] = (short)hb; pm[i] = (short)mb;
      }
      *ldsPtr(WsH, oc, koct * 16) = ph;
      *ldsPtr(WsM, oc, koct * 16) = pm;
    }
    __syncthreads();                       // drains vmcnt (global_load_lds) + lgkm
    // ---- MFMA: 2 k-steps of 32, 4 px groups, 4 products ----
    #pragma unroll
    for (int ks = 0; ks < 2; ++ks) {
      const int kbyte = ks * 64 + lh * 16;
      short8m aH = *ldsPtr(WsH, wv * 16 + lr, kbyte);
      short8m aM = *ldsPtr(WsM, wv * 16 + lr, kbyte);
      const int xoff = (ks * 4 + lh) * 512;
      #pragma unroll
      for (int g4 = 0; g4 < 4; ++g4) {
        short8m bH = *(const short8m*)(XsH + xoff + (g4 * 16 + lr) * 8);
        short8m bM = *(const short8m*)(XsM + xoff + (g4 * 16 + lr) * 8);
        acc[g4] = __builtin_amdgcn_mfma_f32_16x16x32_bf16(aH, bH, acc[g4], 0, 0, 0);
        acc[g4] = __builtin_amdgcn_mfma_f32_16x16x32_bf16(aH, bM, acc[g4], 0, 0, 0);
        acc[g4] = __builtin_amdgcn_mfma_f32_16x16x32_bf16(aM, bH, acc[g4], 0, 0, 0);
        acc[g4] = __builtin_amdgcn_mfma_f32_16x16x32_bf16(aM, bM, acc[g4], 0, 0, 0);
      }
    }
    __syncthreads();
  }
  const size_t N = (size_t)4 * COUT * HOUT * WOUT;
  #pragma unroll
  for (int g4 = 0; g4 < 4; ++g4) {
    int pxl = g4 * 16 + lr;
    int pidx = pxblk * 64 + pxl;
    if (pidx < NPX) {
      #pragma unroll
      for (int r = 0; r < 4; ++r) {
        int ocl = wv * 16 + lh * 4 + r;
        part[(size_t)spl * N +
             (((size_t)pb[pxl] * COUT + (oc0 + ocl)) * HOUT + pyA[pxl]) * WOUT + pxA[pxl]] =
            acc[g4][r];
      }
    }
  }
}

// ---------------- fallback conv (round-11 proven path) ----------------
template <int CIN, int HIN, int WIN, int COUT, int HOUT, int WOUT, int SPLIT>
__global__ __launch_bounds__(256) void k_convm(const float* __restrict__ x,
                                               const float* __restrict__ wsrc,
                                               float* __restrict__ part) {
  constexpr int NPX = 4 * HOUT * WOUT;
  constexpr int KTOT = (CIN * 9) / SPLIT;
  constexpr int NCH = KTOT / 64;
  __shared__ __align__(16) unsigned short Xs[2][64][64];
  __shared__ __align__(16) unsigned short Wsh[3][64][64];
  __shared__ int pb[64], pyA[64], pxA[64];
  const int tid = threadIdx.x;
  const int oc0 = blockIdx.y * 64, px0 = blockIdx.x * 64;
  const int spl = blockIdx.z;
  const int kg0 = spl * KTOT;
  if (tid < 64) {
    int p = px0 + tid;
    if (p > NPX - 1) p = NPX - 1;
    int hw = HOUT * WOUT;
    pb[tid] = p / hw;
    int r = p % hw;
    pyA[tid] = r / WOUT;
    pxA[tid] = r % WOUT;
  }
  f32x4 acc[4] = {};
  const int l = tid & 63, wv = tid >> 6;
  const int lr = l & 15, lh = l >> 4;
  __syncthreads();
  for (int ch = 0; ch < NCH; ++ch) {
    const int kbase = kg0 + ch * 64;
    #pragma unroll
    for (int j = 0; j < 2; ++j) {
      int c = tid + 256 * j;
      int oc = c >> 3, koct = c & 7;
      const float* wp = wsrc + (size_t)(oc0 + oc) * (CIN * 9) + kbase + koct * 8;
      float vv[8];
      *(float4*)&vv[0] = *(const float4*)wp;
      *(float4*)&vv[4] = *(const float4*)(wp + 4);
      short8m ph, pm, pl2;
      #pragma unroll
      for (int i = 0; i < 8; ++i) {
        unsigned short hb = bf16_trunc(vv[i]);
        float r = vv[i] - bf16_tof(hb);
        unsigned short mb = bf16_rte(r);
        float r2 = r - bf16_tof(mb);
        unsigned short lb = bf16_rte(r2);
        ph[i] = (short)hb; pm[i] = (short)mb; pl2[i] = (short)lb;
      }
      *ldsPtr(&Wsh[0][0][0], oc, koct * 16) = ph;
      *ldsPtr(&Wsh[1][0][0], oc, koct * 16) = pm;
      *ldsPtr(&Wsh[2][0][0], oc, koct * 16) = pl2;
    }
    #pragma unroll
    for (int j = 0; j < 2; ++j) {
      int c = tid + 256 * j;
      int px = c & 63, koct = c >> 6;
      int pbv = pb[px], py = pyA[px], pxv = pxA[px];
      float vv[8];
      #pragma unroll
      for (int i = 0; i < 8; ++i) {
        int k = kbase + koct * 8 + i;
        int ci = k / 9, tap = k - ci * 9;
        int iy = py * 2 - 1 + tap / 3, ix = pxv * 2 - 1 + (tap % 3);
        float v = 0.f;
        if ((unsigned)iy < (unsigned)HIN && (unsigned)ix < (unsigned)WIN)
          v = x[(((size_t)pbv * CIN + ci) * HIN + iy) * WIN + ix];
        vv[i] = v;
      }
      short8m ph, pm;
      #pragma unroll
      for (int i = 0; i < 8; ++i) {
        unsigned short hb = bf16_trunc(vv[i]);
        unsigned short mb = bf16_rte(vv[i] - bf16_tof(hb));
        ph[i] = (short)hb; pm[i] = (short)mb;
      }
      *ldsPtr(&Xs[0][0][0], px, koct * 16) = ph;
      *ldsPtr(&Xs[1][0][0], px, koct * 16) = pm;
    }
    __syncthreads();
    #pragma unroll
    for (int ks = 0; ks < 2; ++ks) {
      const int kbyte = ks * 64 + lh * 16;
      short8m aH = *ldsPtr(&Wsh[0][0][0], wv * 16 + lr, kbyte);
      short8m aM = *ldsPtr(&Wsh[1][0][0], wv * 16 + lr, kbyte);
      short8m aL = *ldsPtr(&Wsh[2][0][0], wv * 16 + lr, kbyte);
      #pragma unroll
      for (int g = 0; g < 4; ++g) {
        short8m bH = *ldsPtr(&Xs[0][0][0], g * 16 + lr, kbyte);
        short8m bM = *ldsPtr(&Xs[1][0][0], g * 16 + lr, kbyte);
        acc[g] = __builtin_amdgcn_mfma_f32_16x16x32_bf16(aH, bH, acc[g], 0, 0, 0);
        acc[g] = __builtin_amdgcn_mfma_f32_16x16x32_bf16(aH, bM, acc[g], 0, 0, 0);
        acc[g] = __builtin_amdgcn_mfma_f32_16x16x32_bf16(aM, bH, acc[g], 0, 0, 0);
        acc[g] = __builtin_amdgcn_mfma_f32_16x16x32_bf16(aM, bM, acc[g], 0, 0, 0);
        acc[g] = __builtin_amdgcn_mfma_f32_16x16x32_bf16(aL, bH, acc[g], 0, 0, 0);
      }
    }
    __syncthreads();
  }
  const size_t N = (size_t)4 * COUT * HOUT * WOUT;
  #pragma unroll
  for (int g = 0; g < 4; ++g) {
    int pxl = g * 16 + lr;
    int pidx = px0 + pxl;
    if (pidx < NPX) {
      #pragma unroll
      for (int r = 0; r < 4; ++r) {
        int ocl = wv * 16 + lh * 4 + r;
        part[(size_t)spl * N +
             (((size_t)pb[pxl] * COUT + (oc0 + ocl)) * HOUT + pyA[pxl]) * WOUT + pxA[pxl]] =
            acc[g][r];
      }
    }
  }
}

// ---------------- split-K reduction + ReLU ----------------
template <int SPLIT>
__global__ __launch_bounds__(256) void k_red(const float* __restrict__ part,
                                             float* __restrict__ y, int n) {
  for (int i = blockIdx.x * 256 + threadIdx.x; i < n; i += gridDim.x * 256) {
    float s = 0.f;
    #pragma unroll
    for (int sp = 0; sp < SPLIT; ++sp) s += part[(size_t)sp * n + i];
    y[i] = fmaxf(s, 0.f);
  }
}

// ---------------- global-max-pool (7x7): one thread per (b,ch) ----------------
__global__ __launch_bounds__(256) void k_pool(const float* __restrict__ feat,
                                              float* __restrict__ pool) {
  int idx = blockIdx.x * 256 + threadIdx.x;
  if (idx >= 8192) return;
  const float* fp = feat + (size_t)idx * 49;
  float m = fp[0];
  #pragma unroll
  for (int i = 1; i < 49; ++i) m = fmaxf(m, fp[i]);
  pool[idx] = m;
}

// ---------------- FC(2048->14) + sigmoid: one block per (b,c) ----------------
__global__ __launch_bounds__(256) void k_fcsig(const float* __restrict__ pool,
                                               const float* __restrict__ fw,
                                               const float* __restrict__ fb,
                                               float* __restrict__ outp) {
  __shared__ float red[256];
  const int blk = blockIdx.x;       // b*14 + c
  const int b = blk / 14, c = blk % 14;
  const int tid = threadIdx.x;
  float s = 0.f;
  for (int k = tid; k < 2048; k += 256) s += pool[b * 2048 + k] * fw[c * 2048 + k];
  red[tid] = s;
  __syncthreads();
  for (int st = 128; st > 0; st >>= 1) {
    if (tid < st) red[tid] += red[tid + st];
    __syncthreads();
  }
  if (tid == 0) outp[b * 14 + c] = 1.f / (1.f + expf(-(red[0] + fb[c])));
}

// ---------------- heatmap stage A: per-(b,cell) channel max|.| ----------------
__global__ __launch_bounds__(256) void k_hm7a(const float* __restrict__ feat,
                                              float* __restrict__ hmr) {
  __shared__ float red[256];
  const int b = blockIdx.x / 49, cell = blockIdx.x % 49;
  const int tid = threadIdx.x;
  float m = 0.f;
  for (int ch = tid; ch < 2048; ch += 256)
    m = fmaxf(m, fabsf(feat[((size_t)b * 2048 + ch) * 49 + cell]));
  red[tid] = m;
  __syncthreads();
  for (int st = 128; st > 0; st >>= 1) {
    if (tid < st) red[tid] = fmaxf(red[tid], red[tid + st]);
    __syncthreads();
  }
  if (tid == 0) hmr[b * 49 + cell] = red[0];
}

// ---------------- heatmap stage B: per-sample min-max normalize ----------------
__global__ __launch_bounds__(64) void k_hm7b(const float* __restrict__ hmr,
                                             float* __restrict__ hm7) {
  __shared__ float h[49];
  const int b = blockIdx.x, tid = threadIdx.x;
  if (tid < 49) h[tid] = hmr[b * 49 + tid];
  __syncthreads();
  if (tid == 0) {
    float mn = h[0], mx = h[0];
    for (int i = 1; i < 49; ++i) {
      mn = fminf(mn, h[i]);
      mx = fmaxf(mx, h[i]);
    }
    for (int i = 0; i < 49; ++i) hm7[b * 49 + i] = (h[i] - mn) / (mx - mn);
  }
}

// ---------------- parallel CCL on mask runs + bbox of largest component ----------------
#define MAXR 8
#define NRUNS (224 * MAXR)
__global__ __launch_bounds__(256) void k_ccl(const float* __restrict__ hm7, float* __restrict__ bbox) {
  const int b = blockIdx.x, tid = threadIdx.x;
  __shared__ float h7[49];
  __shared__ short rx0[NRUNS], rx1[NRUNS];
  __shared__ short nr[224];
  __shared__ int lab[NRUNS];
  __shared__ int cnt[NRUNS], mid[NRUNS];
  __shared__ int rmn[NRUNS], rmx[NRUNS], cmn[NRUNS], cmx[NRUNS];
  __shared__ int chg, chg2;
  __shared__ int bestC[256], bestM[256], bestI[256];

  if (tid < 49) h7[tid] = hm7[b * 49 + tid];
  for (int i = tid; i < NRUNS; i += 256) {
    cnt[i] = 0; mid[i] = -1;
    rmn[i] = 1 << 30; rmx[i] = -1; cmn[i] = 1 << 30; cmx[i] = -1;
    lab[i] = i;
  }
  __syncthreads();
  if (tid < 224) {
    int yy = tid;
    float py = ((float)yy + 0.5f) * (7.f / 224.f) - 0.5f;
    py = fminf(fmaxf(py, 0.f), 6.f);
    int y0 = (int)floorf(py);
    if (y0 > 5) y0 = 5;
    float fy = py - (float)y0;
    int n = 0, start = -1;
    const int segLo[6] = {0, 48, 80, 112, 144, 176};
    const int segHi[6] = {48, 80, 112, 144, 176, 224};
    #pragma unroll
    for (int s = 0; s < 6; ++s) {
      float A = h7[y0 * 7 + s], B = h7[y0 * 7 + s + 1];
      float C = h7[(y0 + 1) * 7 + s], D = h7[(y0 + 1) * 7 + s + 1];
      for (int xx = segLo[s]; xx < segHi[s]; ++xx) {
        float px = ((float)xx + 0.5f) * (7.f / 224.f) - 0.5f;
        px = fminf(fmaxf(px, 0.f), 6.f);
        float fx = px - (float)s;
        float v = (1.f - fy) * ((1.f - fx) * A + fx * B) +
                  fy * ((1.f - fx) * C + fx * D);
        bool m = v > 0.7f;
        if (m && start < 0) start = xx;
        if (!m && start >= 0) {
          if (n < MAXR) { rx0[yy * MAXR + n] = (short)start; rx1[yy * MAXR + n] = (short)(xx - 1); n++; }
          start = -1;
        }
      }
    }
    if (start >= 0 && n < MAXR) { rx0[yy * MAXR + n] = (short)start; rx1[yy * MAXR + n] = 223; n++; }
    nr[yy] = (short)n;
  }
  __syncthreads();
  int myA0[7], myA1[7];
  bool myV[7];
  #pragma unroll
  for (int j = 0; j < 7; ++j) {
    int i = tid + j * 256;
    int yy = i >> 3, k = i & 7;
    bool v = (k < (int)nr[yy]);
    myV[j] = v;
    myA0[j] = v ? (int)rx0[i] : 0;
    myA1[j] = v ? (int)rx1[i] : 0;
  }
  for (int outer = 0; outer < 48; ++outer) {
    if (tid == 0) chg = 0;
    __syncthreads();
    bool any = false;
    #pragma unroll
    for (int j = 0; j < 7; ++j) {
      if (!myV[j]) continue;
      int i = tid + j * 256;
      int yy = i >> 3;
      int a0 = myA0[j], a1 = myA1[j];
      int ri = lab[i];
      if (yy > 0) {
        int n1 = nr[yy - 1];
        for (int kk = 0; kk < n1; ++kk) {
          int q = ((yy - 1) << 3) + kk;
          if (a0 <= rx1[q] + 1 && a1 >= rx0[q] - 1) {
            int rq = lab[q];
            if (rq < ri) { atomicMin(&lab[ri], rq); any = true; }
            else if (ri < rq) { atomicMin(&lab[rq], ri); any = true; }
          }
        }
      }
      if (yy < 223) {
        int n1 = nr[yy + 1];
        for (int kk = 0; kk < n1; ++kk) {
          int q = ((yy + 1) << 3) + kk;
          if (a0 <= rx1[q] + 1 && a1 >= rx0[q] - 1) {
            int rq = lab[q];
            if (rq < ri) { atomicMin(&lab[ri], rq); any = true; }
            else if (ri < rq) { atomicMin(&lab[rq], ri); any = true; }
          }
        }
      }
    }
    if (any) chg = 1;
    __syncthreads();
    for (int sc = 0; sc < 12; ++sc) {
      if (tid == 0) chg2 = 0;
      __syncthreads();
      bool a2 = false;
      #pragma unroll
      for (int j = 0; j < 7; ++j) {
        int i = tid + j * 256;
        int ll = lab[i];
        int l2 = lab[ll];
        if (l2 < ll) { lab[i] = l2; a2 = true; }
      }
      if (a2) chg2 = 1;
      __syncthreads();
      if (!chg2) break;
    }
    if (!chg) break;
  }
  for (int i = tid; i < NRUNS; i += 256) {
    int yy = i >> 3, k = i & 7;
    if (k >= (int)nr[yy]) continue;
    int r = lab[i];
    int a0 = rx0[i], a1 = rx1[i];
    atomicAdd(&cnt[r], a1 - a0 + 1);
    atomicMax(&mid[r], yy * 224 + a1 + 1);
    atomicMin(&rmn[r], yy);
    atomicMax(&rmx[r], yy);
    atomicMin(&cmn[r], a0);
    atomicMax(&cmx[r], a1);
  }
  __syncthreads();
  int bc = -1, bm = 0x7fffffff, bi = -1;
  for (int i = tid; i < NRUNS; i += 256) {
    if (cnt[i] > 0 && lab[i] == i) {
      if (cnt[i] > bc || (cnt[i] == bc && mid[i] < bm)) { bc = cnt[i]; bm = mid[i]; bi = i; }
    }
  }
  bestC[tid] = bc; bestM[tid] = bm; bestI[tid] = bi;
  __syncthreads();
  for (int st = 128; st > 0; st >>= 1) {
    if (tid < st) {
      if (bestC[tid + st] > bestC[tid] ||
          (bestC[tid + st] == bestC[tid] && bestM[tid + st] < bestM[tid])) {
        bestC[tid] = bestC[tid + st]; bestM[tid] = bestM[tid + st]; bestI[tid] = bestI[tid + st];
      }
    }
    __syncthreads();
  }
  if (tid == 0) {
    int bw = bestI[0];
    float fy0, chf, fx0, cwf;
    if (bw < 0) { fy0 = 224.f; chf = 1.f; fx0 = 224.f; cwf = 1.f; }
    else {
      int dr = rmx[bw] - rmn[bw]; if (dr < 1) dr = 1;
      int dc = cmx[bw] - cmn[bw]; if (dc < 1) dc = 1;
      fy0 = (float)rmn[bw]; chf = (float)dr;
      fx0 = (float)cmn[bw]; cwf = (float)dc;
    }
    bbox[b * 4 + 0] = fy0; bbox[b * 4 + 1] = chf;
    bbox[b * 4 + 2] = fx0; bbox[b * 4 + 3] = cwf;
  }
}

// ---------------- bilinear crop-resize back to 224x224 ----------------
__global__ __launch_bounds__(256) void k_sample(const float* __restrict__ img,
                                                const float* __restrict__ bbox,
                                                float* __restrict__ patch_out,
                                                float* __restrict__ patch_ws) {
  int idx = blockIdx.x * 256 + threadIdx.x;
  if (idx >= 4 * 3 * 224 * 224) return;
  int b = idx / (3 * 224 * 224);
  int r = idx % (3 * 224 * 224);
  int c = r / (224 * 224);
  int p = r % (224 * 224);
  int oy = p / 224, ox = p % 224;
  float fy0 = bbox[b * 4 + 0], chf = bbox[b * 4 + 1];
  float fx0 = bbox[b * 4 + 2], cwf = bbox[b * 4 + 3];
  float gy = ((float)oy + 0.5f) * (chf / 224.f) + fy0 - 0.5f;
  float gx = ((float)ox + 0.5f) * (cwf / 224.f) + fx0 - 0.5f;
  gy = fminf(fmaxf(gy, fy0), fmaxf(fy0 + chf - 1.f, fy0));
  gx = fminf(fmaxf(gx, fx0), fmaxf(fx0 + cwf - 1.f, fx0));
  int y0 = (int)floorf(gy);
  int x0 = (int)floorf(gx);
  float fy = gy - (float)y0, fx = gx - (float)x0;
  int y0c = min(max(y0, 0), 223), y1c = min(max(y0 + 1, 0), 223);
  int x0c = min(max(x0, 0), 223), x1c = min(max(x0 + 1, 0), 223);
  const float* ip = img + ((size_t)b * 3 + c) * 224 * 224;
  float v00 = ip[y0c * 224 + x0c], v01 = ip[y0c * 224 + x1c];
  float v10 = ip[y1c * 224 + x0c], v11 = ip[y1c * 224 + x1c];
  float v = (1.f - fy) * ((1.f - fx) * v00 + fx * v01) + fy * ((1.f - fx) * v10 + fx * v11);
  patch_out[idx] = v;
  patch_ws[idx] = v;
}

// ---------------- out_f = sigmoid([pool_g|pool_l] @ fw.T + fb); loss = weighted BCEs ----------------
__global__ __launch_bounds__(256) void k_final(const float* __restrict__ poolg,
                                               const float* __restrict__ pooll,
                                               const float* __restrict__ fw,
                                               const float* __restrict__ fb,
                                               const float* __restrict__ target,
                                               float* __restrict__ dout) {
  __shared__ float outf[56];
  __shared__ float red[256];
  const int tid = threadIdx.x;
  int pair = tid >> 2, l4 = tid & 3;
  if (pair < 56) {
    int bb = pair / 14, c = pair % 14;
    const float* w = fw + (size_t)c * 4096;
    float s = 0.f;
    for (int k = l4; k < 2048; k += 4) s += poolg[bb * 2048 + k] * w[k];
    for (int k = l4; k < 2048; k += 4) s += pooll[bb * 2048 + k] * w[2048 + k];
    s += __shfl_down(s, 2, 4);
    s += __shfl_down(s, 1, 4);
    if (l4 == 0) {
      float o = 1.f / (1.f + expf(-(s + fb[c])));
      outf[pair] = o;
      dout[113 + pair] = o;
    }
  }
  __syncthreads();
  float term = 0.f;
  if (tid < 56) {
    float t = target[tid];
    float pg = dout[1 + tid], plo = dout[57 + tid], pf = outf[tid];
    auto bce1 = [&](float pp) {
      pp = fminf(fmaxf(pp, 1e-7f), 1.f - 1e-7f);
      return -(t * logf(pp) + (1.f - t) * log1pf(-pp));
    };
    term = (0.8f * bce1(pg) + 0.1f * bce1(plo) + 0.1f * bce1(pf)) * (1.f / 56.f);
  }
  red[tid] = term;
  __syncthreads();
  for (int st = 128; st > 0; st >>= 1) {
    if (tid < st) red[tid] += red[tid + st];
    __syncthreads();
  }
  if (tid == 0) dout[0] = red[0];
}

extern "C" void kernel_launch(void* const* d_in, const int* in_sizes, int n_in,
                              void* d_out, int out_size, void* d_ws, size_t ws_size,
                              hipStream_t stream) {
  const float* img = (const float*)d_in[0];
  const float* target = (const float*)d_in[1];
  const float* gw0 = (const float*)d_in[2];
  const float* gw1 = (const float*)d_in[3];
  const float* gw2 = (const float*)d_in[4];
  const float* gw3 = (const float*)d_in[5];
  const float* gfw = (const float*)d_in[6];
  const float* gfb = (const float*)d_in[7];
  const float* lw0 = (const float*)d_in[8];
  const float* lw1 = (const float*)d_in[9];
  const float* lw2 = (const float*)d_in[10];
  const float* lw3 = (const float*)d_in[11];
  const float* lfw = (const float*)d_in[12];
  const float* lfb = (const float*)d_in[13];
  const float* fw = (const float*)d_in[14];
  const float* fb = (const float*)d_in[15];
  float* out = (float*)d_out;
  float* ws = (float*)d_ws;

  float* c1 = ws;                    // 802816   [4,64,56,56]
  float* c2 = c1 + 802816;           // 1605632  [4,512,28,28]
  float* c3 = c2 + 1605632;          // 802816   [4,1024,14,14]
  float* c4 = c3 + 802816;           // 401408   [4,2048,7,7]
  float* poolg = c4 + 401408;        // 8192
  float* pooll = poolg + 8192;       // 8192
  float* hm7 = pooll + 8192;         // 196
  float* hmr = hm7 + 196;            // 196
  float* bbox = hmr + 196;           // 16
  float* patch = ws + 3629568;       // 602112 (16B aligned)
  float* part = ws + 4231680;        // <=3211264 split-K partials
  float* Wp = part + 2800000;        // 12288 padded conv7 weights (dead corner of part)
  unsigned short* XgH = (unsigned short*)(ws + 7442944);   // fast path only
  unsigned short* XgM = XgH + 3840000;

  const bool fast = ws_size >= (size_t)45131776;

  dim3 g7(13, 256);
  const int rg1 = 2048, rg2 = 2048, rg3 = 2048, rg4 = 1568;

  for (int pass = 0; pass < 2; ++pass) {
    const float* w0 = pass ? lw0 : gw0;
    const float* w1 = pass ? lw1 : gw1;
    const float* w2 = pass ? lw2 : gw2;
    const float* w3 = pass ? lw3 : gw3;
    const float* fwp = pass ? lfw : gfw;
    const float* fbp = pass ? lfb : gfb;
    const float* inp = pass ? patch : img;
    float* pool = pass ? pooll : poolg;
    float* outp = pass ? (out + 57) : (out + 1);

    if (fast) {
      // conv7 as im2col GEMM (K=147 zero-padded to 192)
      k_padw<<<48, 256, 0, stream>>>(w0, Wp, 147, 192, 64);
      k_im2col<3, 224, 224, 56, 56, 7, 7, 4, 3, 192><<<1176, 256, 0, stream>>>(inp, XgH, XgM);
      k_gemmx<64, 56, 56, 192, 1><<<dim3(196, 1, 1), 256, 0, stream>>>(XgH, XgM, Wp, part);
      k_red<1><<<rg1, 256, 0, stream>>>(part, c1, 802816);
      k_im2col<64, 56, 56, 28, 28, 3, 3, 2, 1, 576><<<882, 256, 0, stream>>>(c1, XgH, XgM);
      k_gemmx<512, 28, 28, 576, 1><<<dim3(49, 8, 1), 256, 0, stream>>>(XgH, XgM, w1, part);
      k_red<1><<<rg2, 256, 0, stream>>>(part, c2, 1605632);
      k_im2col<512, 28, 28, 14, 14, 3, 3, 2, 1, 4608><<<1872, 256, 0, stream>>>(c2, XgH, XgM);
      k_gemmx<1024, 14, 14, 4608, 4><<<dim3(13, 16, 4), 256, 0, stream>>>(XgH, XgM, w2, part);
      k_red<4><<<rg3, 256, 0, stream>>>(part, c3, 802816);
      k_im2col<1024, 14, 14, 7, 7, 3, 3, 2, 1, 9216><<<1152, 256, 0, stream>>>(c3, XgH, XgM);
      k_gemmx<2048, 7, 7, 9216, 8><<<dim3(4, 32, 8), 256, 0, stream>>>(XgH, XgM, w3, part);
      k_red<8><<<rg4, 256, 0, stream>>>(part, c4, 401408);
    } else {
      k_conv7<<<g7, 256, 0, stream>>>(inp, w0, c1);
      k_convm<64, 56, 56, 512, 28, 28, 1><<<dim3(49, 8, 1), 256, 0, stream>>>(c1, w1, part);
      k_red<1><<<rg2, 256, 0, stream>>>(part, c2, 1605632);
      k_convm<512, 28, 28, 1024, 14, 14, 4><<<dim3(13, 16, 4), 256, 0, stream>>>(c2, w2, part);
      k_red<4><<<rg3, 256, 0, stream>>>(part, c3, 802816);
      k_convm<1024, 14, 14, 2048, 7, 7, 8><<<dim3(4, 32, 8), 256, 0, stream>>>(c3, w3, part);
      k_red<8><<<rg4, 256, 0, stream>>>(part, c4, 401408);
    }
    k_pool<<<32, 256, 0, stream>>>(c4, pool);
    k_fcsig<<<56, 256, 0, stream>>>(pool, fwp, fbp, outp);

    if (pass == 0) {
      k_hm7a<<<196, 256, 0, stream>>>(c4, hmr);
      k_hm7b<<<4, 64, 0, stream>>>(hmr, hm7);
      k_ccl<<<4, 256, 0, stream>>>(hm7, bbox);
      k_sample<<<2352, 256, 0, stream>>>(img, bbox, out + 169, patch);
    }
  }
  k_final<<<1, 256, 0, stream>>>(poolg, pooll, fw, fb, target, out);
}

// Round 14
// 436.643 us; speedup vs baseline: 9.1227x; 1.1863x over previous
//
#include <hip/hip_runtime.h>
#include <math.h>

typedef __attribute__((ext_vector_type(8))) short short8m;   // 8 bf16 (4 VGPRs)
typedef __attribute__((ext_vector_type(4))) float f32x4;

__device__ inline unsigned short bf16_trunc(float f) {
  return (unsigned short)(__float_as_uint(f) >> 16);
}
__device__ inline unsigned short bf16_rte(float f) {
  unsigned u = __float_as_uint(f);
  u += 0x7fffu + ((u >> 16) & 1u);
  return (unsigned short)(u >> 16);
}
__device__ inline float bf16_tof(unsigned short h) {
  return __uint_as_float(((unsigned)h) << 16);
}
// LDS XOR-swizzle for W tiles: row pitch 128B; byte ^= ((row&7)<<4) -> conflict-free b128 r/w
__device__ inline short8m* ldsPtr(unsigned short* base, int row, int byteInRow) {
  int off = (row * 128 + byteInRow) ^ ((row & 7) << 4);
  return (short8m*)((char*)base + off);
}
__device__ inline void gload16_lds(const void* g, void* d) {
  __builtin_amdgcn_global_load_lds((const __attribute__((address_space(1))) unsigned int*)g,
                                   (__attribute__((address_space(3))) unsigned int*)d, 16, 0, 0);
}

// ---------------- conv 7x7 direct (fallback path only) ----------------
__global__ __launch_bounds__(256) void k_conv7(const float* __restrict__ x,
                                               const float* __restrict__ w,
                                               float* __restrict__ y) {
  __shared__ float ws[147];
  const int boc = blockIdx.y;
  const int oc = boc & 63;
  const int b = boc >> 6;
  for (int i = threadIdx.x; i < 147; i += 256) ws[i] = w[oc * 147 + i];
  __syncthreads();
  int px = blockIdx.x * 256 + threadIdx.x;
  if (px >= 56 * 56) return;
  int oy = px / 56, ox = px % 56;
  int iy0 = oy * 4 - 3, ix0 = ox * 4 - 3;
  float acc = 0.f;
  for (int c = 0; c < 3; ++c) {
    const float* xp = x + ((size_t)(b * 3 + c)) * 224 * 224;
    #pragma unroll
    for (int ky = 0; ky < 7; ++ky) {
      int iy = iy0 + ky;
      if ((unsigned)iy < 224u) {
        #pragma unroll
        for (int kx = 0; kx < 7; ++kx) {
          int ix = ix0 + kx;
          if ((unsigned)ix < 224u)
            acc += xp[iy * 224 + ix] * ws[c * 49 + ky * 7 + kx];
        }
      }
    }
  }
  y[((size_t)boc * 56 + oy) * 56 + ox] = fmaxf(acc, 0.f);
}

// ---------------- zero-pad weights along K: wp[oc][KTOT], wp[k>=KREAL]=0 ----------------
__global__ __launch_bounds__(256) void k_padw(const float* __restrict__ w,
                                              float* __restrict__ wp,
                                              int kreal, int ktot, int noc) {
  int i = blockIdx.x * 256 + threadIdx.x;
  if (i >= noc * ktot) return;
  int oc = i / ktot, k = i % ktot;
  wp[i] = (k < kreal) ? w[oc * kreal + k] : 0.f;
}

// ---------------- generic im2col + 2-plane bf16 split, block-tiled layout ----------------
// Xg element (px,k) at pxblk*KTOT*64 + (k>>3)*512 + pxin*8 + (k&7) (ushort units).
// k = ci*KH*KW + tap (ci >= CIN -> zero pad, for KTOT rounded up to 64).
template <int CIN, int HIN, int WIN, int HOUT, int WOUT, int KH, int KW, int STR, int PAD, int KTOT>
__global__ __launch_bounds__(256) void k_im2col(const float* __restrict__ x,
                                                unsigned short* __restrict__ XgH,
                                                unsigned short* __restrict__ XgM) {
  constexpr int NPX = 4 * HOUT * WOUT;
  constexpr int K8 = KTOT / 8;
  constexpr int KK = KH * KW;
  int u = blockIdx.x * 256 + threadIdx.x;
  int pxin = u & 63;
  int k8 = (u >> 6) % K8;
  int pxblk = (u >> 6) / K8;
  int px = pxblk * 64 + pxin;
  if (px > NPX - 1) px = NPX - 1;          // pad replication
  const int hw = HOUT * WOUT;
  int pbv = px / hw;
  int r = px % hw;
  int py = r / WOUT, pxv = r % WOUT;
  short8m ph, pm;
  #pragma unroll
  for (int i = 0; i < 8; ++i) {
    int k = k8 * 8 + i;
    int ci = k / KK, tap = k - ci * KK;
    float v = 0.f;
    if (ci < CIN) {
      int iy = py * STR - PAD + tap / KW, ix = pxv * STR - PAD + (tap % KW);
      if ((unsigned)iy < (unsigned)HIN && (unsigned)ix < (unsigned)WIN)
        v = x[(((size_t)pbv * CIN + ci) * HIN + iy) * WIN + ix];
    }
    unsigned short hb = bf16_trunc(v);
    unsigned short mb = bf16_rte(v - bf16_tof(hb));
    ph[i] = (short)hb; pm[i] = (short)mb;
  }
  size_t off = (size_t)u * 8;
  *(short8m*)(XgH + off) = ph;
  *(short8m*)(XgM + off) = pm;
}

// ---------------- GEMM on pre-im2col'd X: bf16 2x2-plane emulated f32 ----------------
// Block 64oc x 64px, 4 waves, mfma_f32_16x16x32_bf16, 4 products (HH,HM,MH,MM).
// X staged via global_load_lds (no VALU); W split in-kernel (trunc+rte).
template <int COUT, int HOUT, int WOUT, int KTOT, int SPLIT>
__global__ __launch_bounds__(256) void k_gemmx(const unsigned short* __restrict__ XgH,
                                               const unsigned short* __restrict__ XgM,
                                               const float* __restrict__ wsrc,
                                               float* __restrict__ part) {
  constexpr int NPX = 4 * HOUT * WOUT;
  constexpr int KCH = KTOT / SPLIT;
  constexpr int NCH = KCH / 64;
  __shared__ __align__(16) unsigned short XsH[4096];   // [8 koct][64 px][8 k] linear image
  __shared__ __align__(16) unsigned short XsM[4096];
  __shared__ __align__(16) unsigned short WsH[4096];   // swizzled [64 oc][64 k]
  __shared__ __align__(16) unsigned short WsM[4096];
  __shared__ int pb[64], pyA[64], pxA[64];
  const int tid = threadIdx.x;
  const int oc0 = blockIdx.y * 64;
  const int pxblk = blockIdx.x;
  const int spl = blockIdx.z;
  if (tid < 64) {
    int p = pxblk * 64 + tid;
    if (p > NPX - 1) p = NPX - 1;
    int hw = HOUT * WOUT;
    pb[tid] = p / hw;
    int r = p % hw;
    pyA[tid] = r / WOUT;
    pxA[tid] = r % WOUT;
  }
  f32x4 acc[4] = {};
  const int l = tid & 63, wv = tid >> 6;
  const int lr = l & 15, lh = l >> 4;
  __syncthreads();
  for (int ch = 0; ch < NCH; ++ch) {
    const int kbase = spl * KCH + ch * 64;
    // ---- X: 16 async 1KB slabs (2 planes x 8 koct), 4 per wave ----
    const size_t tileOff = (size_t)pxblk * KTOT * 64 + (size_t)kbase * 64;
    #pragma unroll
    for (int t = 0; t < 4; ++t) {
      int ins = wv * 4 + t;
      int pl = ins >> 3, ko = ins & 7;
      const unsigned short* g = (pl ? XgM : XgH) + tileOff + ko * 512 + l * 8;
      unsigned short* d = (pl ? XsM : XsH) + ko * 512;
      gload16_lds(g, d);
    }
    // ---- W: 2-plane split, swizzled LDS ----
    #pragma unroll
    for (int j = 0; j < 2; ++j) {
      int c = tid + 256 * j;
      int oc = c >> 3, koct = c & 7;
      const float* wp = wsrc + (size_t)(oc0 + oc) * KTOT + kbase + koct * 8;
      float vv[8];
      *(float4*)&vv[0] = *(const float4*)wp;
      *(float4*)&vv[4] = *(const float4*)(wp + 4);
      short8m ph, pm;
      #pragma unroll
      for (int i = 0; i < 8; ++i) {
        unsigned short hb = bf16_trunc(vv[i]);
        unsigned short mb = bf16_rte(vv[i] - bf16_tof(hb));
        ph[i] = (short)hb; pm[i] = (short)mb;
      }
      *ldsPtr(WsH, oc, koct * 16) = ph;
      *ldsPtr(WsM, oc, koct * 16) = pm;
    }
    __syncthreads();                       // drains vmcnt (global_load_lds) + lgkm
    // ---- MFMA: 2 k-steps of 32, 4 px groups, 4 products ----
    #pragma unroll
    for (int ks = 0; ks < 2; ++ks) {
      const int kbyte = ks * 64 + lh * 16;
      short8m aH = *ldsPtr(WsH, wv * 16 + lr, kbyte);
      short8m aM = *ldsPtr(WsM, wv * 16 + lr, kbyte);
      const int xoff = (ks * 4 + lh) * 512;
      #pragma unroll
      for (int g4 = 0; g4 < 4; ++g4) {
        short8m bH = *(const short8m*)(XsH + xoff + (g4 * 16 + lr) * 8);
        short8m bM = *(const short8m*)(XsM + xoff + (g4 * 16 + lr) * 8);
        acc[g4] = __builtin_amdgcn_mfma_f32_16x16x32_bf16(aH, bH, acc[g4], 0, 0, 0);
        acc[g4] = __builtin_amdgcn_mfma_f32_16x16x32_bf16(aH, bM, acc[g4], 0, 0, 0);
        acc[g4] = __builtin_amdgcn_mfma_f32_16x16x32_bf16(aM, bH, acc[g4], 0, 0, 0);
        acc[g4] = __builtin_amdgcn_mfma_f32_16x16x32_bf16(aM, bM, acc[g4], 0, 0, 0);
      }
    }
    __syncthreads();
  }
  const size_t N = (size_t)4 * COUT * HOUT * WOUT;
  #pragma unroll
  for (int g4 = 0; g4 < 4; ++g4) {
    int pxl = g4 * 16 + lr;
    int pidx = pxblk * 64 + pxl;
    if (pidx < NPX) {
      #pragma unroll
      for (int r = 0; r < 4; ++r) {
        int ocl = wv * 16 + lh * 4 + r;
        part[(size_t)spl * N +
             (((size_t)pb[pxl] * COUT + (oc0 + ocl)) * HOUT + pyA[pxl]) * WOUT + pxA[pxl]] =
            acc[g4][r];
      }
    }
  }
}

// ---------------- fallback conv (round-11 proven path) ----------------
template <int CIN, int HIN, int WIN, int COUT, int HOUT, int WOUT, int SPLIT>
__global__ __launch_bounds__(256) void k_convm(const float* __restrict__ x,
                                               const float* __restrict__ wsrc,
                                               float* __restrict__ part) {
  constexpr int NPX = 4 * HOUT * WOUT;
  constexpr int KTOT = (CIN * 9) / SPLIT;
  constexpr int NCH = KTOT / 64;
  __shared__ __align__(16) unsigned short Xs[2][64][64];
  __shared__ __align__(16) unsigned short Wsh[3][64][64];
  __shared__ int pb[64], pyA[64], pxA[64];
  const int tid = threadIdx.x;
  const int oc0 = blockIdx.y * 64, px0 = blockIdx.x * 64;
  const int spl = blockIdx.z;
  const int kg0 = spl * KTOT;
  if (tid < 64) {
    int p = px0 + tid;
    if (p > NPX - 1) p = NPX - 1;
    int hw = HOUT * WOUT;
    pb[tid] = p / hw;
    int r = p % hw;
    pyA[tid] = r / WOUT;
    pxA[tid] = r % WOUT;
  }
  f32x4 acc[4] = {};
  const int l = tid & 63, wv = tid >> 6;
  const int lr = l & 15, lh = l >> 4;
  __syncthreads();
  for (int ch = 0; ch < NCH; ++ch) {
    const int kbase = kg0 + ch * 64;
    #pragma unroll
    for (int j = 0; j < 2; ++j) {
      int c = tid + 256 * j;
      int oc = c >> 3, koct = c & 7;
      const float* wp = wsrc + (size_t)(oc0 + oc) * (CIN * 9) + kbase + koct * 8;
      float vv[8];
      *(float4*)&vv[0] = *(const float4*)wp;
      *(float4*)&vv[4] = *(const float4*)(wp + 4);
      short8m ph, pm, pl2;
      #pragma unroll
      for (int i = 0; i < 8; ++i) {
        unsigned short hb = bf16_trunc(vv[i]);
        float r = vv[i] - bf16_tof(hb);
        unsigned short mb = bf16_rte(r);
        float r2 = r - bf16_tof(mb);
        unsigned short lb = bf16_rte(r2);
        ph[i] = (short)hb; pm[i] = (short)mb; pl2[i] = (short)lb;
      }
      *ldsPtr(&Wsh[0][0][0], oc, koct * 16) = ph;
      *ldsPtr(&Wsh[1][0][0], oc, koct * 16) = pm;
      *ldsPtr(&Wsh[2][0][0], oc, koct * 16) = pl2;
    }
    #pragma unroll
    for (int j = 0; j < 2; ++j) {
      int c = tid + 256 * j;
      int px = c & 63, koct = c >> 6;
      int pbv = pb[px], py = pyA[px], pxv = pxA[px];
      float vv[8];
      #pragma unroll
      for (int i = 0; i < 8; ++i) {
        int k = kbase + koct * 8 + i;
        int ci = k / 9, tap = k - ci * 9;
        int iy = py * 2 - 1 + tap / 3, ix = pxv * 2 - 1 + (tap % 3);
        float v = 0.f;
        if ((unsigned)iy < (unsigned)HIN && (unsigned)ix < (unsigned)WIN)
          v = x[(((size_t)pbv * CIN + ci) * HIN + iy) * WIN + ix];
        vv[i] = v;
      }
      short8m ph, pm;
      #pragma unroll
      for (int i = 0; i < 8; ++i) {
        unsigned short hb = bf16_trunc(vv[i]);
        unsigned short mb = bf16_rte(vv[i] - bf16_tof(hb));
        ph[i] = (short)hb; pm[i] = (short)mb;
      }
      *ldsPtr(&Xs[0][0][0], px, koct * 16) = ph;
      *ldsPtr(&Xs[1][0][0], px, koct * 16) = pm;
    }
    __syncthreads();
    #pragma unroll
    for (int ks = 0; ks < 2; ++ks) {
      const int kbyte = ks * 64 + lh * 16;
      short8m aH = *ldsPtr(&Wsh[0][0][0], wv * 16 + lr, kbyte);
      short8m aM = *ldsPtr(&Wsh[1][0][0], wv * 16 + lr, kbyte);
      short8m aL = *ldsPtr(&Wsh[2][0][0], wv * 16 + lr, kbyte);
      #pragma unroll
      for (int g = 0; g < 4; ++g) {
        short8m bH = *ldsPtr(&Xs[0][0][0], g * 16 + lr, kbyte);
        short8m bM = *ldsPtr(&Xs[1][0][0], g * 16 + lr, kbyte);
        acc[g] = __builtin_amdgcn_mfma_f32_16x16x32_bf16(aH, bH, acc[g], 0, 0, 0);
        acc[g] = __builtin_amdgcn_mfma_f32_16x16x32_bf16(aH, bM, acc[g], 0, 0, 0);
        acc[g] = __builtin_amdgcn_mfma_f32_16x16x32_bf16(aM, bH, acc[g], 0, 0, 0);
        acc[g] = __builtin_amdgcn_mfma_f32_16x16x32_bf16(aM, bM, acc[g], 0, 0, 0);
        acc[g] = __builtin_amdgcn_mfma_f32_16x16x32_bf16(aL, bH, acc[g], 0, 0, 0);
      }
    }
    __syncthreads();
  }
  const size_t N = (size_t)4 * COUT * HOUT * WOUT;
  #pragma unroll
  for (int g = 0; g < 4; ++g) {
    int pxl = g * 16 + lr;
    int pidx = px0 + pxl;
    if (pidx < NPX) {
      #pragma unroll
      for (int r = 0; r < 4; ++r) {
        int ocl = wv * 16 + lh * 4 + r;
        part[(size_t)spl * N +
             (((size_t)pb[pxl] * COUT + (oc0 + ocl)) * HOUT + pyA[pxl]) * WOUT + pxA[pxl]] =
            acc[g][r];
      }
    }
  }
}

// ---------------- split-K reduction + ReLU ----------------
template <int SPLIT>
__global__ __launch_bounds__(256) void k_red(const float* __restrict__ part,
                                             float* __restrict__ y, int n) {
  for (int i = blockIdx.x * 256 + threadIdx.x; i < n; i += gridDim.x * 256) {
    float s = 0.f;
    #pragma unroll
    for (int sp = 0; sp < SPLIT; ++sp) s += part[(size_t)sp * n + i];
    y[i] = fmaxf(s, 0.f);
  }
}

// ---------------- global-max-pool (7x7): one thread per (b,ch) ----------------
__global__ __launch_bounds__(256) void k_pool(const float* __restrict__ feat,
                                              float* __restrict__ pool) {
  int idx = blockIdx.x * 256 + threadIdx.x;
  if (idx >= 8192) return;
  const float* fp = feat + (size_t)idx * 49;
  float m = fp[0];
  #pragma unroll
  for (int i = 1; i < 49; ++i) m = fmaxf(m, fp[i]);
  pool[idx] = m;
}

// ---------------- FC(2048->14) + sigmoid: one block per (b,c) ----------------
__global__ __launch_bounds__(256) void k_fcsig(const float* __restrict__ pool,
                                               const float* __restrict__ fw,
                                               const float* __restrict__ fb,
                                               float* __restrict__ outp) {
  __shared__ float red[256];
  const int blk = blockIdx.x;       // b*14 + c
  const int b = blk / 14, c = blk % 14;
  const int tid = threadIdx.x;
  float s = 0.f;
  for (int k = tid; k < 2048; k += 256) s += pool[b * 2048 + k] * fw[c * 2048 + k];
  red[tid] = s;
  __syncthreads();
  for (int st = 128; st > 0; st >>= 1) {
    if (tid < st) red[tid] += red[tid + st];
    __syncthreads();
  }
  if (tid == 0) outp[b * 14 + c] = 1.f / (1.f + expf(-(red[0] + fb[c])));
}

// ---------------- fused FC(4096->14) + sigmoid for out_f: one block per (b,c) ----------------
__global__ __launch_bounds__(256) void k_fcsig2(const float* __restrict__ poolg,
                                                const float* __restrict__ pooll,
                                                const float* __restrict__ fw,
                                                const float* __restrict__ fb,
                                                float* __restrict__ outp) {
  __shared__ float red[256];
  const int blk = blockIdx.x;       // b*14 + c
  const int b = blk / 14, c = blk % 14;
  const int tid = threadIdx.x;
  const float* w = fw + (size_t)c * 4096;
  float s = 0.f;
  for (int k = tid; k < 2048; k += 256) s += poolg[b * 2048 + k] * w[k];
  for (int k = tid; k < 2048; k += 256) s += pooll[b * 2048 + k] * w[2048 + k];
  red[tid] = s;
  __syncthreads();
  for (int st = 128; st > 0; st >>= 1) {
    if (tid < st) red[tid] += red[tid + st];
    __syncthreads();
  }
  if (tid == 0) outp[blk] = 1.f / (1.f + expf(-(red[0] + fb[c])));
}

// ---------------- loss: weighted BCEs over the 3x56 sigmoid outputs already in d_out ----------------
__global__ __launch_bounds__(64) void k_loss(const float* __restrict__ target,
                                             float* __restrict__ dout) {
  __shared__ float red[64];
  const int tid = threadIdx.x;
  float term = 0.f;
  if (tid < 56) {
    float t = target[tid];
    float pg = dout[1 + tid], plo = dout[57 + tid], pf = dout[113 + tid];
    auto bce1 = [&](float pp) {
      pp = fminf(fmaxf(pp, 1e-7f), 1.f - 1e-7f);
      return -(t * logf(pp) + (1.f - t) * log1pf(-pp));
    };
    term = (0.8f * bce1(pg) + 0.1f * bce1(plo) + 0.1f * bce1(pf)) * (1.f / 56.f);
  }
  red[tid] = term;
  __syncthreads();
  for (int st = 32; st > 0; st >>= 1) {
    if (tid < st) red[tid] += red[tid + st];
    __syncthreads();
  }
  if (tid == 0) dout[0] = red[0];
}

// ---------------- heatmap stage A: per-(b,cell) channel max|.| ----------------
__global__ __launch_bounds__(256) void k_hm7a(const float* __restrict__ feat,
                                              float* __restrict__ hmr) {
  __shared__ float red[256];
  const int b = blockIdx.x / 49, cell = blockIdx.x % 49;
  const int tid = threadIdx.x;
  float m = 0.f;
  for (int ch = tid; ch < 2048; ch += 256)
    m = fmaxf(m, fabsf(feat[((size_t)b * 2048 + ch) * 49 + cell]));
  red[tid] = m;
  __syncthreads();
  for (int st = 128; st > 0; st >>= 1) {
    if (tid < st) red[tid] = fmaxf(red[tid], red[tid + st]);
    __syncthreads();
  }
  if (tid == 0) hmr[b * 49 + cell] = red[0];
}

// ---------------- heatmap stage B: per-sample min-max normalize ----------------
__global__ __launch_bounds__(64) void k_hm7b(const float* __restrict__ hmr,
                                             float* __restrict__ hm7) {
  __shared__ float h[49];
  const int b = blockIdx.x, tid = threadIdx.x;
  if (tid < 49) h[tid] = hmr[b * 49 + tid];
  __syncthreads();
  if (tid == 0) {
    float mn = h[0], mx = h[0];
    for (int i = 1; i < 49; ++i) {
      mn = fminf(mn, h[i]);
      mx = fmaxf(mx, h[i]);
    }
    for (int i = 0; i < 49; ++i) hm7[b * 49 + i] = (h[i] - mn) / (mx - mn);
  }
}

// ---------------- parallel CCL on mask runs + bbox of largest component ----------------
#define MAXR 8
#define NRUNS (224 * MAXR)
__global__ __launch_bounds__(256) void k_ccl(const float* __restrict__ hm7, float* __restrict__ bbox) {
  const int b = blockIdx.x, tid = threadIdx.x;
  __shared__ float h7[49];
  __shared__ short rx0[NRUNS], rx1[NRUNS];
  __shared__ short nr[224];
  __shared__ int lab[NRUNS];
  __shared__ int cnt[NRUNS], mid[NRUNS];
  __shared__ int rmn[NRUNS], rmx[NRUNS], cmn[NRUNS], cmx[NRUNS];
  __shared__ int chg, chg2;
  __shared__ int bestC[256], bestM[256], bestI[256];

  if (tid < 49) h7[tid] = hm7[b * 49 + tid];
  for (int i = tid; i < NRUNS; i += 256) {
    cnt[i] = 0; mid[i] = -1;
    rmn[i] = 1 << 30; rmx[i] = -1; cmn[i] = 1 << 30; cmx[i] = -1;
    lab[i] = i;
  }
  __syncthreads();
  if (tid < 224) {
    int yy = tid;
    float py = ((float)yy + 0.5f) * (7.f / 224.f) - 0.5f;
    py = fminf(fmaxf(py, 0.f), 6.f);
    int y0 = (int)floorf(py);
    if (y0 > 5) y0 = 5;
    float fy = py - (float)y0;
    int n = 0, start = -1;
    const int segLo[6] = {0, 48, 80, 112, 144, 176};
    const int segHi[6] = {48, 80, 112, 144, 176, 224};
    #pragma unroll
    for (int s = 0; s < 6; ++s) {
      float A = h7[y0 * 7 + s], B = h7[y0 * 7 + s + 1];
      float C = h7[(y0 + 1) * 7 + s], D = h7[(y0 + 1) * 7 + s + 1];
      for (int xx = segLo[s]; xx < segHi[s]; ++xx) {
        float px = ((float)xx + 0.5f) * (7.f / 224.f) - 0.5f;
        px = fminf(fmaxf(px, 0.f), 6.f);
        float fx = px - (float)s;
        float v = (1.f - fy) * ((1.f - fx) * A + fx * B) +
                  fy * ((1.f - fx) * C + fx * D);
        bool m = v > 0.7f;
        if (m && start < 0) start = xx;
        if (!m && start >= 0) {
          if (n < MAXR) { rx0[yy * MAXR + n] = (short)start; rx1[yy * MAXR + n] = (short)(xx - 1); n++; }
          start = -1;
        }
      }
    }
    if (start >= 0 && n < MAXR) { rx0[yy * MAXR + n] = (short)start; rx1[yy * MAXR + n] = 223; n++; }
    nr[yy] = (short)n;
  }
  __syncthreads();
  int myA0[7], myA1[7];
  bool myV[7];
  #pragma unroll
  for (int j = 0; j < 7; ++j) {
    int i = tid + j * 256;
    int yy = i >> 3, k = i & 7;
    bool v = (k < (int)nr[yy]);
    myV[j] = v;
    myA0[j] = v ? (int)rx0[i] : 0;
    myA1[j] = v ? (int)rx1[i] : 0;
  }
  for (int outer = 0; outer < 48; ++outer) {
    if (tid == 0) chg = 0;
    __syncthreads();
    bool any = false;
    #pragma unroll
    for (int j = 0; j < 7; ++j) {
      if (!myV[j]) continue;
      int i = tid + j * 256;
      int yy = i >> 3;
      int a0 = myA0[j], a1 = myA1[j];
      int ri = lab[i];
      if (yy > 0) {
        int n1 = nr[yy - 1];
        for (int kk = 0; kk < n1; ++kk) {
          int q = ((yy - 1) << 3) + kk;
          if (a0 <= rx1[q] + 1 && a1 >= rx0[q] - 1) {
            int rq = lab[q];
            if (rq < ri) { atomicMin(&lab[ri], rq); any = true; }
            else if (ri < rq) { atomicMin(&lab[rq], ri); any = true; }
          }
        }
      }
      if (yy < 223) {
        int n1 = nr[yy + 1];
        for (int kk = 0; kk < n1; ++kk) {
          int q = ((yy + 1) << 3) + kk;
          if (a0 <= rx1[q] + 1 && a1 >= rx0[q] - 1) {
            int rq = lab[q];
            if (rq < ri) { atomicMin(&lab[ri], rq); any = true; }
            else if (ri < rq) { atomicMin(&lab[rq], ri); any = true; }
          }
        }
      }
    }
    if (any) chg = 1;
    __syncthreads();
    for (int sc = 0; sc < 12; ++sc) {
      if (tid == 0) chg2 = 0;
      __syncthreads();
      bool a2 = false;
      #pragma unroll
      for (int j = 0; j < 7; ++j) {
        int i = tid + j * 256;
        int ll = lab[i];
        int l2 = lab[ll];
        if (l2 < ll) { lab[i] = l2; a2 = true; }
      }
      if (a2) chg2 = 1;
      __syncthreads();
      if (!chg2) break;
    }
    if (!chg) break;
  }
  for (int i = tid; i < NRUNS; i += 256) {
    int yy = i >> 3, k = i & 7;
    if (k >= (int)nr[yy]) continue;
    int r = lab[i];
    int a0 = rx0[i], a1 = rx1[i];
    atomicAdd(&cnt[r], a1 - a0 + 1);
    atomicMax(&mid[r], yy * 224 + a1 + 1);
    atomicMin(&rmn[r], yy);
    atomicMax(&rmx[r], yy);
    atomicMin(&cmn[r], a0);
    atomicMax(&cmx[r], a1);
  }
  __syncthreads();
  int bc = -1, bm = 0x7fffffff, bi = -1;
  for (int i = tid; i < NRUNS; i += 256) {
    if (cnt[i] > 0 && lab[i] == i) {
      if (cnt[i] > bc || (cnt[i] == bc && mid[i] < bm)) { bc = cnt[i]; bm = mid[i]; bi = i; }
    }
  }
  bestC[tid] = bc; bestM[tid] = bm; bestI[tid] = bi;
  __syncthreads();
  for (int st = 128; st > 0; st >>= 1) {
    if (tid < st) {
      if (bestC[tid + st] > bestC[tid] ||
          (bestC[tid + st] == bestC[tid] && bestM[tid + st] < bestM[tid])) {
        bestC[tid] = bestC[tid + st]; bestM[tid] = bestM[tid + st]; bestI[tid] = bestI[tid + st];
      }
    }
    __syncthreads();
  }
  if (tid == 0) {
    int bw = bestI[0];
    float fy0, chf, fx0, cwf;
    if (bw < 0) { fy0 = 224.f; chf = 1.f; fx0 = 224.f; cwf = 1.f; }
    else {
      int dr = rmx[bw] - rmn[bw]; if (dr < 1) dr = 1;
      int dc = cmx[bw] - cmn[bw]; if (dc < 1) dc = 1;
      fy0 = (float)rmn[bw]; chf = (float)dr;
      fx0 = (float)cmn[bw]; cwf = (float)dc;
    }
    bbox[b * 4 + 0] = fy0; bbox[b * 4 + 1] = chf;
    bbox[b * 4 + 2] = fx0; bbox[b * 4 + 3] = cwf;
  }
}

// ---------------- bilinear crop-resize back to 224x224 ----------------
__global__ __launch_bounds__(256) void k_sample(const float* __restrict__ img,
                                                const float* __restrict__ bbox,
                                                float* __restrict__ patch_out,
                                                float* __restrict__ patch_ws) {
  int idx = blockIdx.x * 256 + threadIdx.x;
  if (idx >= 4 * 3 * 224 * 224) return;
  int b = idx / (3 * 224 * 224);
  int r = idx % (3 * 224 * 224);
  int c = r / (224 * 224);
  int p = r % (224 * 224);
  int oy = p / 224, ox = p % 224;
  float fy0 = bbox[b * 4 + 0], chf = bbox[b * 4 + 1];
  float fx0 = bbox[b * 4 + 2], cwf = bbox[b * 4 + 3];
  float gy = ((float)oy + 0.5f) * (chf / 224.f) + fy0 - 0.5f;
  float gx = ((float)ox + 0.5f) * (cwf / 224.f) + fx0 - 0.5f;
  gy = fminf(fmaxf(gy, fy0), fmaxf(fy0 + chf - 1.f, fy0));
  gx = fminf(fmaxf(gx, fx0), fmaxf(fx0 + cwf - 1.f, fx0));
  int y0 = (int)floorf(gy);
  int x0 = (int)floorf(gx);
  float fy = gy - (float)y0, fx = gx - (float)x0;
  int y0c = min(max(y0, 0), 223), y1c = min(max(y0 + 1, 0), 223);
  int x0c = min(max(x0, 0), 223), x1c = min(max(x0 + 1, 0), 223);
  const float* ip = img + ((size_t)b * 3 + c) * 224 * 224;
  float v00 = ip[y0c * 224 + x0c], v01 = ip[y0c * 224 + x1c];
  float v10 = ip[y1c * 224 + x0c], v11 = ip[y1c * 224 + x1c];
  float v = (1.f - fy) * ((1.f - fx) * v00 + fx * v01) + fy * ((1.f - fx) * v10 + fx * v11);
  patch_out[idx] = v;
  patch_ws[idx] = v;
}

extern "C" void kernel_launch(void* const* d_in, const int* in_sizes, int n_in,
                              void* d_out, int out_size, void* d_ws, size_t ws_size,
                              hipStream_t stream) {
  const float* img = (const float*)d_in[0];
  const float* target = (const float*)d_in[1];
  const float* gw0 = (const float*)d_in[2];
  const float* gw1 = (const float*)d_in[3];
  const float* gw2 = (const float*)d_in[4];
  const float* gw3 = (const float*)d_in[5];
  const float* gfw = (const float*)d_in[6];
  const float* gfb = (const float*)d_in[7];
  const float* lw0 = (const float*)d_in[8];
  const float* lw1 = (const float*)d_in[9];
  const float* lw2 = (const float*)d_in[10];
  const float* lw3 = (const float*)d_in[11];
  const float* lfw = (const float*)d_in[12];
  const float* lfb = (const float*)d_in[13];
  const float* fw = (const float*)d_in[14];
  const float* fb = (const float*)d_in[15];
  float* out = (float*)d_out;
  float* ws = (float*)d_ws;

  float* c1 = ws;                    // 802816   [4,64,56,56]
  float* c2 = c1 + 802816;           // 1605632  [4,512,28,28]
  float* c3 = c2 + 1605632;          // 802816   [4,1024,14,14]
  float* c4 = c3 + 802816;           // 401408   [4,2048,7,7]
  float* poolg = c4 + 401408;        // 8192
  float* pooll = poolg + 8192;       // 8192
  float* hm7 = pooll + 8192;         // 196
  float* hmr = hm7 + 196;            // 196
  float* bbox = hmr + 196;           // 16
  float* patch = ws + 3629568;       // 602112 (16B aligned)
  float* part = ws + 4231680;        // <=3211264 split-K partials
  float* Wp = part + 2800000;        // 12288 padded conv7 weights (dead corner of part)
  unsigned short* XgH = (unsigned short*)(ws + 7442944);   // fast path only
  unsigned short* XgM = XgH + 3840000;

  const bool fast = ws_size >= (size_t)45131776;

  dim3 g7(13, 256);
  const int rg1 = 2048, rg2 = 2048, rg3 = 2048, rg4 = 1568;

  for (int pass = 0; pass < 2; ++pass) {
    const float* w0 = pass ? lw0 : gw0;
    const float* w1 = pass ? lw1 : gw1;
    const float* w2 = pass ? lw2 : gw2;
    const float* w3 = pass ? lw3 : gw3;
    const float* fwp = pass ? lfw : gfw;
    const float* fbp = pass ? lfb : gfb;
    const float* inp = pass ? patch : img;
    float* pool = pass ? pooll : poolg;
    float* outp = pass ? (out + 57) : (out + 1);

    if (fast) {
      // conv7 as im2col GEMM (K=147 zero-padded to 192)
      k_padw<<<48, 256, 0, stream>>>(w0, Wp, 147, 192, 64);
      k_im2col<3, 224, 224, 56, 56, 7, 7, 4, 3, 192><<<1176, 256, 0, stream>>>(inp, XgH, XgM);
      k_gemmx<64, 56, 56, 192, 1><<<dim3(196, 1, 1), 256, 0, stream>>>(XgH, XgM, Wp, part);
      k_red<1><<<rg1, 256, 0, stream>>>(part, c1, 802816);
      k_im2col<64, 56, 56, 28, 28, 3, 3, 2, 1, 576><<<882, 256, 0, stream>>>(c1, XgH, XgM);
      k_gemmx<512, 28, 28, 576, 1><<<dim3(49, 8, 1), 256, 0, stream>>>(XgH, XgM, w1, part);
      k_red<1><<<rg2, 256, 0, stream>>>(part, c2, 1605632);
      k_im2col<512, 28, 28, 14, 14, 3, 3, 2, 1, 4608><<<1872, 256, 0, stream>>>(c2, XgH, XgM);
      k_gemmx<1024, 14, 14, 4608, 4><<<dim3(13, 16, 4), 256, 0, stream>>>(XgH, XgM, w2, part);
      k_red<4><<<rg3, 256, 0, stream>>>(part, c3, 802816);
      k_im2col<1024, 14, 14, 7, 7, 3, 3, 2, 1, 9216><<<1152, 256, 0, stream>>>(c3, XgH, XgM);
      k_gemmx<2048, 7, 7, 9216, 8><<<dim3(4, 32, 8), 256, 0, stream>>>(XgH, XgM, w3, part);
      k_red<8><<<rg4, 256, 0, stream>>>(part, c4, 401408);
    } else {
      k_conv7<<<g7, 256, 0, stream>>>(inp, w0, c1);
      k_convm<64, 56, 56, 512, 28, 28, 1><<<dim3(49, 8, 1), 256, 0, stream>>>(c1, w1, part);
      k_red<1><<<rg2, 256, 0, stream>>>(part, c2, 1605632);
      k_convm<512, 28, 28, 1024, 14, 14, 4><<<dim3(13, 16, 4), 256, 0, stream>>>(c2, w2, part);
      k_red<4><<<rg3, 256, 0, stream>>>(part, c3, 802816);
      k_convm<1024, 14, 14, 2048, 7, 7, 8><<<dim3(4, 32, 8), 256, 0, stream>>>(c3, w3, part);
      k_red<8><<<rg4, 256, 0, stream>>>(part, c4, 401408);
    }
    k_pool<<<32, 256, 0, stream>>>(c4, pool);
    k_fcsig<<<56, 256, 0, stream>>>(pool, fwp, fbp, outp);

    if (pass == 0) {
      k_hm7a<<<196, 256, 0, stream>>>(c4, hmr);
      k_hm7b<<<4, 64, 0, stream>>>(hmr, hm7);
      k_ccl<<<4, 256, 0, stream>>>(hm7, bbox);
      k_sample<<<2352, 256, 0, stream>>>(img, bbox, out + 169, patch);
    }
  }
  // fusion FC (parallel) + loss (tiny)
  k_fcsig2<<<56, 256, 0, stream>>>(poolg, pooll, fw, fb, out + 113);
  k_loss<<<1, 64, 0, stream>>>(target, out);
}

// Round 15
// 358.148 us; speedup vs baseline: 11.1221x; 1.2192x over previous
//
#include <hip/hip_runtime.h>
#include <math.h>

typedef __attribute__((ext_vector_type(8))) short short8m;   // 8 bf16 (4 VGPRs)
typedef __attribute__((ext_vector_type(4))) float f32x4;

__device__ inline unsigned short bf16_trunc(float f) {
  return (unsigned short)(__float_as_uint(f) >> 16);
}
__device__ inline unsigned short bf16_rte(float f) {
  unsigned u = __float_as_uint(f);
  u += 0x7fffu + ((u >> 16) & 1u);
  return (unsigned short)(u >> 16);
}
__device__ inline float bf16_tof(unsigned short h) {
  return __uint_as_float(((unsigned)h) << 16);
}
// LDS XOR-swizzle for W tiles: row pitch 128B; byte ^= ((row&7)<<4) -> conflict-free b128 r/w
__device__ inline short8m* ldsPtr(unsigned short* base, int row, int byteInRow) {
  int off = (row * 128 + byteInRow) ^ ((row & 7) << 4);
  return (short8m*)((char*)base + off);
}
__device__ inline void gload16_lds(const void* g, void* d) {
  __builtin_amdgcn_global_load_lds((const __attribute__((address_space(1))) unsigned int*)g,
                                   (__attribute__((address_space(3))) unsigned int*)d, 16, 0, 0);
}

// ---------------- conv 7x7 direct (fallback path only) ----------------
__global__ __launch_bounds__(256) void k_conv7(const float* __restrict__ x,
                                               const float* __restrict__ w,
                                               float* __restrict__ y) {
  __shared__ float ws[147];
  const int boc = blockIdx.y;
  const int oc = boc & 63;
  const int b = boc >> 6;
  for (int i = threadIdx.x; i < 147; i += 256) ws[i] = w[oc * 147 + i];
  __syncthreads();
  int px = blockIdx.x * 256 + threadIdx.x;
  if (px >= 56 * 56) return;
  int oy = px / 56, ox = px % 56;
  int iy0 = oy * 4 - 3, ix0 = ox * 4 - 3;
  float acc = 0.f;
  for (int c = 0; c < 3; ++c) {
    const float* xp = x + ((size_t)(b * 3 + c)) * 224 * 224;
    #pragma unroll
    for (int ky = 0; ky < 7; ++ky) {
      int iy = iy0 + ky;
      if ((unsigned)iy < 224u) {
        #pragma unroll
        for (int kx = 0; kx < 7; ++kx) {
          int ix = ix0 + kx;
          if ((unsigned)ix < 224u)
            acc += xp[iy * 224 + ix] * ws[c * 49 + ky * 7 + kx];
        }
      }
    }
  }
  y[((size_t)boc * 56 + oy) * 56 + ox] = fmaxf(acc, 0.f);
}

// ---------------- zero-pad weights along K: wp[oc][KTOT], wp[k>=KREAL]=0 ----------------
__global__ __launch_bounds__(256) void k_padw(const float* __restrict__ w,
                                              float* __restrict__ wp,
                                              int kreal, int ktot, int noc) {
  int i = blockIdx.x * 256 + threadIdx.x;
  if (i >= noc * ktot) return;
  int oc = i / ktot, k = i % ktot;
  wp[i] = (k < kreal) ? w[oc * kreal + k] : 0.f;
}

// ---------------- generic im2col + 2-plane bf16 split, block-tiled layout ----------------
// Xg element (px,k) at pxblk*KTOT*64 + (k>>3)*512 + pxin*8 + (k&7) (ushort units).
// k = ci*KH*KW + tap (ci >= CIN -> zero pad, for KTOT rounded up to 64).
template <int CIN, int HIN, int WIN, int HOUT, int WOUT, int KH, int KW, int STR, int PAD, int KTOT>
__global__ __launch_bounds__(256) void k_im2col(const float* __restrict__ x,
                                                unsigned short* __restrict__ XgH,
                                                unsigned short* __restrict__ XgM) {
  constexpr int NPX = 4 * HOUT * WOUT;
  constexpr int K8 = KTOT / 8;
  constexpr int KK = KH * KW;
  int u = blockIdx.x * 256 + threadIdx.x;
  int pxin = u & 63;
  int k8 = (u >> 6) % K8;
  int pxblk = (u >> 6) / K8;
  int px = pxblk * 64 + pxin;
  if (px > NPX - 1) px = NPX - 1;          // pad replication
  const int hw = HOUT * WOUT;
  int pbv = px / hw;
  int r = px % hw;
  int py = r / WOUT, pxv = r % WOUT;
  short8m ph, pm;
  #pragma unroll
  for (int i = 0; i < 8; ++i) {
    int k = k8 * 8 + i;
    int ci = k / KK, tap = k - ci * KK;
    float v = 0.f;
    if (ci < CIN) {
      int iy = py * STR - PAD + tap / KW, ix = pxv * STR - PAD + (tap % KW);
      if ((unsigned)iy < (unsigned)HIN && (unsigned)ix < (unsigned)WIN)
        v = x[(((size_t)pbv * CIN + ci) * HIN + iy) * WIN + ix];
    }
    unsigned short hb = bf16_trunc(v);
    unsigned short mb = bf16_rte(v - bf16_tof(hb));
    ph[i] = (short)hb; pm[i] = (short)mb;
  }
  size_t off = (size_t)u * 8;
  *(short8m*)(XgH + off) = ph;
  *(short8m*)(XgM + off) = pm;
}

// ---------------- GEMM on pre-im2col'd X: bf16 emulated f32 (3 products) ----------------
// 1D grid with bijective XCD swizzle (m204): contiguous work chunks per XCD -> L2 reuse.
// Work order (spl, ocb, pxblk-fastest). 3 MFMA products (HH,HM,MH); MM ~2^-17 dropped.
// SPLIT==1 fuses ReLU and writes final output directly.
template <int COUT, int HOUT, int WOUT, int KTOT, int SPLIT>
__global__ __launch_bounds__(256) void k_gemmx(const unsigned short* __restrict__ XgH,
                                               const unsigned short* __restrict__ XgM,
                                               const float* __restrict__ wsrc,
                                               float* __restrict__ part) {
  constexpr int NPX = 4 * HOUT * WOUT;
  constexpr int NPXB = (NPX + 63) / 64;
  constexpr int NOCB = COUT / 64;
  constexpr int NWG = NPXB * NOCB * SPLIT;
  constexpr int KCH = KTOT / SPLIT;
  constexpr int NCH = KCH / 64;
  __shared__ __align__(16) unsigned short XsH[4096];   // [8 koct][64 px][8 k] linear image
  __shared__ __align__(16) unsigned short XsM[4096];
  __shared__ __align__(16) unsigned short WsH[4096];   // swizzled [64 oc][64 k]
  __shared__ __align__(16) unsigned short WsM[4096];
  __shared__ int pb[64], pyA[64], pxA[64];
  const int tid = threadIdx.x;
  // bijective XCD swizzle (q/r form, works for any NWG)
  const int flat = blockIdx.x;
  constexpr int q = NWG >> 3, r = NWG & 7;
  const int xc = flat & 7, of = flat >> 3;
  const int work = ((xc < r) ? xc * (q + 1) : r * (q + 1) + (xc - r) * q) + of;
  const int pxblk = work % NPXB;
  const int t2 = work / NPXB;
  const int oc0 = (t2 % NOCB) * 64;
  const int spl = t2 / NOCB;
  if (tid < 64) {
    int p = pxblk * 64 + tid;
    if (p > NPX - 1) p = NPX - 1;
    int hw = HOUT * WOUT;
    pb[tid] = p / hw;
    int rr = p % hw;
    pyA[tid] = rr / WOUT;
    pxA[tid] = rr % WOUT;
  }
  f32x4 acc[4] = {};
  const int l = tid & 63, wv = tid >> 6;
  const int lr = l & 15, lh = l >> 4;
  __syncthreads();
  for (int ch = 0; ch < NCH; ++ch) {
    const int kbase = spl * KCH + ch * 64;
    // ---- X: 16 async 1KB slabs (2 planes x 8 koct), 4 per wave ----
    const size_t tileOff = (size_t)pxblk * KTOT * 64 + (size_t)kbase * 64;
    #pragma unroll
    for (int t = 0; t < 4; ++t) {
      int ins = wv * 4 + t;
      int pl = ins >> 3, ko = ins & 7;
      const unsigned short* g = (pl ? XgM : XgH) + tileOff + ko * 512 + l * 8;
      unsigned short* d = (pl ? XsM : XsH) + ko * 512;
      gload16_lds(g, d);
    }
    // ---- W: 2-plane split, swizzled LDS ----
    #pragma unroll
    for (int j = 0; j < 2; ++j) {
      int c = tid + 256 * j;
      int oc = c >> 3, koct = c & 7;
      const float* wp = wsrc + (size_t)(oc0 + oc) * KTOT + kbase + koct * 8;
      float vv[8];
      *(float4*)&vv[0] = *(const float4*)wp;
      *(float4*)&vv[4] = *(const float4*)(wp + 4);
      short8m ph, pm;
      #pragma unroll
      for (int i = 0; i < 8; ++i) {
        unsigned short hb = bf16_trunc(vv[i]);
        unsigned short mb = bf16_rte(vv[i] - bf16_tof(hb));
        ph[i] = (short)hb; pm[i] = (short)mb;
      }
      *ldsPtr(WsH, oc, koct * 16) = ph;
      *ldsPtr(WsM, oc, koct * 16) = pm;
    }
    __syncthreads();                       // drains vmcnt (global_load_lds) + lgkm
    // ---- MFMA: 2 k-steps of 32, 4 px groups, 3 products ----
    #pragma unroll
    for (int ks = 0; ks < 2; ++ks) {
      const int kbyte = ks * 64 + lh * 16;
      short8m aH = *ldsPtr(WsH, wv * 16 + lr, kbyte);
      short8m aM = *ldsPtr(WsM, wv * 16 + lr, kbyte);
      const int xoff = (ks * 4 + lh) * 512;
      #pragma unroll
      for (int g4 = 0; g4 < 4; ++g4) {
        short8m bH = *(const short8m*)(XsH + xoff + (g4 * 16 + lr) * 8);
        short8m bM = *(const short8m*)(XsM + xoff + (g4 * 16 + lr) * 8);
        acc[g4] = __builtin_amdgcn_mfma_f32_16x16x32_bf16(aH, bH, acc[g4], 0, 0, 0);
        acc[g4] = __builtin_amdgcn_mfma_f32_16x16x32_bf16(aH, bM, acc[g4], 0, 0, 0);
        acc[g4] = __builtin_amdgcn_mfma_f32_16x16x32_bf16(aM, bH, acc[g4], 0, 0, 0);
      }
    }
    __syncthreads();
  }
  const size_t N = (size_t)4 * COUT * HOUT * WOUT;
  #pragma unroll
  for (int g4 = 0; g4 < 4; ++g4) {
    int pxl = g4 * 16 + lr;
    int pidx = pxblk * 64 + pxl;
    if (pidx < NPX) {
      #pragma unroll
      for (int rr = 0; rr < 4; ++rr) {
        int ocl = wv * 16 + lh * 4 + rr;
        float v = acc[g4][rr];
        if (SPLIT == 1) v = fmaxf(v, 0.f);   // fused ReLU (direct output)
        part[(size_t)spl * N +
             (((size_t)pb[pxl] * COUT + (oc0 + ocl)) * HOUT + pyA[pxl]) * WOUT + pxA[pxl]] = v;
      }
    }
  }
}

// ---------------- fallback conv (round-11 proven path) ----------------
template <int CIN, int HIN, int WIN, int COUT, int HOUT, int WOUT, int SPLIT>
__global__ __launch_bounds__(256) void k_convm(const float* __restrict__ x,
                                               const float* __restrict__ wsrc,
                                               float* __restrict__ part) {
  constexpr int NPX = 4 * HOUT * WOUT;
  constexpr int KTOT = (CIN * 9) / SPLIT;
  constexpr int NCH = KTOT / 64;
  __shared__ __align__(16) unsigned short Xs[2][64][64];
  __shared__ __align__(16) unsigned short Wsh[3][64][64];
  __shared__ int pb[64], pyA[64], pxA[64];
  const int tid = threadIdx.x;
  const int oc0 = blockIdx.y * 64, px0 = blockIdx.x * 64;
  const int spl = blockIdx.z;
  const int kg0 = spl * KTOT;
  if (tid < 64) {
    int p = px0 + tid;
    if (p > NPX - 1) p = NPX - 1;
    int hw = HOUT * WOUT;
    pb[tid] = p / hw;
    int r = p % hw;
    pyA[tid] = r / WOUT;
    pxA[tid] = r % WOUT;
  }
  f32x4 acc[4] = {};
  const int l = tid & 63, wv = tid >> 6;
  const int lr = l & 15, lh = l >> 4;
  __syncthreads();
  for (int ch = 0; ch < NCH; ++ch) {
    const int kbase = kg0 + ch * 64;
    #pragma unroll
    for (int j = 0; j < 2; ++j) {
      int c = tid + 256 * j;
      int oc = c >> 3, koct = c & 7;
      const float* wp = wsrc + (size_t)(oc0 + oc) * (CIN * 9) + kbase + koct * 8;
      float vv[8];
      *(float4*)&vv[0] = *(const float4*)wp;
      *(float4*)&vv[4] = *(const float4*)(wp + 4);
      short8m ph, pm, pl2;
      #pragma unroll
      for (int i = 0; i < 8; ++i) {
        unsigned short hb = bf16_trunc(vv[i]);
        float r = vv[i] - bf16_tof(hb);
        unsigned short mb = bf16_rte(r);
        float r2 = r - bf16_tof(mb);
        unsigned short lb = bf16_rte(r2);
        ph[i] = (short)hb; pm[i] = (short)mb; pl2[i] = (short)lb;
      }
      *ldsPtr(&Wsh[0][0][0], oc, koct * 16) = ph;
      *ldsPtr(&Wsh[1][0][0], oc, koct * 16) = pm;
      *ldsPtr(&Wsh[2][0][0], oc, koct * 16) = pl2;
    }
    #pragma unroll
    for (int j = 0; j < 2; ++j) {
      int c = tid + 256 * j;
      int px = c & 63, koct = c >> 6;
      int pbv = pb[px], py = pyA[px], pxv = pxA[px];
      float vv[8];
      #pragma unroll
      for (int i = 0; i < 8; ++i) {
        int k = kbase + koct * 8 + i;
        int ci = k / 9, tap = k - ci * 9;
        int iy = py * 2 - 1 + tap / 3, ix = pxv * 2 - 1 + (tap % 3);
        float v = 0.f;
        if ((unsigned)iy < (unsigned)HIN && (unsigned)ix < (unsigned)WIN)
          v = x[(((size_t)pbv * CIN + ci) * HIN + iy) * WIN + ix];
        vv[i] = v;
      }
      short8m ph, pm;
      #pragma unroll
      for (int i = 0; i < 8; ++i) {
        unsigned short hb = bf16_trunc(vv[i]);
        unsigned short mb = bf16_rte(vv[i] - bf16_tof(hb));
        ph[i] = (short)hb; pm[i] = (short)mb;
      }
      *ldsPtr(&Xs[0][0][0], px, koct * 16) = ph;
      *ldsPtr(&Xs[1][0][0], px, koct * 16) = pm;
    }
    __syncthreads();
    #pragma unroll
    for (int ks = 0; ks < 2; ++ks) {
      const int kbyte = ks * 64 + lh * 16;
      short8m aH = *ldsPtr(&Wsh[0][0][0], wv * 16 + lr, kbyte);
      short8m aM = *ldsPtr(&Wsh[1][0][0], wv * 16 + lr, kbyte);
      short8m aL = *ldsPtr(&Wsh[2][0][0], wv * 16 + lr, kbyte);
      #pragma unroll
      for (int g = 0; g < 4; ++g) {
        short8m bH = *ldsPtr(&Xs[0][0][0], g * 16 + lr, kbyte);
        short8m bM = *ldsPtr(&Xs[1][0][0], g * 16 + lr, kbyte);
        acc[g] = __builtin_amdgcn_mfma_f32_16x16x32_bf16(aH, bH, acc[g], 0, 0, 0);
        acc[g] = __builtin_amdgcn_mfma_f32_16x16x32_bf16(aH, bM, acc[g], 0, 0, 0);
        acc[g] = __builtin_amdgcn_mfma_f32_16x16x32_bf16(aM, bH, acc[g], 0, 0, 0);
        acc[g] = __builtin_amdgcn_mfma_f32_16x16x32_bf16(aM, bM, acc[g], 0, 0, 0);
        acc[g] = __builtin_amdgcn_mfma_f32_16x16x32_bf16(aL, bH, acc[g], 0, 0, 0);
      }
    }
    __syncthreads();
  }
  const size_t N = (size_t)4 * COUT * HOUT * WOUT;
  #pragma unroll
  for (int g = 0; g < 4; ++g) {
    int pxl = g * 16 + lr;
    int pidx = px0 + pxl;
    if (pidx < NPX) {
      #pragma unroll
      for (int r = 0; r < 4; ++r) {
        int ocl = wv * 16 + lh * 4 + r;
        part[(size_t)spl * N +
             (((size_t)pb[pxl] * COUT + (oc0 + ocl)) * HOUT + pyA[pxl]) * WOUT + pxA[pxl]] =
            acc[g][r];
      }
    }
  }
}

// ---------------- split-K reduction + ReLU ----------------
template <int SPLIT>
__global__ __launch_bounds__(256) void k_red(const float* __restrict__ part,
                                             float* __restrict__ y, int n) {
  for (int i = blockIdx.x * 256 + threadIdx.x; i < n; i += gridDim.x * 256) {
    float s = 0.f;
    #pragma unroll
    for (int sp = 0; sp < SPLIT; ++sp) s += part[(size_t)sp * n + i];
    y[i] = fmaxf(s, 0.f);
  }
}

// ---------------- global-max-pool (7x7): one thread per (b,ch) ----------------
__global__ __launch_bounds__(256) void k_pool(const float* __restrict__ feat,
                                              float* __restrict__ pool) {
  int idx = blockIdx.x * 256 + threadIdx.x;
  if (idx >= 8192) return;
  const float* fp = feat + (size_t)idx * 49;
  float m = fp[0];
  #pragma unroll
  for (int i = 1; i < 49; ++i) m = fmaxf(m, fp[i]);
  pool[idx] = m;
}

// ---------------- FC(2048->14) + sigmoid: one block per (b,c) ----------------
__global__ __launch_bounds__(256) void k_fcsig(const float* __restrict__ pool,
                                               const float* __restrict__ fw,
                                               const float* __restrict__ fb,
                                               float* __restrict__ outp) {
  __shared__ float red[256];
  const int blk = blockIdx.x;       // b*14 + c
  const int b = blk / 14, c = blk % 14;
  const int tid = threadIdx.x;
  float s = 0.f;
  for (int k = tid; k < 2048; k += 256) s += pool[b * 2048 + k] * fw[c * 2048 + k];
  red[tid] = s;
  __syncthreads();
  for (int st = 128; st > 0; st >>= 1) {
    if (tid < st) red[tid] += red[tid + st];
    __syncthreads();
  }
  if (tid == 0) outp[b * 14 + c] = 1.f / (1.f + expf(-(red[0] + fb[c])));
}

// ---------------- fused FC(4096->14) + sigmoid for out_f: one block per (b,c) ----------------
__global__ __launch_bounds__(256) void k_fcsig2(const float* __restrict__ poolg,
                                                const float* __restrict__ pooll,
                                                const float* __restrict__ fw,
                                                const float* __restrict__ fb,
                                                float* __restrict__ outp) {
  __shared__ float red[256];
  const int blk = blockIdx.x;       // b*14 + c
  const int b = blk / 14, c = blk % 14;
  const int tid = threadIdx.x;
  const float* w = fw + (size_t)c * 4096;
  float s = 0.f;
  for (int k = tid; k < 2048; k += 256) s += poolg[b * 2048 + k] * w[k];
  for (int k = tid; k < 2048; k += 256) s += pooll[b * 2048 + k] * w[2048 + k];
  red[tid] = s;
  __syncthreads();
  for (int st = 128; st > 0; st >>= 1) {
    if (tid < st) red[tid] += red[tid + st];
    __syncthreads();
  }
  if (tid == 0) outp[blk] = 1.f / (1.f + expf(-(red[0] + fb[c])));
}

// ---------------- loss: weighted BCEs over the 3x56 sigmoid outputs already in d_out ----------------
__global__ __launch_bounds__(64) void k_loss(const float* __restrict__ target,
                                             float* __restrict__ dout) {
  __shared__ float red[64];
  const int tid = threadIdx.x;
  float term = 0.f;
  if (tid < 56) {
    float t = target[tid];
    float pg = dout[1 + tid], plo = dout[57 + tid], pf = dout[113 + tid];
    auto bce1 = [&](float pp) {
      pp = fminf(fmaxf(pp, 1e-7f), 1.f - 1e-7f);
      return -(t * logf(pp) + (1.f - t) * log1pf(-pp));
    };
    term = (0.8f * bce1(pg) + 0.1f * bce1(plo) + 0.1f * bce1(pf)) * (1.f / 56.f);
  }
  red[tid] = term;
  __syncthreads();
  for (int st = 32; st > 0; st >>= 1) {
    if (tid < st) red[tid] += red[tid + st];
    __syncthreads();
  }
  if (tid == 0) dout[0] = red[0];
}

// ---------------- heatmap stage A: per-(b,cell) channel max|.| ----------------
__global__ __launch_bounds__(256) void k_hm7a(const float* __restrict__ feat,
                                              float* __restrict__ hmr) {
  __shared__ float red[256];
  const int b = blockIdx.x / 49, cell = blockIdx.x % 49;
  const int tid = threadIdx.x;
  float m = 0.f;
  for (int ch = tid; ch < 2048; ch += 256)
    m = fmaxf(m, fabsf(feat[((size_t)b * 2048 + ch) * 49 + cell]));
  red[tid] = m;
  __syncthreads();
  for (int st = 128; st > 0; st >>= 1) {
    if (tid < st) red[tid] = fmaxf(red[tid], red[tid + st]);
    __syncthreads();
  }
  if (tid == 0) hmr[b * 49 + cell] = red[0];
}

// ---------------- heatmap stage B: per-sample min-max normalize ----------------
__global__ __launch_bounds__(64) void k_hm7b(const float* __restrict__ hmr,
                                             float* __restrict__ hm7) {
  __shared__ float h[49];
  const int b = blockIdx.x, tid = threadIdx.x;
  if (tid < 49) h[tid] = hmr[b * 49 + tid];
  __syncthreads();
  if (tid == 0) {
    float mn = h[0], mx = h[0];
    for (int i = 1; i < 49; ++i) {
      mn = fminf(mn, h[i]);
      mx = fmaxf(mx, h[i]);
    }
    for (int i = 0; i < 49; ++i) hm7[b * 49 + i] = (h[i] - mn) / (mx - mn);
  }
}

// ---------------- parallel CCL on mask runs + bbox of largest component ----------------
#define MAXR 8
#define NRUNS (224 * MAXR)
__global__ __launch_bounds__(256) void k_ccl(const float* __restrict__ hm7, float* __restrict__ bbox) {
  const int b = blockIdx.x, tid = threadIdx.x;
  __shared__ float h7[49];
  __shared__ short rx0[NRUNS], rx1[NRUNS];
  __shared__ short nr[224];
  __shared__ int lab[NRUNS];
  __shared__ int cnt[NRUNS], mid[NRUNS];
  __shared__ int rmn[NRUNS], rmx[NRUNS], cmn[NRUNS], cmx[NRUNS];
  __shared__ int chg, chg2;
  __shared__ int bestC[256], bestM[256], bestI[256];

  if (tid < 49) h7[tid] = hm7[b * 49 + tid];
  for (int i = tid; i < NRUNS; i += 256) {
    cnt[i] = 0; mid[i] = -1;
    rmn[i] = 1 << 30; rmx[i] = -1; cmn[i] = 1 << 30; cmx[i] = -1;
    lab[i] = i;
  }
  __syncthreads();
  if (tid < 224) {
    int yy = tid;
    float py = ((float)yy + 0.5f) * (7.f / 224.f) - 0.5f;
    py = fminf(fmaxf(py, 0.f), 6.f);
    int y0 = (int)floorf(py);
    if (y0 > 5) y0 = 5;
    float fy = py - (float)y0;
    int n = 0, start = -1;
    const int segLo[6] = {0, 48, 80, 112, 144, 176};
    const int segHi[6] = {48, 80, 112, 144, 176, 224};
    #pragma unroll
    for (int s = 0; s < 6; ++s) {
      float A = h7[y0 * 7 + s], B = h7[y0 * 7 + s + 1];
      float C = h7[(y0 + 1) * 7 + s], D = h7[(y0 + 1) * 7 + s + 1];
      for (int xx = segLo[s]; xx < segHi[s]; ++xx) {
        float px = ((float)xx + 0.5f) * (7.f / 224.f) - 0.5f;
        px = fminf(fmaxf(px, 0.f), 6.f);
        float fx = px - (float)s;
        float v = (1.f - fy) * ((1.f - fx) * A + fx * B) +
                  fy * ((1.f - fx) * C + fx * D);
        bool m = v > 0.7f;
        if (m && start < 0) start = xx;
        if (!m && start >= 0) {
          if (n < MAXR) { rx0[yy * MAXR + n] = (short)start; rx1[yy * MAXR + n] = (short)(xx - 1); n++; }
          start = -1;
        }
      }
    }
    if (start >= 0 && n < MAXR) { rx0[yy * MAXR + n] = (short)start; rx1[yy * MAXR + n] = 223; n++; }
    nr[yy] = (short)n;
  }
  __syncthreads();
  int myA0[7], myA1[7];
  bool myV[7];
  #pragma unroll
  for (int j = 0; j < 7; ++j) {
    int i = tid + j * 256;
    int yy = i >> 3, k = i & 7;
    bool v = (k < (int)nr[yy]);
    myV[j] = v;
    myA0[j] = v ? (int)rx0[i] : 0;
    myA1[j] = v ? (int)rx1[i] : 0;
  }
  for (int outer = 0; outer < 48; ++outer) {
    if (tid == 0) chg = 0;
    __syncthreads();
    bool any = false;
    #pragma unroll
    for (int j = 0; j < 7; ++j) {
      if (!myV[j]) continue;
      int i = tid + j * 256;
      int yy = i >> 3;
      int a0 = myA0[j], a1 = myA1[j];
      int ri = lab[i];
      if (yy > 0) {
        int n1 = nr[yy - 1];
        for (int kk = 0; kk < n1; ++kk) {
          int q = ((yy - 1) << 3) + kk;
          if (a0 <= rx1[q] + 1 && a1 >= rx0[q] - 1) {
            int rq = lab[q];
            if (rq < ri) { atomicMin(&lab[ri], rq); any = true; }
            else if (ri < rq) { atomicMin(&lab[rq], ri); any = true; }
          }
        }
      }
      if (yy < 223) {
        int n1 = nr[yy + 1];
        for (int kk = 0; kk < n1; ++kk) {
          int q = ((yy + 1) << 3) + kk;
          if (a0 <= rx1[q] + 1 && a1 >= rx0[q] - 1) {
            int rq = lab[q];
            if (rq < ri) { atomicMin(&lab[ri], rq); any = true; }
            else if (ri < rq) { atomicMin(&lab[rq], ri); any = true; }
          }
        }
      }
    }
    if (any) chg = 1;
    __syncthreads();
    for (int sc = 0; sc < 12; ++sc) {
      if (tid == 0) chg2 = 0;
      __syncthreads();
      bool a2 = false;
      #pragma unroll
      for (int j = 0; j < 7; ++j) {
        int i = tid + j * 256;
        int ll = lab[i];
        int l2 = lab[ll];
        if (l2 < ll) { lab[i] = l2; a2 = true; }
      }
      if (a2) chg2 = 1;
      __syncthreads();
      if (!chg2) break;
    }
    if (!chg) break;
  }
  for (int i = tid; i < NRUNS; i += 256) {
    int yy = i >> 3, k = i & 7;
    if (k >= (int)nr[yy]) continue;
    int r = lab[i];
    int a0 = rx0[i], a1 = rx1[i];
    atomicAdd(&cnt[r], a1 - a0 + 1);
    atomicMax(&mid[r], yy * 224 + a1 + 1);
    atomicMin(&rmn[r], yy);
    atomicMax(&rmx[r], yy);
    atomicMin(&cmn[r], a0);
    atomicMax(&cmx[r], a1);
  }
  __syncthreads();
  int bc = -1, bm = 0x7fffffff, bi = -1;
  for (int i = tid; i < NRUNS; i += 256) {
    if (cnt[i] > 0 && lab[i] == i) {
      if (cnt[i] > bc || (cnt[i] == bc && mid[i] < bm)) { bc = cnt[i]; bm = mid[i]; bi = i; }
    }
  }
  bestC[tid] = bc; bestM[tid] = bm; bestI[tid] = bi;
  __syncthreads();
  for (int st = 128; st > 0; st >>= 1) {
    if (tid < st) {
      if (bestC[tid + st] > bestC[tid] ||
          (bestC[tid + st] == bestC[tid] && bestM[tid + st] < bestM[tid])) {
        bestC[tid] = bestC[tid + st]; bestM[tid] = bestM[tid + st]; bestI[tid] = bestI[tid + st];
      }
    }
    __syncthreads();
  }
  if (tid == 0) {
    int bw = bestI[0];
    float fy0, chf, fx0, cwf;
    if (bw < 0) { fy0 = 224.f; chf = 1.f; fx0 = 224.f; cwf = 1.f; }
    else {
      int dr = rmx[bw] - rmn[bw]; if (dr < 1) dr = 1;
      int dc = cmx[bw] - cmn[bw]; if (dc < 1) dc = 1;
      fy0 = (float)rmn[bw]; chf = (float)dr;
      fx0 = (float)cmn[bw]; cwf = (float)dc;
    }
    bbox[b * 4 + 0] = fy0; bbox[b * 4 + 1] = chf;
    bbox[b * 4 + 2] = fx0; bbox[b * 4 + 3] = cwf;
  }
}

// ---------------- bilinear crop-resize back to 224x224 ----------------
__global__ __launch_bounds__(256) void k_sample(const float* __restrict__ img,
                                                const float* __restrict__ bbox,
                                                float* __restrict__ patch_out,
                                                float* __restrict__ patch_ws) {
  int idx = blockIdx.x * 256 + threadIdx.x;
  if (idx >= 4 * 3 * 224 * 224) return;
  int b = idx / (3 * 224 * 224);
  int r = idx % (3 * 224 * 224);
  int c = r / (224 * 224);
  int p = r % (224 * 224);
  int oy = p / 224, ox = p % 224;
  float fy0 = bbox[b * 4 + 0], chf = bbox[b * 4 + 1];
  float fx0 = bbox[b * 4 + 2], cwf = bbox[b * 4 + 3];
  float gy = ((float)oy + 0.5f) * (chf / 224.f) + fy0 - 0.5f;
  float gx = ((float)ox + 0.5f) * (cwf / 224.f) + fx0 - 0.5f;
  gy = fminf(fmaxf(gy, fy0), fmaxf(fy0 + chf - 1.f, fy0));
  gx = fminf(fmaxf(gx, fx0), fmaxf(fx0 + cwf - 1.f, fx0));
  int y0 = (int)floorf(gy);
  int x0 = (int)floorf(gx);
  float fy = gy - (float)y0, fx = gx - (float)x0;
  int y0c = min(max(y0, 0), 223), y1c = min(max(y0 + 1, 0), 223);
  int x0c = min(max(x0, 0), 223), x1c = min(max(x0 + 1, 0), 223);
  const float* ip = img + ((size_t)b * 3 + c) * 224 * 224;
  float v00 = ip[y0c * 224 + x0c], v01 = ip[y0c * 224 + x1c];
  float v10 = ip[y1c * 224 + x0c], v11 = ip[y1c * 224 + x1c];
  float v = (1.f - fy) * ((1.f - fx) * v00 + fx * v01) + fy * ((1.f - fx) * v10 + fx * v11);
  patch_out[idx] = v;
  patch_ws[idx] = v;
}

extern "C" void kernel_launch(void* const* d_in, const int* in_sizes, int n_in,
                              void* d_out, int out_size, void* d_ws, size_t ws_size,
                              hipStream_t stream) {
  const float* img = (const float*)d_in[0];
  const float* target = (const float*)d_in[1];
  const float* gw0 = (const float*)d_in[2];
  const float* gw1 = (const float*)d_in[3];
  const float* gw2 = (const float*)d_in[4];
  const float* gw3 = (const float*)d_in[5];
  const float* gfw = (const float*)d_in[6];
  const float* gfb = (const float*)d_in[7];
  const float* lw0 = (const float*)d_in[8];
  const float* lw1 = (const float*)d_in[9];
  const float* lw2 = (const float*)d_in[10];
  const float* lw3 = (const float*)d_in[11];
  const float* lfw = (const float*)d_in[12];
  const float* lfb = (const float*)d_in[13];
  const float* fw = (const float*)d_in[14];
  const float* fb = (const float*)d_in[15];
  float* out = (float*)d_out;
  float* ws = (float*)d_ws;

  float* c1 = ws;                    // 802816   [4,64,56,56]
  float* c2 = c1 + 802816;           // 1605632  [4,512,28,28]
  float* c3 = c2 + 1605632;          // 802816   [4,1024,14,14]
  float* c4 = c3 + 802816;           // 401408   [4,2048,7,7]
  float* poolg = c4 + 401408;        // 8192
  float* pooll = poolg + 8192;       // 8192
  float* hm7 = pooll + 8192;         // 196
  float* hmr = hm7 + 196;            // 196
  float* bbox = hmr + 196;           // 16
  float* patch = ws + 3629568;       // 602112 (16B aligned)
  float* part = ws + 4231680;        // <=3211264 split-K partials
  float* Wp = part + 2800000;        // 12288 padded conv7 weights (dead corner of part)
  unsigned short* XgH = (unsigned short*)(ws + 7442944);   // fast path only
  unsigned short* XgM = XgH + 3840000;

  const bool fast = ws_size >= (size_t)45131776;

  dim3 g7(13, 256);
  const int rg2 = 2048, rg3 = 2048, rg4 = 1568;

  for (int pass = 0; pass < 2; ++pass) {
    const float* w0 = pass ? lw0 : gw0;
    const float* w1 = pass ? lw1 : gw1;
    const float* w2 = pass ? lw2 : gw2;
    const float* w3 = pass ? lw3 : gw3;
    const float* fwp = pass ? lfw : gfw;
    const float* fbp = pass ? lfb : gfb;
    const float* inp = pass ? patch : img;
    float* pool = pass ? pooll : poolg;
    float* outp = pass ? (out + 57) : (out + 1);

    if (fast) {
      // conv7 as im2col GEMM (K=147 zero-padded to 192), fused ReLU -> c1
      k_padw<<<48, 256, 0, stream>>>(w0, Wp, 147, 192, 64);
      k_im2col<3, 224, 224, 56, 56, 7, 7, 4, 3, 192><<<1176, 256, 0, stream>>>(inp, XgH, XgM);
      k_gemmx<64, 56, 56, 192, 1><<<196, 256, 0, stream>>>(XgH, XgM, Wp, c1);
      k_im2col<64, 56, 56, 28, 28, 3, 3, 2, 1, 576><<<882, 256, 0, stream>>>(c1, XgH, XgM);
      k_gemmx<512, 28, 28, 576, 1><<<392, 256, 0, stream>>>(XgH, XgM, w1, c2);
      k_im2col<512, 28, 28, 14, 14, 3, 3, 2, 1, 4608><<<1872, 256, 0, stream>>>(c2, XgH, XgM);
      k_gemmx<1024, 14, 14, 4608, 4><<<832, 256, 0, stream>>>(XgH, XgM, w2, part);
      k_red<4><<<rg3, 256, 0, stream>>>(part, c3, 802816);
      k_im2col<1024, 14, 14, 7, 7, 3, 3, 2, 1, 9216><<<1152, 256, 0, stream>>>(c3, XgH, XgM);
      k_gemmx<2048, 7, 7, 9216, 8><<<1024, 256, 0, stream>>>(XgH, XgM, w3, part);
      k_red<8><<<rg4, 256, 0, stream>>>(part, c4, 401408);
    } else {
      k_conv7<<<g7, 256, 0, stream>>>(inp, w0, c1);
      k_convm<64, 56, 56, 512, 28, 28, 1><<<dim3(49, 8, 1), 256, 0, stream>>>(c1, w1, part);
      k_red<1><<<rg2, 256, 0, stream>>>(part, c2, 1605632);
      k_convm<512, 28, 28, 1024, 14, 14, 4><<<dim3(13, 16, 4), 256, 0, stream>>>(c2, w2, part);
      k_red<4><<<rg3, 256, 0, stream>>>(part, c3, 802816);
      k_convm<1024, 14, 14, 2048, 7, 7, 8><<<dim3(4, 32, 8), 256, 0, stream>>>(c3, w3, part);
      k_red<8><<<rg4, 256, 0, stream>>>(part, c4, 401408);
    }
    k_pool<<<32, 256, 0, stream>>>(c4, pool);
    k_fcsig<<<56, 256, 0, stream>>>(pool, fwp, fbp, outp);

    if (pass == 0) {
      k_hm7a<<<196, 256, 0, stream>>>(c4, hmr);
      k_hm7b<<<4, 64, 0, stream>>>(hmr, hm7);
      k_ccl<<<4, 256, 0, stream>>>(hm7, bbox);
      k_sample<<<2352, 256, 0, stream>>>(img, bbox, out + 169, patch);
    }
  }
  // fusion FC (parallel) + loss (tiny)
  k_fcsig2<<<56, 256, 0, stream>>>(poolg, pooll, fw, fb, out + 113);
  k_loss<<<1, 64, 0, stream>>>(target, out);
}